// Round 1
// baseline (724.671 us; speedup 1.0000x reference)
//
#include <hip/hip_runtime.h>

#define CH 128  // channels = H*D = 4*32

// ---------- bf16 helpers (bit-level, no hip_bf16 class issues) ----------
static __device__ __forceinline__ float bf2f(unsigned short u) {
  union { unsigned int i; float f; } c;
  c.i = ((unsigned int)u) << 16;
  return c.f;
}
static __device__ __forceinline__ unsigned short f2bf(float f) {
  union { float f; unsigned int i; } c;
  c.f = f;
  unsigned int r = c.i + 0x7fffu + ((c.i >> 16) & 1u);  // RNE
  return (unsigned short)(r >> 16);
}

// ---------- 1. BatchNorm statistics ----------
__global__ void bn_stats_kernel(const float* __restrict__ x, float* __restrict__ stats, int N) {
  int t = threadIdx.x;          // 256 threads: 2 rows x 128 channels
  int ch = t & (CH - 1);
  int r0 = t >> 7;
  float s = 0.f, ss = 0.f;
  for (int row = blockIdx.x * 2 + r0; row < N; row += gridDim.x * 2) {
    float v = x[(size_t)row * CH + ch];
    s += v;
    ss += v * v;
  }
  atomicAdd(&stats[ch], s);
  atomicAdd(&stats[CH + ch], ss);
}

__global__ void bn_finalize_kernel(const float* __restrict__ stats,
                                   const float* __restrict__ gamma,
                                   const float* __restrict__ beta,
                                   float* __restrict__ scsh, int N) {
  int c = threadIdx.x;
  if (c < CH) {
    float inv_n = 1.0f / (float)N;
    float mu = stats[c] * inv_n;
    float var = stats[CH + c] * inv_n - mu * mu;  // population var (ddof=0)
    float sc = gamma[c] * rsqrtf(var + 1e-5f);
    scsh[c] = sc;
    scsh[CH + c] = beta[c] - mu * sc;
  }
}

// ---------- 2. fused BN+ReLU + 4 projections (q,k,v,skip), bf16 out ----------
// grid: (ceil(N/64), 8); blockIdx.y: mat = y>>1 (q,k,v,skip), colOff = (y&1)*64
__global__ __launch_bounds__(256) void proj_kernel(
    const float* __restrict__ x, const float* __restrict__ scsh,
    const float* __restrict__ Wq, const float* __restrict__ bq_,
    const float* __restrict__ Wk, const float* __restrict__ bk_,
    const float* __restrict__ Wv, const float* __restrict__ bv_,
    const float* __restrict__ Ws, const float* __restrict__ bs_,
    unsigned short* __restrict__ q, unsigned short* __restrict__ k,
    unsigned short* __restrict__ v, unsigned short* __restrict__ s_, int N) {
  __shared__ __align__(16) float As[64 * 128];  // h tile (rows x K)
  __shared__ __align__(16) float Bs[128 * 64];  // W tile (K x cols)
  int t = threadIdx.x;
  const float* W;
  const float* bias;
  unsigned short* out;
  int mat = blockIdx.y >> 1;
  int colOff = (blockIdx.y & 1) * 64;
  switch (mat) {
    case 0: W = Wq; bias = bq_; out = q; break;
    case 1: W = Wk; bias = bk_; out = k; break;
    case 2: W = Wv; bias = bv_; out = v; break;
    default: W = Ws; bias = bs_; out = s_; break;
  }
  size_t row0 = (size_t)blockIdx.x * 64;
  size_t limit = (size_t)N * CH;

  // stage A = relu(bn(x)) for 64 rows (contiguous 32KB region)
  for (int i = 0; i < 8; ++i) {
    int idx = i * 1024 + t * 4;
    size_t g = row0 * CH + idx;
    float4 val = make_float4(0.f, 0.f, 0.f, 0.f);
    if (g + 4 <= limit) val = *reinterpret_cast<const float4*>(x + g);
    int c = idx & (CH - 1);
    float4 sc = *reinterpret_cast<const float4*>(scsh + c);
    float4 sh = *reinterpret_cast<const float4*>(scsh + CH + c);
    float4 hv;
    hv.x = fmaxf(fmaf(val.x, sc.x, sh.x), 0.f);
    hv.y = fmaxf(fmaf(val.y, sc.y, sh.y), 0.f);
    hv.z = fmaxf(fmaf(val.z, sc.z, sh.z), 0.f);
    hv.w = fmaxf(fmaf(val.w, sc.w, sh.w), 0.f);
    *reinterpret_cast<float4*>(As + idx) = hv;
  }
  // stage B: W[0:128, colOff:colOff+64]
  for (int i = 0; i < 8; ++i) {
    int e = i * 256 + t;
    int rw = e >> 4, c4 = (e & 15) << 2;
    *reinterpret_cast<float4*>(Bs + rw * 64 + c4) =
        *reinterpret_cast<const float4*>(W + rw * CH + colOff + c4);
  }
  __syncthreads();

  int rg = (t >> 4) << 2;  // 4 rows
  int cg = (t & 15) << 2;  // 4 cols
  float acc[4][4] = {{0.f}};
  for (int kk = 0; kk < 128; kk += 4) {
    float4 av[4], bvv[4];
#pragma unroll
    for (int i = 0; i < 4; ++i)
      av[i] = *reinterpret_cast<const float4*>(As + (rg + i) * 128 + kk);
#pragma unroll
    for (int j = 0; j < 4; ++j)
      bvv[j] = *reinterpret_cast<const float4*>(Bs + (kk + j) * 64 + cg);
    const float* ap = reinterpret_cast<const float*>(av);
    const float* bp = reinterpret_cast<const float*>(bvv);
#pragma unroll
    for (int kx = 0; kx < 4; ++kx)
#pragma unroll
      for (int i = 0; i < 4; ++i)
#pragma unroll
        for (int j = 0; j < 4; ++j)
          acc[i][j] = fmaf(ap[i * 4 + kx], bp[kx * 4 + j], acc[i][j]);
  }
  int cbase = colOff + cg;
  float b0 = bias[cbase + 0], b1 = bias[cbase + 1];
  float b2 = bias[cbase + 2], b3 = bias[cbase + 3];
#pragma unroll
  for (int i = 0; i < 4; ++i) {
    size_t row = row0 + rg + i;
    if (row < (size_t)N) {
      ushort4 pk;
      pk.x = f2bf(acc[i][0] + b0);
      pk.y = f2bf(acc[i][1] + b1);
      pk.z = f2bf(acc[i][2] + b2);
      pk.w = f2bf(acc[i][3] + b3);
      *reinterpret_cast<ushort4*>(out + row * CH + cbase) = pk;
    }
  }
}

// ---------- 3. CSR build over dst ----------
__global__ void deg_count_kernel(const int* __restrict__ dst, int* __restrict__ deg, int E) {
  for (int e = blockIdx.x * blockDim.x + threadIdx.x; e < E; e += gridDim.x * blockDim.x)
    atomicAdd(&deg[dst[e]], 1);
}

__global__ void sum_chunks_kernel(const int* __restrict__ deg, int* __restrict__ chunksums, int N) {
  __shared__ int sd[256];
  int t = threadIdx.x;
  int base = blockIdx.x * 2048;
  int s = 0;
  for (int i = 0; i < 8; ++i) {
    int idx = base + t * 8 + i;
    if (idx < N) s += deg[idx];
  }
  sd[t] = s;
  __syncthreads();
  for (int o = 128; o > 0; o >>= 1) {
    if (t < o) sd[t] += sd[t + o];
    __syncthreads();
  }
  if (t == 0) chunksums[blockIdx.x] = sd[0];
}

__global__ void scan_sums_kernel(const int* __restrict__ chunksums, int* __restrict__ chunkoffs,
                                 int nchunks, int* __restrict__ rowptr, int N) {
  if (threadIdx.x == 0) {
    int acc = 0;
    for (int i = 0; i < nchunks; ++i) {
      chunkoffs[i] = acc;
      acc += chunksums[i];
    }
    rowptr[N] = acc;  // = E
  }
}

__global__ void scan_chunks_kernel(const int* __restrict__ deg, const int* __restrict__ chunkoffs,
                                   int* __restrict__ rowptr, int N) {
  __shared__ int sd[256];
  int t = threadIdx.x;
  int base = blockIdx.x * 2048;
  int vals[8];
  int s = 0;
  for (int i = 0; i < 8; ++i) {
    int idx = base + t * 8 + i;
    int d = (idx < N) ? deg[idx] : 0;
    vals[i] = s;
    s += d;
  }
  sd[t] = s;
  __syncthreads();
  int mytot = s;
  for (int o = 1; o < 256; o <<= 1) {
    int vprev = (t >= o) ? sd[t - o] : 0;
    __syncthreads();
    sd[t] += vprev;
    __syncthreads();
  }
  int texcl = sd[t] - mytot;
  int cb = chunkoffs[blockIdx.x];
  for (int i = 0; i < 8; ++i) {
    int idx = base + t * 8 + i;
    if (idx < N) rowptr[idx] = cb + texcl + vals[i];
  }
}

__global__ void scatter_kernel(const int* __restrict__ src, const int* __restrict__ dst,
                               const int* __restrict__ rowptr, int* __restrict__ fill,
                               int* __restrict__ sorted_src, int E) {
  for (int e = blockIdx.x * blockDim.x + threadIdx.x; e < E; e += gridDim.x * blockDim.x) {
    int d = dst[e];
    int pos = rowptr[d] + atomicAdd(&fill[d], 1);
    sorted_src[pos] = src[e];
  }
}

// ---------- 4. per-dst-node online softmax + weighted aggregation ----------
// one wave per node; lane owns channels {2*lane, 2*lane+1}; head = lane/16.
__global__ __launch_bounds__(256) void attn_kernel(
    const unsigned short* __restrict__ q, const unsigned short* __restrict__ k,
    const unsigned short* __restrict__ v, const unsigned short* __restrict__ skp,
    const int* __restrict__ rowptr, const int* __restrict__ sorted_src,
    float* __restrict__ conv, int N) {
  int lane = threadIdx.x & 63;
  int n = blockIdx.x * 4 + (threadIdx.x >> 6);
  if (n >= N) return;
  int beg = rowptr[n], end = rowptr[n + 1];
  size_t rowb = (size_t)n * CH;
  int c0 = lane * 2;
  ushort2 q2 = *reinterpret_cast<const ushort2*>(q + rowb + c0);
  const float ASC = 0.17677669529663687f;  // 1/sqrt(32)
  float qf0 = bf2f(q2.x) * ASC;
  float qf1 = bf2f(q2.y) * ASC;
  float m = -INFINITY, ssum = 0.f, acc0 = 0.f, acc1 = 0.f;
  for (int e = beg; e < end; ++e) {
    int src = sorted_src[e];
    size_t sbase = (size_t)src * CH + c0;
    ushort2 k2 = *reinterpret_cast<const ushort2*>(k + sbase);
    ushort2 v2 = *reinterpret_cast<const ushort2*>(v + sbase);
    float p = qf0 * bf2f(k2.x) + qf1 * bf2f(k2.y);
#pragma unroll
    for (int msk = 8; msk > 0; msk >>= 1) p += __shfl_xor(p, msk, 16);
    // p = alpha for this lane's head; online softmax update
    float nm = fmaxf(m, p);
    float f = __expf(m - nm);   // exp(-inf)=0 handles first edge
    float ex = __expf(p - nm);
    ssum = ssum * f + ex;
    acc0 = fmaf(acc0, f, ex * bf2f(v2.x));
    acc1 = fmaf(acc1, f, ex * bf2f(v2.y));
    m = nm;
  }
  float inv = (end > beg) ? 1.0f / ssum : 0.f;  // deg==0 -> agg = 0
  ushort2 s2 = *reinterpret_cast<const ushort2*>(skp + rowb + c0);
  float2 o;
  o.x = acc0 * inv + bf2f(s2.x);
  o.y = acc1 * inv + bf2f(s2.y);
  *reinterpret_cast<float2*>(conv + rowb + c0) = o;
}

// ---------- 5. out = conv @ Wfc + bfc + x  (in-place on d_out; row-disjoint) ----------
__global__ __launch_bounds__(256) void final_kernel(
    const float* __restrict__ conv, const float* __restrict__ Wfc,
    const float* __restrict__ bfc, const float* __restrict__ x,
    float* __restrict__ outp, int N) {
  __shared__ __align__(16) float As[64 * 128];
  __shared__ __align__(16) float Bs[64 * 128];  // one K-half of Wfc
  int t = threadIdx.x;
  size_t row0 = (size_t)blockIdx.x * 64;
  size_t limit = (size_t)N * CH;
  // stage A fully BEFORE any writes to these rows (in-place safety)
  for (int i = 0; i < 8; ++i) {
    int idx = i * 1024 + t * 4;
    size_t g = row0 * CH + idx;
    float4 val = make_float4(0.f, 0.f, 0.f, 0.f);
    if (g + 4 <= limit) val = *reinterpret_cast<const float4*>(conv + g);
    *reinterpret_cast<float4*>(As + idx) = val;
  }
  int rg = (t >> 4) << 2;  // 4 rows
  int cg = (t & 15) << 3;  // 8 cols
  float acc[4][8] = {{0.f}};
  for (int half = 0; half < 2; ++half) {
    __syncthreads();
    for (int i = 0; i < 8; ++i) {
      int e = i * 256 + t;
      int rw = e >> 5, c4 = (e & 31) << 2;
      *reinterpret_cast<float4*>(Bs + rw * 128 + c4) =
          *reinterpret_cast<const float4*>(Wfc + (half * 64 + rw) * CH + c4);
    }
    __syncthreads();
    for (int kk = 0; kk < 64; kk += 4) {
      float4 av[4], bv0[4], bv1[4];
#pragma unroll
      for (int i = 0; i < 4; ++i)
        av[i] = *reinterpret_cast<const float4*>(As + (rg + i) * 128 + half * 64 + kk);
#pragma unroll
      for (int j = 0; j < 4; ++j) {
        bv0[j] = *reinterpret_cast<const float4*>(Bs + (kk + j) * 128 + cg);
        bv1[j] = *reinterpret_cast<const float4*>(Bs + (kk + j) * 128 + cg + 4);
      }
      const float* ap = reinterpret_cast<const float*>(av);
      const float* b0p = reinterpret_cast<const float*>(bv0);
      const float* b1p = reinterpret_cast<const float*>(bv1);
#pragma unroll
      for (int kx = 0; kx < 4; ++kx)
#pragma unroll
        for (int i = 0; i < 4; ++i)
#pragma unroll
          for (int j = 0; j < 4; ++j) {
            acc[i][j]     = fmaf(ap[i * 4 + kx], b0p[kx * 4 + j], acc[i][j]);
            acc[i][j + 4] = fmaf(ap[i * 4 + kx], b1p[kx * 4 + j], acc[i][j + 4]);
          }
    }
  }
  float bb[8];
#pragma unroll
  for (int j = 0; j < 8; ++j) bb[j] = bfc[cg + j];
#pragma unroll
  for (int i = 0; i < 4; ++i) {
    size_t row = row0 + rg + i;
    if (row < (size_t)N) {
      size_t gb = row * CH + cg;
      float4 r0 = *reinterpret_cast<const float4*>(x + gb);
      float4 r1 = *reinterpret_cast<const float4*>(x + gb + 4);
      float4 o0, o1;
      o0.x = acc[i][0] + bb[0] + r0.x;
      o0.y = acc[i][1] + bb[1] + r0.y;
      o0.z = acc[i][2] + bb[2] + r0.z;
      o0.w = acc[i][3] + bb[3] + r0.w;
      o1.x = acc[i][4] + bb[4] + r1.x;
      o1.y = acc[i][5] + bb[5] + r1.y;
      o1.z = acc[i][6] + bb[6] + r1.z;
      o1.w = acc[i][7] + bb[7] + r1.w;
      *reinterpret_cast<float4*>(outp + gb) = o0;
      *reinterpret_cast<float4*>(outp + gb + 4) = o1;
    }
  }
}

// ---------------------------------------------------------------
extern "C" void kernel_launch(void* const* d_in, const int* in_sizes, int n_in,
                              void* d_out, int out_size, void* d_ws, size_t ws_size,
                              hipStream_t stream) {
  const float* x = (const float*)d_in[0];
  const int* ei = (const int*)d_in[1];
  const float* gamma = (const float*)d_in[2];
  const float* beta = (const float*)d_in[3];
  const float* Wq = (const float*)d_in[4];
  const float* bq = (const float*)d_in[5];
  const float* Wk = (const float*)d_in[6];
  const float* bk = (const float*)d_in[7];
  const float* Wv = (const float*)d_in[8];
  const float* bv = (const float*)d_in[9];
  const float* Ws = (const float*)d_in[10];
  const float* bs = (const float*)d_in[11];
  const float* Wfc = (const float*)d_in[12];
  const float* bfc = (const float*)d_in[13];

  const int N = in_sizes[0] / CH;   // 100000
  const int E = in_sizes[1] / 2;    // 1600000
  const int* srcp = ei;             // edge_index[0]
  const int* dstp = ei + E;         // edge_index[1]
  float* outp = (float*)d_out;

  char* wsb = (char*)d_ws;
  size_t off = 0;
  auto take = [&](size_t bytes) -> void* {
    void* p = wsb + off;
    off = (off + bytes + 255) & ~(size_t)255;
    return p;
  };
  float* stats = (float*)take(256 * 4);
  float* scsh = (float*)take(256 * 4);
  unsigned short* qb = (unsigned short*)take((size_t)N * CH * 2);
  unsigned short* kb = (unsigned short*)take((size_t)N * CH * 2);
  unsigned short* vb = (unsigned short*)take((size_t)N * CH * 2);
  unsigned short* sb = (unsigned short*)take((size_t)N * CH * 2);
  int* deg = (int*)take((size_t)N * 4);
  int* fill = (int*)take((size_t)N * 4);
  int* rowptr = (int*)take((size_t)(N + 1) * 4);
  int nchunks = (N + 2047) / 2048;
  int* chunksums = (int*)take((size_t)nchunks * 4);
  int* chunkoffs = (int*)take((size_t)nchunks * 4);
  int* sorted_src = (int*)take((size_t)E * 4);
  // total ws use ~110 MB

  hipMemsetAsync(stats, 0, 256 * 4, stream);
  hipMemsetAsync(deg, 0, (size_t)N * 4, stream);
  hipMemsetAsync(fill, 0, (size_t)N * 4, stream);

  bn_stats_kernel<<<512, 256, 0, stream>>>(x, stats, N);
  bn_finalize_kernel<<<1, 128, 0, stream>>>(stats, gamma, beta, scsh, N);

  dim3 pgrid((N + 63) / 64, 8);
  proj_kernel<<<pgrid, 256, 0, stream>>>(x, scsh, Wq, bq, Wk, bk, Wv, bv, Ws, bs,
                                         qb, kb, vb, sb, N);

  deg_count_kernel<<<2048, 256, 0, stream>>>(dstp, deg, E);
  sum_chunks_kernel<<<nchunks, 256, 0, stream>>>(deg, chunksums, N);
  scan_sums_kernel<<<1, 64, 0, stream>>>(chunksums, chunkoffs, nchunks, rowptr, N);
  scan_chunks_kernel<<<nchunks, 256, 0, stream>>>(deg, chunkoffs, rowptr, N);
  scatter_kernel<<<2048, 256, 0, stream>>>(srcp, dstp, rowptr, fill, sorted_src, E);

  // conv (= agg + skip) written into d_out, then final GEMM runs in-place
  attn_kernel<<<(N + 3) / 4, 256, 0, stream>>>(qb, kb, vb, sb, rowptr, sorted_src, outp, N);
  final_kernel<<<(N + 63) / 64, 256, 0, stream>>>(outp, Wfc, bfc, x, outp, N);
}

// Round 2
// 543.315 us; speedup vs baseline: 1.3338x; 1.3338x over previous
//
#include <hip/hip_runtime.h>

#define CH 128  // channels = H*D = 4*32

typedef short bf16x8 __attribute__((ext_vector_type(8)));
typedef float f32x4 __attribute__((ext_vector_type(4)));

// ---------- bf16 helpers ----------
static __device__ __forceinline__ float bf2f(unsigned short u) {
  union { unsigned int i; float f; } c;
  c.i = ((unsigned int)u) << 16;
  return c.f;
}
static __device__ __forceinline__ unsigned short f2bf(float f) {
  union { float f; unsigned int i; } c;
  c.f = f;
  unsigned int r = c.i + 0x7fffu + ((c.i >> 16) & 1u);  // RNE
  return (unsigned short)(r >> 16);
}

// ---------- 1. BatchNorm statistics ----------
__global__ void bn_stats_kernel(const float* __restrict__ x, float* __restrict__ stats, int N) {
  int t = threadIdx.x;
  int ch = t & (CH - 1);
  int r0 = t >> 7;
  float s = 0.f, ss = 0.f;
  for (int row = blockIdx.x * 2 + r0; row < N; row += gridDim.x * 2) {
    float v = x[(size_t)row * CH + ch];
    s += v;
    ss += v * v;
  }
  atomicAdd(&stats[ch], s);
  atomicAdd(&stats[CH + ch], ss);
}

__global__ void bn_finalize_kernel(const float* __restrict__ stats,
                                   const float* __restrict__ gamma,
                                   const float* __restrict__ beta,
                                   float* __restrict__ scsh, int N) {
  int c = threadIdx.x;
  if (c < CH) {
    float inv_n = 1.0f / (float)N;
    float mu = stats[c] * inv_n;
    float var = stats[CH + c] * inv_n - mu * mu;
    float sc = gamma[c] * rsqrtf(var + 1e-5f);
    scsh[c] = sc;
    scsh[CH + c] = beta[c] - mu * sc;
  }
}

// ---------- 1b. pack weights: Wt[mat][n][k] bf16, mats = q,k,v,skip,fc ----------
__global__ void pack_w_kernel(const float* __restrict__ Wq, const float* __restrict__ Wk,
                              const float* __restrict__ Wv, const float* __restrict__ Ws,
                              const float* __restrict__ Wfc, unsigned short* __restrict__ Wt) {
  int el = blockIdx.x * 256 + threadIdx.x;  // 5*16384 elements
  int mat = el >> 14;
  int rem = el & 16383;
  int kk = rem >> 7;
  int n = rem & 127;
  const float* W = mat == 0 ? Wq : mat == 1 ? Wk : mat == 2 ? Wv : mat == 3 ? Ws : Wfc;
  Wt[((size_t)mat << 14) + n * 128 + kk] = f2bf(W[kk * 128 + n]);
}

// ---------- 2. fused BN+ReLU + 4 projections via MFMA ----------
// block = 256 thr (4 waves); block covers 64 rows; wave w computes matrix w (q,k,v,skip).
__global__ __launch_bounds__(256, 2) void proj_mfma_kernel(
    const float* __restrict__ x, const float* __restrict__ scsh,
    const unsigned short* __restrict__ Wt,
    const float* __restrict__ bq_, const float* __restrict__ bk_,
    const float* __restrict__ bv_, const float* __restrict__ bs_,
    unsigned short* __restrict__ q, unsigned short* __restrict__ k,
    unsigned short* __restrict__ v, unsigned short* __restrict__ s_, int N) {
  __shared__ __align__(16) unsigned short As[64 * 128];  // 16KB, XOR-swizzled
  int t = threadIdx.x;
  int lane = t & 63;
  int wid = t >> 6;
  size_t row0 = (size_t)blockIdx.x * 64;

  // stage A = bf16(relu(bn(x))): 1024 chunks of 8 elements
  for (int i = 0; i < 4; ++i) {
    int c = i * 256 + t;
    int r = c >> 4;
    int kc = (c & 15) * 8;
    float4 v0 = make_float4(0.f, 0.f, 0.f, 0.f), v1 = v0;
    if (row0 + r < (size_t)N) {
      const float* g = x + (row0 + r) * CH + kc;
      v0 = *reinterpret_cast<const float4*>(g);
      v1 = *reinterpret_cast<const float4*>(g + 4);
    }
    float4 sca = *reinterpret_cast<const float4*>(scsh + kc);
    float4 scb = *reinterpret_cast<const float4*>(scsh + kc + 4);
    float4 sha = *reinterpret_cast<const float4*>(scsh + CH + kc);
    float4 shb = *reinterpret_cast<const float4*>(scsh + CH + kc + 4);
    unsigned short h[8];
    h[0] = f2bf(fmaxf(fmaf(v0.x, sca.x, sha.x), 0.f));
    h[1] = f2bf(fmaxf(fmaf(v0.y, sca.y, sha.y), 0.f));
    h[2] = f2bf(fmaxf(fmaf(v0.z, sca.z, sha.z), 0.f));
    h[3] = f2bf(fmaxf(fmaf(v0.w, sca.w, sha.w), 0.f));
    h[4] = f2bf(fmaxf(fmaf(v1.x, scb.x, shb.x), 0.f));
    h[5] = f2bf(fmaxf(fmaf(v1.y, scb.y, shb.y), 0.f));
    h[6] = f2bf(fmaxf(fmaf(v1.z, scb.z, shb.z), 0.f));
    h[7] = f2bf(fmaxf(fmaf(v1.w, scb.w, shb.w), 0.f));
    int4 pk;
    pk.x = (int)h[0] | ((int)h[1] << 16);
    pk.y = (int)h[2] | ((int)h[3] << 16);
    pk.z = (int)h[4] | ((int)h[5] << 16);
    pk.w = (int)h[6] | ((int)h[7] << 16);
    int byte = (r * 256 + kc * 2) ^ ((r & 7) << 4);
    *reinterpret_cast<int4*>((char*)As + byte) = pk;
  }
  __syncthreads();

  const unsigned short* wt = Wt + ((size_t)wid << 14);
  const float* bias = wid == 0 ? bq_ : wid == 1 ? bk_ : wid == 2 ? bv_ : bs_;
  unsigned short* outp = wid == 0 ? q : wid == 1 ? k : wid == 2 ? v : s_;
  int lr = lane & 15;
  int lg = lane >> 4;

  f32x4 acc[4][8];
#pragma unroll
  for (int mt = 0; mt < 4; ++mt)
#pragma unroll
    for (int nt = 0; nt < 8; ++nt) acc[mt][nt] = (f32x4){0.f, 0.f, 0.f, 0.f};

  for (int ks = 0; ks < 4; ++ks) {
    bf16x8 a[4], b[8];
#pragma unroll
    for (int mt = 0; mt < 4; ++mt) {
      int r = mt * 16 + lr;
      int byte = (r * 256 + (ks * 32 + lg * 8) * 2) ^ ((r & 7) << 4);
      a[mt] = *reinterpret_cast<const bf16x8*>((const char*)As + byte);
    }
#pragma unroll
    for (int nt = 0; nt < 8; ++nt)
      b[nt] = *reinterpret_cast<const bf16x8*>(wt + (nt * 16 + lr) * 128 + ks * 32 + lg * 8);
#pragma unroll
    for (int mt = 0; mt < 4; ++mt)
#pragma unroll
      for (int nt = 0; nt < 8; ++nt)
        acc[mt][nt] = __builtin_amdgcn_mfma_f32_16x16x32_bf16(a[mt], b[nt], acc[mt][nt], 0, 0, 0);
  }

  float bn_[8];
#pragma unroll
  for (int nt = 0; nt < 8; ++nt) bn_[nt] = bias[nt * 16 + lr];
#pragma unroll
  for (int mt = 0; mt < 4; ++mt) {
#pragma unroll
    for (int j = 0; j < 4; ++j) {
      size_t row = row0 + mt * 16 + lg * 4 + j;
      if (row < (size_t)N) {
#pragma unroll
        for (int nt = 0; nt < 8; ++nt)
          outp[row * CH + nt * 16 + lr] = f2bf(acc[mt][nt][j] + bn_[nt]);
      }
    }
  }
}

// ---------- 3. CSR build over dst ----------
__global__ void deg_count_kernel(const int* __restrict__ dst, int* __restrict__ deg, int E) {
  for (int e = blockIdx.x * blockDim.x + threadIdx.x; e < E; e += gridDim.x * blockDim.x)
    atomicAdd(&deg[dst[e]], 1);
}

__global__ void sum_chunks_kernel(const int* __restrict__ deg, int* __restrict__ chunksums, int N) {
  __shared__ int sd[256];
  int t = threadIdx.x;
  int base = blockIdx.x * 2048;
  int s = 0;
  for (int i = 0; i < 8; ++i) {
    int idx = base + t * 8 + i;
    if (idx < N) s += deg[idx];
  }
  sd[t] = s;
  __syncthreads();
  for (int o = 128; o > 0; o >>= 1) {
    if (t < o) sd[t] += sd[t + o];
    __syncthreads();
  }
  if (t == 0) chunksums[blockIdx.x] = sd[0];
}

__global__ void scan_sums_kernel(const int* __restrict__ chunksums, int* __restrict__ chunkoffs,
                                 int nchunks, int* __restrict__ rowptr, int N) {
  if (threadIdx.x == 0) {
    int acc = 0;
    for (int i = 0; i < nchunks; ++i) {
      chunkoffs[i] = acc;
      acc += chunksums[i];
    }
    rowptr[N] = acc;
  }
}

__global__ void scan_chunks_kernel(const int* __restrict__ deg, const int* __restrict__ chunkoffs,
                                   int* __restrict__ rowptr, int N) {
  __shared__ int sd[256];
  int t = threadIdx.x;
  int base = blockIdx.x * 2048;
  int vals[8];
  int s = 0;
  for (int i = 0; i < 8; ++i) {
    int idx = base + t * 8 + i;
    int d = (idx < N) ? deg[idx] : 0;
    vals[i] = s;
    s += d;
  }
  sd[t] = s;
  __syncthreads();
  int mytot = s;
  for (int o = 1; o < 256; o <<= 1) {
    int vprev = (t >= o) ? sd[t - o] : 0;
    __syncthreads();
    sd[t] += vprev;
    __syncthreads();
  }
  int texcl = sd[t] - mytot;
  int cb = chunkoffs[blockIdx.x];
  for (int i = 0; i < 8; ++i) {
    int idx = base + t * 8 + i;
    if (idx < N) rowptr[idx] = cb + texcl + vals[i];
  }
}

__global__ void scatter_kernel(const int* __restrict__ src, const int* __restrict__ dst,
                               const int* __restrict__ rowptr, int* __restrict__ fill,
                               int* __restrict__ sorted_src, int E) {
  for (int e = blockIdx.x * blockDim.x + threadIdx.x; e < E; e += gridDim.x * blockDim.x) {
    int d = dst[e];
    int pos = rowptr[d] + atomicAdd(&fill[d], 1);
    sorted_src[pos] = src[e];
  }
}

// ---------- 4. per-dst online softmax + aggregation; conv = agg + skip (bf16) ----------
__global__ __launch_bounds__(256) void attn_kernel(
    const unsigned short* __restrict__ q, const unsigned short* __restrict__ k,
    const unsigned short* __restrict__ v, const unsigned short* __restrict__ skp,
    const int* __restrict__ rowptr, const int* __restrict__ sorted_src,
    unsigned short* __restrict__ conv, int N) {
  int lane = threadIdx.x & 63;
  int n = blockIdx.x * 4 + (threadIdx.x >> 6);
  if (n >= N) return;
  int beg = rowptr[n], end = rowptr[n + 1];
  size_t rowb = (size_t)n * CH;
  int c0 = lane * 2;
  ushort2 q2 = *reinterpret_cast<const ushort2*>(q + rowb + c0);
  const float ASC = 0.17677669529663687f;  // 1/sqrt(32)
  float qf0 = bf2f(q2.x) * ASC;
  float qf1 = bf2f(q2.y) * ASC;
  float m = -INFINITY, ssum = 0.f, acc0 = 0.f, acc1 = 0.f;
  for (int e = beg; e < end; ++e) {
    int src = sorted_src[e];
    size_t sbase = (size_t)src * CH + c0;
    ushort2 k2 = *reinterpret_cast<const ushort2*>(k + sbase);
    ushort2 v2 = *reinterpret_cast<const ushort2*>(v + sbase);
    float p = qf0 * bf2f(k2.x) + qf1 * bf2f(k2.y);
#pragma unroll
    for (int msk = 8; msk > 0; msk >>= 1) p += __shfl_xor(p, msk, 16);
    float nm = fmaxf(m, p);
    float f = __expf(m - nm);
    float ex = __expf(p - nm);
    ssum = ssum * f + ex;
    acc0 = fmaf(acc0, f, ex * bf2f(v2.x));
    acc1 = fmaf(acc1, f, ex * bf2f(v2.y));
    m = nm;
  }
  float inv = (end > beg) ? 1.0f / ssum : 0.f;
  ushort2 s2 = *reinterpret_cast<const ushort2*>(skp + rowb + c0);
  ushort2 o;
  o.x = f2bf(acc0 * inv + bf2f(s2.x));
  o.y = f2bf(acc1 * inv + bf2f(s2.y));
  *reinterpret_cast<ushort2*>(conv + rowb + c0) = o;
}

// ---------- 5. out = conv @ Wfc + bfc + x via MFMA ----------
// block covers 64 rows; wave w handles nt in {2w, 2w+1} (32 cols)
__global__ __launch_bounds__(256) void final_mfma_kernel(
    const unsigned short* __restrict__ conv, const unsigned short* __restrict__ Wt,
    const float* __restrict__ bfc, const float* __restrict__ x,
    float* __restrict__ outp, int N) {
  __shared__ __align__(16) unsigned short As[64 * 128];
  int t = threadIdx.x;
  int lane = t & 63;
  int wid = t >> 6;
  size_t row0 = (size_t)blockIdx.x * 64;

  for (int i = 0; i < 4; ++i) {
    int c = i * 256 + t;
    int r = c >> 4;
    int kc = (c & 15) * 8;
    int4 pk = make_int4(0, 0, 0, 0);
    if (row0 + r < (size_t)N)
      pk = *reinterpret_cast<const int4*>(conv + (row0 + r) * CH + kc);
    int byte = (r * 256 + kc * 2) ^ ((r & 7) << 4);
    *reinterpret_cast<int4*>((char*)As + byte) = pk;
  }
  __syncthreads();

  const unsigned short* wt = Wt + ((size_t)4 << 14);
  int lr = lane & 15;
  int lg = lane >> 4;

  f32x4 acc[4][2];
#pragma unroll
  for (int mt = 0; mt < 4; ++mt)
#pragma unroll
    for (int i = 0; i < 2; ++i) acc[mt][i] = (f32x4){0.f, 0.f, 0.f, 0.f};

  for (int ks = 0; ks < 4; ++ks) {
    bf16x8 a[4], b[2];
#pragma unroll
    for (int mt = 0; mt < 4; ++mt) {
      int r = mt * 16 + lr;
      int byte = (r * 256 + (ks * 32 + lg * 8) * 2) ^ ((r & 7) << 4);
      a[mt] = *reinterpret_cast<const bf16x8*>((const char*)As + byte);
    }
#pragma unroll
    for (int i = 0; i < 2; ++i) {
      int n = (wid * 2 + i) * 16 + lr;
      b[i] = *reinterpret_cast<const bf16x8*>(wt + n * 128 + ks * 32 + lg * 8);
    }
#pragma unroll
    for (int mt = 0; mt < 4; ++mt)
#pragma unroll
      for (int i = 0; i < 2; ++i)
        acc[mt][i] = __builtin_amdgcn_mfma_f32_16x16x32_bf16(a[mt], b[i], acc[mt][i], 0, 0, 0);
  }

  float bf_[2];
#pragma unroll
  for (int i = 0; i < 2; ++i) bf_[i] = bfc[(wid * 2 + i) * 16 + lr];
#pragma unroll
  for (int mt = 0; mt < 4; ++mt) {
#pragma unroll
    for (int j = 0; j < 4; ++j) {
      size_t row = row0 + mt * 16 + lg * 4 + j;
      if (row < (size_t)N) {
#pragma unroll
        for (int i = 0; i < 2; ++i) {
          int col = (wid * 2 + i) * 16 + lr;
          outp[row * CH + col] = acc[mt][i][j] + bf_[i] + x[row * CH + col];
        }
      }
    }
  }
}

// ---------------------------------------------------------------
extern "C" void kernel_launch(void* const* d_in, const int* in_sizes, int n_in,
                              void* d_out, int out_size, void* d_ws, size_t ws_size,
                              hipStream_t stream) {
  const float* x = (const float*)d_in[0];
  const int* ei = (const int*)d_in[1];
  const float* gamma = (const float*)d_in[2];
  const float* beta = (const float*)d_in[3];
  const float* Wq = (const float*)d_in[4];
  const float* bq = (const float*)d_in[5];
  const float* Wk = (const float*)d_in[6];
  const float* bk = (const float*)d_in[7];
  const float* Wv = (const float*)d_in[8];
  const float* bv = (const float*)d_in[9];
  const float* Ws = (const float*)d_in[10];
  const float* bs = (const float*)d_in[11];
  const float* Wfc = (const float*)d_in[12];
  const float* bfc = (const float*)d_in[13];

  const int N = in_sizes[0] / CH;
  const int E = in_sizes[1] / 2;
  const int* srcp = ei;
  const int* dstp = ei + E;
  float* outp = (float*)d_out;

  char* wsb = (char*)d_ws;
  size_t off = 0;
  auto take = [&](size_t bytes) -> void* {
    void* p = wsb + off;
    off = (off + bytes + 255) & ~(size_t)255;
    return p;
  };
  float* stats = (float*)take(256 * 4);
  float* scsh = (float*)take(256 * 4);
  unsigned short* Wt = (unsigned short*)take((size_t)5 * 16384 * 2);
  unsigned short* qb = (unsigned short*)take((size_t)N * CH * 2);
  unsigned short* kb = (unsigned short*)take((size_t)N * CH * 2);
  unsigned short* vb = (unsigned short*)take((size_t)N * CH * 2);
  unsigned short* sb = (unsigned short*)take((size_t)N * CH * 2);
  unsigned short* convb = (unsigned short*)take((size_t)N * CH * 2);
  int* deg = (int*)take((size_t)N * 4);
  int* fill = (int*)take((size_t)N * 4);
  int* rowptr = (int*)take((size_t)(N + 1) * 4);
  int nchunks = (N + 2047) / 2048;
  int* chunksums = (int*)take((size_t)nchunks * 4);
  int* chunkoffs = (int*)take((size_t)nchunks * 4);
  int* sorted_src = (int*)take((size_t)E * 4);

  hipMemsetAsync(stats, 0, 256 * 4, stream);
  hipMemsetAsync(deg, 0, (size_t)N * 4, stream);
  hipMemsetAsync(fill, 0, (size_t)N * 4, stream);

  bn_stats_kernel<<<512, 256, 0, stream>>>(x, stats, N);
  bn_finalize_kernel<<<1, 128, 0, stream>>>(stats, gamma, beta, scsh, N);
  pack_w_kernel<<<320, 256, 0, stream>>>(Wq, Wk, Wv, Ws, Wfc, Wt);

  int nblk = (N + 63) / 64;
  proj_mfma_kernel<<<nblk, 256, 0, stream>>>(x, scsh, Wt, bq, bk, bv, bs, qb, kb, vb, sb, N);

  deg_count_kernel<<<2048, 256, 0, stream>>>(dstp, deg, E);
  sum_chunks_kernel<<<nchunks, 256, 0, stream>>>(deg, chunksums, N);
  scan_sums_kernel<<<1, 64, 0, stream>>>(chunksums, chunkoffs, nchunks, rowptr, N);
  scan_chunks_kernel<<<nchunks, 256, 0, stream>>>(deg, chunkoffs, rowptr, N);
  scatter_kernel<<<2048, 256, 0, stream>>>(srcp, dstp, rowptr, fill, sorted_src, E);

  attn_kernel<<<(N + 3) / 4, 256, 0, stream>>>(qb, kb, vb, sb, rowptr, sorted_src, convb, N);
  final_mfma_kernel<<<nblk, 256, 0, stream>>>(convb, Wt, bfc, x, outp, N);
}

// Round 3
// 448.675 us; speedup vs baseline: 1.6151x; 1.2109x over previous
//
#include <hip/hip_runtime.h>

#define CH 128  // channels = H*D = 4*32

typedef short bf16x8 __attribute__((ext_vector_type(8)));
typedef float f32x4 __attribute__((ext_vector_type(4)));
typedef _Float16 f16x2 __attribute__((ext_vector_type(2)));

// ---------- helpers ----------
static __device__ __forceinline__ float bf2f(unsigned short u) {
  union { unsigned int i; float f; } c;
  c.i = ((unsigned int)u) << 16;
  return c.f;
}
static __device__ __forceinline__ unsigned short f2bf(float f) {
  union { float f; unsigned int i; } c;
  c.f = f;
  unsigned int r = c.i + 0x7fffu + ((c.i >> 16) & 1u);  // RNE
  return (unsigned short)(r >> 16);
}
static __device__ __forceinline__ float hdot2(f16x2 a, f16x2 b, float c) {
#if __has_builtin(__builtin_amdgcn_fdot2)
  return __builtin_amdgcn_fdot2(a, b, c, false);
#else
  return c + (float)a[0] * (float)b[0] + (float)a[1] * (float)b[1];
#endif
}

// ---------- 1. BatchNorm statistics ----------
__global__ void bn_stats_kernel(const float* __restrict__ x, float* __restrict__ stats, int N) {
  int t = threadIdx.x;
  int ch = t & (CH - 1);
  int r0 = t >> 7;
  float s = 0.f, ss = 0.f;
  for (int row = blockIdx.x * 2 + r0; row < N; row += gridDim.x * 2) {
    float v = x[(size_t)row * CH + ch];
    s += v;
    ss += v * v;
  }
  atomicAdd(&stats[ch], s);
  atomicAdd(&stats[CH + ch], ss);
}

__global__ void bn_finalize_kernel(const float* __restrict__ stats,
                                   const float* __restrict__ gamma,
                                   const float* __restrict__ beta,
                                   float* __restrict__ scsh, int N) {
  int c = threadIdx.x;
  if (c < CH) {
    float inv_n = 1.0f / (float)N;
    float mu = stats[c] * inv_n;
    float var = stats[CH + c] * inv_n - mu * mu;
    float sc = gamma[c] * rsqrtf(var + 1e-5f);
    scsh[c] = sc;
    scsh[CH + c] = beta[c] - mu * sc;
  }
}

// ---------- 1b. pack weights: Wt[mat][n][k] bf16, mats = q,k,v,skip,fc ----------
__global__ void pack_w_kernel(const float* __restrict__ Wq, const float* __restrict__ Wk,
                              const float* __restrict__ Wv, const float* __restrict__ Ws,
                              const float* __restrict__ Wfc, unsigned short* __restrict__ Wt) {
  int el = blockIdx.x * 256 + threadIdx.x;  // 5*16384 elements
  int mat = el >> 14;
  int rem = el & 16383;
  int kk = rem >> 7;
  int n = rem & 127;
  const float* W = mat == 0 ? Wq : mat == 1 ? Wk : mat == 2 ? Wv : mat == 3 ? Ws : Wfc;
  Wt[((size_t)mat << 14) + n * 128 + kk] = f2bf(W[kk * 128 + n]);
}

// ---------- 2. fused BN+ReLU + 4 projections via MFMA (f16 out) ----------
__global__ __launch_bounds__(256, 2) void proj_mfma_kernel(
    const float* __restrict__ x, const float* __restrict__ scsh,
    const unsigned short* __restrict__ Wt,
    const float* __restrict__ bq_, const float* __restrict__ bk_,
    const float* __restrict__ bv_, const float* __restrict__ bs_,
    unsigned short* __restrict__ q, unsigned short* __restrict__ k,
    unsigned short* __restrict__ v, unsigned short* __restrict__ s_, int N) {
  __shared__ __align__(16) unsigned short As[64 * 128];  // 16KB, XOR-swizzled
  int t = threadIdx.x;
  int lane = t & 63;
  int wid = t >> 6;
  size_t row0 = (size_t)blockIdx.x * 64;

  for (int i = 0; i < 4; ++i) {
    int c = i * 256 + t;
    int r = c >> 4;
    int kc = (c & 15) * 8;
    float4 v0 = make_float4(0.f, 0.f, 0.f, 0.f), v1 = v0;
    if (row0 + r < (size_t)N) {
      const float* g = x + (row0 + r) * CH + kc;
      v0 = *reinterpret_cast<const float4*>(g);
      v1 = *reinterpret_cast<const float4*>(g + 4);
    }
    float4 sca = *reinterpret_cast<const float4*>(scsh + kc);
    float4 scb = *reinterpret_cast<const float4*>(scsh + kc + 4);
    float4 sha = *reinterpret_cast<const float4*>(scsh + CH + kc);
    float4 shb = *reinterpret_cast<const float4*>(scsh + CH + kc + 4);
    unsigned short h[8];
    h[0] = f2bf(fmaxf(fmaf(v0.x, sca.x, sha.x), 0.f));
    h[1] = f2bf(fmaxf(fmaf(v0.y, sca.y, sha.y), 0.f));
    h[2] = f2bf(fmaxf(fmaf(v0.z, sca.z, sha.z), 0.f));
    h[3] = f2bf(fmaxf(fmaf(v0.w, sca.w, sha.w), 0.f));
    h[4] = f2bf(fmaxf(fmaf(v1.x, scb.x, shb.x), 0.f));
    h[5] = f2bf(fmaxf(fmaf(v1.y, scb.y, shb.y), 0.f));
    h[6] = f2bf(fmaxf(fmaf(v1.z, scb.z, shb.z), 0.f));
    h[7] = f2bf(fmaxf(fmaf(v1.w, scb.w, shb.w), 0.f));
    int4 pk;
    pk.x = (int)h[0] | ((int)h[1] << 16);
    pk.y = (int)h[2] | ((int)h[3] << 16);
    pk.z = (int)h[4] | ((int)h[5] << 16);
    pk.w = (int)h[6] | ((int)h[7] << 16);
    int byte = (r * 256 + kc * 2) ^ ((r & 7) << 4);
    *reinterpret_cast<int4*>((char*)As + byte) = pk;
  }
  __syncthreads();

  const unsigned short* wt = Wt + ((size_t)wid << 14);
  const float* bias = wid == 0 ? bq_ : wid == 1 ? bk_ : wid == 2 ? bv_ : bs_;
  unsigned short* outp = wid == 0 ? q : wid == 1 ? k : wid == 2 ? v : s_;
  int lr = lane & 15;
  int lg = lane >> 4;

  f32x4 acc[4][8];
#pragma unroll
  for (int mt = 0; mt < 4; ++mt)
#pragma unroll
    for (int nt = 0; nt < 8; ++nt) acc[mt][nt] = (f32x4){0.f, 0.f, 0.f, 0.f};

  for (int ks = 0; ks < 4; ++ks) {
    bf16x8 a[4], b[8];
#pragma unroll
    for (int mt = 0; mt < 4; ++mt) {
      int r = mt * 16 + lr;
      int byte = (r * 256 + (ks * 32 + lg * 8) * 2) ^ ((r & 7) << 4);
      a[mt] = *reinterpret_cast<const bf16x8*>((const char*)As + byte);
    }
#pragma unroll
    for (int nt = 0; nt < 8; ++nt)
      b[nt] = *reinterpret_cast<const bf16x8*>(wt + (nt * 16 + lr) * 128 + ks * 32 + lg * 8);
#pragma unroll
    for (int mt = 0; mt < 4; ++mt)
#pragma unroll
      for (int nt = 0; nt < 8; ++nt)
        acc[mt][nt] = __builtin_amdgcn_mfma_f32_16x16x32_bf16(a[mt], b[nt], acc[mt][nt], 0, 0, 0);
  }

  float bn_[8];
#pragma unroll
  for (int nt = 0; nt < 8; ++nt) bn_[nt] = bias[nt * 16 + lr];
#pragma unroll
  for (int mt = 0; mt < 4; ++mt) {
#pragma unroll
    for (int j = 0; j < 4; ++j) {
      size_t row = row0 + mt * 16 + lg * 4 + j;
      if (row < (size_t)N) {
#pragma unroll
        for (int nt = 0; nt < 8; ++nt)
          outp[row * CH + nt * 16 + lr] =
              __builtin_bit_cast(unsigned short, (_Float16)(acc[mt][nt][j] + bn_[nt]));
      }
    }
  }
}

// ---------- 3. CSR build over dst ----------
__global__ void deg_count_kernel(const int* __restrict__ dst, int* __restrict__ deg, int E) {
  for (int e = blockIdx.x * blockDim.x + threadIdx.x; e < E; e += gridDim.x * blockDim.x)
    atomicAdd(&deg[dst[e]], 1);
}

__global__ void sum_chunks_kernel(const int* __restrict__ deg, int* __restrict__ chunksums, int N) {
  __shared__ int sd[256];
  int t = threadIdx.x;
  int base = blockIdx.x * 2048;
  int s = 0;
  for (int i = 0; i < 8; ++i) {
    int idx = base + t * 8 + i;
    if (idx < N) s += deg[idx];
  }
  sd[t] = s;
  __syncthreads();
  for (int o = 128; o > 0; o >>= 1) {
    if (t < o) sd[t] += sd[t + o];
    __syncthreads();
  }
  if (t == 0) chunksums[blockIdx.x] = sd[0];
}

__global__ void scan_sums_kernel(const int* __restrict__ chunksums, int* __restrict__ chunkoffs,
                                 int nchunks, int* __restrict__ rowptr, int N) {
  if (threadIdx.x == 0) {
    int acc = 0;
    for (int i = 0; i < nchunks; ++i) {
      chunkoffs[i] = acc;
      acc += chunksums[i];
    }
    rowptr[N] = acc;
  }
}

__global__ void scan_chunks_kernel(const int* __restrict__ deg, const int* __restrict__ chunkoffs,
                                   int* __restrict__ rowptr, int N) {
  __shared__ int sd[256];
  int t = threadIdx.x;
  int base = blockIdx.x * 2048;
  int vals[8];
  int s = 0;
  for (int i = 0; i < 8; ++i) {
    int idx = base + t * 8 + i;
    int d = (idx < N) ? deg[idx] : 0;
    vals[i] = s;
    s += d;
  }
  sd[t] = s;
  __syncthreads();
  int mytot = s;
  for (int o = 1; o < 256; o <<= 1) {
    int vprev = (t >= o) ? sd[t - o] : 0;
    __syncthreads();
    sd[t] += vprev;
    __syncthreads();
  }
  int texcl = sd[t] - mytot;
  int cb = chunkoffs[blockIdx.x];
  for (int i = 0; i < 8; ++i) {
    int idx = base + t * 8 + i;
    if (idx < N) rowptr[idx] = cb + texcl + vals[i];
  }
}

__global__ void scatter_kernel(const int* __restrict__ src, const int* __restrict__ dst,
                               const int* __restrict__ rowptr, int* __restrict__ fill,
                               int* __restrict__ sorted_src, int E) {
  for (int e = blockIdx.x * blockDim.x + threadIdx.x; e < E; e += gridDim.x * blockDim.x) {
    int d = dst[e];
    int pos = rowptr[d] + atomicAdd(&fill[d], 1);
    sorted_src[pos] = src[e];
  }
}

// ---------- 4. per-dst softmax (no max; range-safe) + aggregation ----------
// 1 wave per node (grid-stride). lane = (g = edge slot 0-3, s = sublane);
// sublane s owns channels 8s..8s+7; head = s>>2; 4 edges per iteration.
__global__ __launch_bounds__(256) void attn_kernel(
    const unsigned short* __restrict__ q, const unsigned short* __restrict__ k,
    const unsigned short* __restrict__ v, const unsigned short* __restrict__ skp,
    const int* __restrict__ rowptr, const int* __restrict__ sorted_src,
    unsigned short* __restrict__ conv, int N, int nw) {
  int lane = threadIdx.x & 63;
  int g = lane >> 4;
  int s = lane & 15;
  int w0 = blockIdx.x * (blockDim.x >> 6) + (threadIdx.x >> 6);
  const float ASC = 0.17677669529663687f;  // 1/sqrt(32)
  for (int n = w0; n < N; n += nw) {
    int beg = rowptr[n], end = rowptr[n + 1];
    size_t rowb = (size_t)n * CH + s * 8;
    uint4 qr = *reinterpret_cast<const uint4*>(q + rowb);
    f16x2 q0 = __builtin_bit_cast(f16x2, qr.x);
    f16x2 q1 = __builtin_bit_cast(f16x2, qr.y);
    f16x2 q2 = __builtin_bit_cast(f16x2, qr.z);
    f16x2 q3 = __builtin_bit_cast(f16x2, qr.w);
    float ssum = 0.f;
    f16x2 acc0 = {(_Float16)0.f, (_Float16)0.f};
    f16x2 acc1 = acc0, acc2 = acc0, acc3 = acc0;
    int nit = (end - beg + 3) >> 2;
    for (int it = 0; it < nit; ++it) {
      int e = beg + it * 4 + g;
      bool valid = e < end;
      int src = sorted_src[valid ? e : beg];
      size_t sb = (size_t)src * CH + s * 8;
      uint4 kr = *reinterpret_cast<const uint4*>(k + sb);
      uint4 vr = *reinterpret_cast<const uint4*>(v + sb);
      float p = hdot2(__builtin_bit_cast(f16x2, kr.x), q0, 0.f);
      p = hdot2(__builtin_bit_cast(f16x2, kr.y), q1, p);
      p = hdot2(__builtin_bit_cast(f16x2, kr.z), q2, p);
      p = hdot2(__builtin_bit_cast(f16x2, kr.w), q3, p);
      p += __shfl_xor(p, 1);
      p += __shfl_xor(p, 2);  // full head dot across 4 sublanes
      float ex = valid ? __expf(p * ASC) : 0.f;
      ssum += ex;
      _Float16 exh = (_Float16)ex;
      f16x2 e2 = {exh, exh};
      acc0 += e2 * __builtin_bit_cast(f16x2, vr.x);
      acc1 += e2 * __builtin_bit_cast(f16x2, vr.y);
      acc2 += e2 * __builtin_bit_cast(f16x2, vr.z);
      acc3 += e2 * __builtin_bit_cast(f16x2, vr.w);
    }
    // reduce across the 4 edge-slot groups (lanes ^16, ^32)
#pragma unroll
    for (int msk = 16; msk <= 32; msk <<= 1) {
      ssum += __shfl_xor(ssum, msk);
      acc0 = acc0 + __builtin_bit_cast(f16x2, __shfl_xor(__builtin_bit_cast(int, acc0), msk));
      acc1 = acc1 + __builtin_bit_cast(f16x2, __shfl_xor(__builtin_bit_cast(int, acc1), msk));
      acc2 = acc2 + __builtin_bit_cast(f16x2, __shfl_xor(__builtin_bit_cast(int, acc2), msk));
      acc3 = acc3 + __builtin_bit_cast(f16x2, __shfl_xor(__builtin_bit_cast(int, acc3), msk));
    }
    float inv = (end > beg) ? 1.0f / ssum : 0.f;
    uint4 sr = *reinterpret_cast<const uint4*>(skp + rowb);
    f16x2 sk0 = __builtin_bit_cast(f16x2, sr.x);
    f16x2 sk1 = __builtin_bit_cast(f16x2, sr.y);
    f16x2 sk2 = __builtin_bit_cast(f16x2, sr.z);
    f16x2 sk3 = __builtin_bit_cast(f16x2, sr.w);
    if (g == 0) {
      int4 pk;
      pk.x = (int)f2bf((float)acc0[0] * inv + (float)sk0[0]) |
             ((int)f2bf((float)acc0[1] * inv + (float)sk0[1]) << 16);
      pk.y = (int)f2bf((float)acc1[0] * inv + (float)sk1[0]) |
             ((int)f2bf((float)acc1[1] * inv + (float)sk1[1]) << 16);
      pk.z = (int)f2bf((float)acc2[0] * inv + (float)sk2[0]) |
             ((int)f2bf((float)acc2[1] * inv + (float)sk2[1]) << 16);
      pk.w = (int)f2bf((float)acc3[0] * inv + (float)sk3[0]) |
             ((int)f2bf((float)acc3[1] * inv + (float)sk3[1]) << 16);
      *reinterpret_cast<int4*>(conv + rowb) = pk;
    }
  }
}

// ---------- 5. out = conv @ Wfc + bfc + x via MFMA ----------
__global__ __launch_bounds__(256) void final_mfma_kernel(
    const unsigned short* __restrict__ conv, const unsigned short* __restrict__ Wt,
    const float* __restrict__ bfc, const float* __restrict__ x,
    float* __restrict__ outp, int N) {
  __shared__ __align__(16) unsigned short As[64 * 128];
  int t = threadIdx.x;
  int lane = t & 63;
  int wid = t >> 6;
  size_t row0 = (size_t)blockIdx.x * 64;

  for (int i = 0; i < 4; ++i) {
    int c = i * 256 + t;
    int r = c >> 4;
    int kc = (c & 15) * 8;
    int4 pk = make_int4(0, 0, 0, 0);
    if (row0 + r < (size_t)N)
      pk = *reinterpret_cast<const int4*>(conv + (row0 + r) * CH + kc);
    int byte = (r * 256 + kc * 2) ^ ((r & 7) << 4);
    *reinterpret_cast<int4*>((char*)As + byte) = pk;
  }
  __syncthreads();

  const unsigned short* wt = Wt + ((size_t)4 << 14);
  int lr = lane & 15;
  int lg = lane >> 4;

  f32x4 acc[4][2];
#pragma unroll
  for (int mt = 0; mt < 4; ++mt)
#pragma unroll
    for (int i = 0; i < 2; ++i) acc[mt][i] = (f32x4){0.f, 0.f, 0.f, 0.f};

  for (int ks = 0; ks < 4; ++ks) {
    bf16x8 a[4], b[2];
#pragma unroll
    for (int mt = 0; mt < 4; ++mt) {
      int r = mt * 16 + lr;
      int byte = (r * 256 + (ks * 32 + lg * 8) * 2) ^ ((r & 7) << 4);
      a[mt] = *reinterpret_cast<const bf16x8*>((const char*)As + byte);
    }
#pragma unroll
    for (int i = 0; i < 2; ++i) {
      int n = (wid * 2 + i) * 16 + lr;
      b[i] = *reinterpret_cast<const bf16x8*>(wt + n * 128 + ks * 32 + lg * 8);
    }
#pragma unroll
    for (int mt = 0; mt < 4; ++mt)
#pragma unroll
      for (int i = 0; i < 2; ++i)
        acc[mt][i] = __builtin_amdgcn_mfma_f32_16x16x32_bf16(a[mt], b[i], acc[mt][i], 0, 0, 0);
  }

  float bf_[2];
#pragma unroll
  for (int i = 0; i < 2; ++i) bf_[i] = bfc[(wid * 2 + i) * 16 + lr];
#pragma unroll
  for (int mt = 0; mt < 4; ++mt) {
#pragma unroll
    for (int j = 0; j < 4; ++j) {
      size_t row = row0 + mt * 16 + lg * 4 + j;
      if (row < (size_t)N) {
#pragma unroll
        for (int i = 0; i < 2; ++i) {
          int col = (wid * 2 + i) * 16 + lr;
          outp[row * CH + col] = acc[mt][i][j] + bf_[i] + x[row * CH + col];
        }
      }
    }
  }
}

// ---------------------------------------------------------------
extern "C" void kernel_launch(void* const* d_in, const int* in_sizes, int n_in,
                              void* d_out, int out_size, void* d_ws, size_t ws_size,
                              hipStream_t stream) {
  const float* x = (const float*)d_in[0];
  const int* ei = (const int*)d_in[1];
  const float* gamma = (const float*)d_in[2];
  const float* beta = (const float*)d_in[3];
  const float* Wq = (const float*)d_in[4];
  const float* bq = (const float*)d_in[5];
  const float* Wk = (const float*)d_in[6];
  const float* bk = (const float*)d_in[7];
  const float* Wv = (const float*)d_in[8];
  const float* bv = (const float*)d_in[9];
  const float* Ws = (const float*)d_in[10];
  const float* bs = (const float*)d_in[11];
  const float* Wfc = (const float*)d_in[12];
  const float* bfc = (const float*)d_in[13];

  const int N = in_sizes[0] / CH;
  const int E = in_sizes[1] / 2;
  const int* srcp = ei;
  const int* dstp = ei + E;
  float* outp = (float*)d_out;

  char* wsb = (char*)d_ws;
  size_t off = 0;
  auto take = [&](size_t bytes) -> void* {
    void* p = wsb + off;
    off = (off + bytes + 255) & ~(size_t)255;
    return p;
  };
  float* stats = (float*)take(256 * 4);
  float* scsh = (float*)take(256 * 4);
  unsigned short* Wt = (unsigned short*)take((size_t)5 * 16384 * 2);
  unsigned short* qb = (unsigned short*)take((size_t)N * CH * 2);
  unsigned short* kb = (unsigned short*)take((size_t)N * CH * 2);
  unsigned short* vb = (unsigned short*)take((size_t)N * CH * 2);
  unsigned short* sb = (unsigned short*)take((size_t)N * CH * 2);
  unsigned short* convb = (unsigned short*)take((size_t)N * CH * 2);
  int* deg = (int*)take((size_t)N * 4);
  int* fill = (int*)take((size_t)N * 4);
  int* rowptr = (int*)take((size_t)(N + 1) * 4);
  int nchunks = (N + 2047) / 2048;
  int* chunksums = (int*)take((size_t)nchunks * 4);
  int* chunkoffs = (int*)take((size_t)nchunks * 4);
  int* sorted_src = (int*)take((size_t)E * 4);

  hipMemsetAsync(stats, 0, 256 * 4, stream);
  hipMemsetAsync(deg, 0, (size_t)N * 4, stream);
  hipMemsetAsync(fill, 0, (size_t)N * 4, stream);

  bn_stats_kernel<<<512, 256, 0, stream>>>(x, stats, N);
  bn_finalize_kernel<<<1, 128, 0, stream>>>(stats, gamma, beta, scsh, N);
  pack_w_kernel<<<320, 256, 0, stream>>>(Wq, Wk, Wv, Ws, Wfc, Wt);

  int nblk = (N + 63) / 64;
  proj_mfma_kernel<<<nblk, 256, 0, stream>>>(x, scsh, Wt, bq, bk, bv, bs, qb, kb, vb, sb, N);

  deg_count_kernel<<<2048, 256, 0, stream>>>(dstp, deg, E);
  sum_chunks_kernel<<<nchunks, 256, 0, stream>>>(deg, chunksums, N);
  scan_sums_kernel<<<1, 64, 0, stream>>>(chunksums, chunkoffs, nchunks, rowptr, N);
  scan_chunks_kernel<<<nchunks, 256, 0, stream>>>(deg, chunkoffs, rowptr, N);
  scatter_kernel<<<2048, 256, 0, stream>>>(srcp, dstp, rowptr, fill, sorted_src, E);

  int ablocks = 4096;
  attn_kernel<<<ablocks, 256, 0, stream>>>(qb, kb, vb, sb, rowptr, sorted_src, convb, N,
                                           ablocks * 4);
  final_mfma_kernel<<<nblk, 256, 0, stream>>>(convb, Wt, bfc, x, outp, N);
}

// Round 5
// 413.032 us; speedup vs baseline: 1.7545x; 1.0863x over previous
//
#include <hip/hip_runtime.h>

#define CH 128  // channels = H*D = 4*32

typedef short bf16x8 __attribute__((ext_vector_type(8)));
typedef float f32x4 __attribute__((ext_vector_type(4)));
typedef float f32x2 __attribute__((ext_vector_type(2)));
typedef _Float16 f16x2 __attribute__((ext_vector_type(2)));

// ---------- helpers ----------
static __device__ __forceinline__ float bf2f(unsigned short u) {
  union { unsigned int i; float f; } c;
  c.i = ((unsigned int)u) << 16;
  return c.f;
}
static __device__ __forceinline__ unsigned short f2bf(float f) {
  union { float f; unsigned int i; } c;
  c.f = f;
  unsigned int r = c.i + 0x7fffu + ((c.i >> 16) & 1u);  // RNE
  return (unsigned short)(r >> 16);
}

// fp8 e4m3 fallbacks (used only if builtins are missing)
static __device__ float fp82f_sw(unsigned int b) {
  int sgn = (b >> 7) & 1;
  int e = (b >> 3) & 15;
  int m = b & 7;
  float v = e ? ldexpf(1.f + m * 0.125f, e - 7) : ldexpf((float)m, -9);
  return sgn ? -v : v;
}
static __device__ unsigned char f2fp8_sw(float f) {
  unsigned char s = (f < 0.f) ? 0x80 : 0;
  float af = fabsf(f);
  if (!(af < 448.f)) return s | 0x7e;
  int ex;
  frexpf(af, &ex);
  int e = ex - 1;
  if (e < -6) e = -6;
  float step = ldexpf(1.f, e - 3);
  float qq = rintf(af / step);
  if (qq >= 16.f) { qq = 8.f; e += 1; }
  if (e > 8) return s | 0x7e;
  unsigned char bits = (qq < 8.f) ? (unsigned char)qq
                                  : (unsigned char)(((e + 7) << 3) | ((int)qq - 8));
  return s | bits;
}
template <bool HI>
static __device__ __forceinline__ unsigned int pkfp8(float a, float b, unsigned int old) {
#if __has_builtin(__builtin_amdgcn_cvt_pk_fp8_f32)
  return (unsigned int)__builtin_amdgcn_cvt_pk_fp8_f32(a, b, (int)old, HI);
#else
  unsigned int w = ((unsigned)f2fp8_sw(a)) | (((unsigned)f2fp8_sw(b)) << 8);
  return HI ? ((old & 0x0000ffffu) | (w << 16)) : ((old & 0xffff0000u) | w);
#endif
}
template <bool HI>
static __device__ __forceinline__ f32x2 upkfp8(unsigned int src) {
#if __has_builtin(__builtin_amdgcn_cvt_pk_f32_fp8)
  return __builtin_amdgcn_cvt_pk_f32_fp8((int)src, HI);
#else
  unsigned int h = HI ? (src >> 16) : (src & 0xffffu);
  f32x2 r;
  r[0] = fp82f_sw(h & 0xff);
  r[1] = fp82f_sw((h >> 8) & 0xff);
  return r;
#endif
}

// ---------- 1. BatchNorm statistics ----------
__global__ void bn_stats_kernel(const float* __restrict__ x, float* __restrict__ stats, int N) {
  int t = threadIdx.x;
  int ch = t & (CH - 1);
  int r0 = t >> 7;
  float s = 0.f, ss = 0.f;
  for (int row = blockIdx.x * 2 + r0; row < N; row += gridDim.x * 2) {
    float v = x[(size_t)row * CH + ch];
    s += v;
    ss += v * v;
  }
  atomicAdd(&stats[ch], s);
  atomicAdd(&stats[CH + ch], ss);
}

__global__ void bn_finalize_kernel(const float* __restrict__ stats,
                                   const float* __restrict__ gamma,
                                   const float* __restrict__ beta,
                                   float* __restrict__ scsh, int N) {
  int c = threadIdx.x;
  if (c < CH) {
    float inv_n = 1.0f / (float)N;
    float mu = stats[c] * inv_n;
    float var = stats[CH + c] * inv_n - mu * mu;
    float sc = gamma[c] * rsqrtf(var + 1e-5f);
    scsh[c] = sc;
    scsh[CH + c] = beta[c] - mu * sc;
  }
}

// ---------- 1b. pack weights: Wt[mat][n][k] bf16, mats = q,k,v,skip,fc ----------
__global__ void pack_w_kernel(const float* __restrict__ Wq, const float* __restrict__ Wk,
                              const float* __restrict__ Wv, const float* __restrict__ Ws,
                              const float* __restrict__ Wfc, unsigned short* __restrict__ Wt) {
  int el = blockIdx.x * 256 + threadIdx.x;  // 5*16384 elements
  int mat = el >> 14;
  int rem = el & 16383;
  int kk = rem >> 7;
  int n = rem & 127;
  const float* W = mat == 0 ? Wq : mat == 1 ? Wk : mat == 2 ? Wv : mat == 3 ? Ws : Wfc;
  Wt[((size_t)mat << 14) + n * 128 + kk] = f2bf(W[kk * 128 + n]);
}

// ---------- 2. fused BN+ReLU + 4 projections via MFMA ----------
// Swapped-operand MFMA: lane holds 4 consecutive output channels of one node row.
// wave 0 -> q (f16), wave 1 -> k (fp8), wave 2 -> v (fp8), wave 3 -> skip (f16)
__global__ __launch_bounds__(256, 2) void proj_mfma_kernel(
    const float* __restrict__ x, const float* __restrict__ scsh,
    const unsigned short* __restrict__ Wt,
    const float* __restrict__ bq_, const float* __restrict__ bk_,
    const float* __restrict__ bv_, const float* __restrict__ bs_,
    unsigned short* __restrict__ q, unsigned char* __restrict__ k8,
    unsigned char* __restrict__ v8, unsigned short* __restrict__ s_, int N) {
  __shared__ __align__(16) unsigned short As[64 * 128];  // 16KB, XOR-swizzled
  int t = threadIdx.x;
  int lane = t & 63;
  int wid = t >> 6;
  size_t row0 = (size_t)blockIdx.x * 64;

  for (int i = 0; i < 4; ++i) {
    int c = i * 256 + t;
    int r = c >> 4;
    int kc = (c & 15) * 8;
    float4 v0 = make_float4(0.f, 0.f, 0.f, 0.f), v1 = v0;
    if (row0 + r < (size_t)N) {
      const float* g = x + (row0 + r) * CH + kc;
      v0 = *reinterpret_cast<const float4*>(g);
      v1 = *reinterpret_cast<const float4*>(g + 4);
    }
    float4 sca = *reinterpret_cast<const float4*>(scsh + kc);
    float4 scb = *reinterpret_cast<const float4*>(scsh + kc + 4);
    float4 sha = *reinterpret_cast<const float4*>(scsh + CH + kc);
    float4 shb = *reinterpret_cast<const float4*>(scsh + CH + kc + 4);
    unsigned short h[8];
    h[0] = f2bf(fmaxf(fmaf(v0.x, sca.x, sha.x), 0.f));
    h[1] = f2bf(fmaxf(fmaf(v0.y, sca.y, sha.y), 0.f));
    h[2] = f2bf(fmaxf(fmaf(v0.z, sca.z, sha.z), 0.f));
    h[3] = f2bf(fmaxf(fmaf(v0.w, sca.w, sha.w), 0.f));
    h[4] = f2bf(fmaxf(fmaf(v1.x, scb.x, shb.x), 0.f));
    h[5] = f2bf(fmaxf(fmaf(v1.y, scb.y, shb.y), 0.f));
    h[6] = f2bf(fmaxf(fmaf(v1.z, scb.z, shb.z), 0.f));
    h[7] = f2bf(fmaxf(fmaf(v1.w, scb.w, shb.w), 0.f));
    int4 pk;
    pk.x = (int)h[0] | ((int)h[1] << 16);
    pk.y = (int)h[2] | ((int)h[3] << 16);
    pk.z = (int)h[4] | ((int)h[5] << 16);
    pk.w = (int)h[6] | ((int)h[7] << 16);
    int byte = (r * 256 + kc * 2) ^ ((r & 7) << 4);
    *reinterpret_cast<int4*>((char*)As + byte) = pk;
  }
  __syncthreads();

  const unsigned short* wt = Wt + ((size_t)wid << 14);
  const float* bias = wid == 0 ? bq_ : wid == 1 ? bk_ : wid == 2 ? bv_ : bs_;
  int lr = lane & 15;
  int lg = lane >> 4;

  f32x4 acc[4][8];
#pragma unroll
  for (int mt = 0; mt < 4; ++mt)
#pragma unroll
    for (int nt = 0; nt < 8; ++nt) acc[mt][nt] = (f32x4){0.f, 0.f, 0.f, 0.f};

  for (int ks = 0; ks < 4; ++ks) {
    bf16x8 a[4], b[8];
#pragma unroll
    for (int mt = 0; mt < 4; ++mt) {
      int r = mt * 16 + lr;
      int byte = (r * 256 + (ks * 32 + lg * 8) * 2) ^ ((r & 7) << 4);
      a[mt] = *reinterpret_cast<const bf16x8*>((const char*)As + byte);
    }
#pragma unroll
    for (int nt = 0; nt < 8; ++nt)
      b[nt] = *reinterpret_cast<const bf16x8*>(wt + (nt * 16 + lr) * 128 + ks * 32 + lg * 8);
    // swapped operands: D[ch][node] -> lane holds node=lr, channels nt*16+lg*4+j
#pragma unroll
    for (int mt = 0; mt < 4; ++mt)
#pragma unroll
      for (int nt = 0; nt < 8; ++nt)
        acc[mt][nt] = __builtin_amdgcn_mfma_f32_16x16x32_bf16(b[nt], a[mt], acc[mt][nt], 0, 0, 0);
  }

  bool isfp8 = (wid == 1) || (wid == 2);
  unsigned short* o16 = (wid == 0) ? q : s_;
  unsigned char* o8 = (wid == 1) ? k8 : v8;
#pragma unroll
  for (int mt = 0; mt < 4; ++mt) {
    size_t row = row0 + mt * 16 + lr;
    if (row < (size_t)N) {
#pragma unroll
      for (int nt = 0; nt < 8; ++nt) {
        int cb = nt * 16 + lg * 4;
        float4 bb = *reinterpret_cast<const float4*>(bias + cb);
        float o0 = acc[mt][nt][0] + bb.x;
        float o1 = acc[mt][nt][1] + bb.y;
        float o2 = acc[mt][nt][2] + bb.z;
        float o3 = acc[mt][nt][3] + bb.w;
        if (isfp8) {
          unsigned int w = pkfp8<false>(o0, o1, 0u);
          w = pkfp8<true>(o2, o3, w);
          *reinterpret_cast<unsigned int*>(o8 + row * CH + cb) = w;
        } else {
          ushort4 u;
          u.x = __builtin_bit_cast(unsigned short, (_Float16)o0);
          u.y = __builtin_bit_cast(unsigned short, (_Float16)o1);
          u.z = __builtin_bit_cast(unsigned short, (_Float16)o2);
          u.w = __builtin_bit_cast(unsigned short, (_Float16)o3);
          *reinterpret_cast<ushort4*>(o16 + row * CH + cb) = u;
        }
      }
    }
  }
}

// ---------- 3. CSR build over dst ----------
__global__ void deg_count_kernel(const int* __restrict__ dst, int* __restrict__ deg, int E) {
  for (int e = blockIdx.x * blockDim.x + threadIdx.x; e < E; e += gridDim.x * blockDim.x)
    atomicAdd(&deg[dst[e]], 1);
}

__global__ void sum_chunks_kernel(const int* __restrict__ deg, int* __restrict__ chunksums, int N) {
  __shared__ int sd[256];
  int t = threadIdx.x;
  int base = blockIdx.x * 2048;
  int s = 0;
  for (int i = 0; i < 8; ++i) {
    int idx = base + t * 8 + i;
    if (idx < N) s += deg[idx];
  }
  sd[t] = s;
  __syncthreads();
  for (int o = 128; o > 0; o >>= 1) {
    if (t < o) sd[t] += sd[t + o];
    __syncthreads();
  }
  if (t == 0) chunksums[blockIdx.x] = sd[0];
}

__global__ void scan_sums_kernel(const int* __restrict__ chunksums, int* __restrict__ chunkoffs,
                                 int nchunks, int* __restrict__ rowptr, int N) {
  if (threadIdx.x == 0) {
    int acc = 0;
    for (int i = 0; i < nchunks; ++i) {
      chunkoffs[i] = acc;
      acc += chunksums[i];
    }
    rowptr[N] = acc;
  }
}

__global__ void scan_chunks_kernel(const int* __restrict__ deg, const int* __restrict__ chunkoffs,
                                   int* __restrict__ rowptr, int N) {
  __shared__ int sd[256];
  int t = threadIdx.x;
  int base = blockIdx.x * 2048;
  int vals[8];
  int s = 0;
  for (int i = 0; i < 8; ++i) {
    int idx = base + t * 8 + i;
    int d = (idx < N) ? deg[idx] : 0;
    vals[i] = s;
    s += d;
  }
  sd[t] = s;
  __syncthreads();
  int mytot = s;
  for (int o = 1; o < 256; o <<= 1) {
    int vprev = (t >= o) ? sd[t - o] : 0;
    __syncthreads();
    sd[t] += vprev;
    __syncthreads();
  }
  int texcl = sd[t] - mytot;
  int cb = chunkoffs[blockIdx.x];
  for (int i = 0; i < 8; ++i) {
    int idx = base + t * 8 + i;
    if (idx < N) rowptr[idx] = cb + texcl + vals[i];
  }
}

__global__ void scatter_kernel(const int* __restrict__ src, const int* __restrict__ dst,
                               const int* __restrict__ rowptr, int* __restrict__ fill,
                               int* __restrict__ sorted_src, int E) {
  for (int e = blockIdx.x * blockDim.x + threadIdx.x; e < E; e += gridDim.x * blockDim.x) {
    int d = dst[e];
    int pos = rowptr[d] + atomicAdd(&fill[d], 1);
    sorted_src[pos] = src[e];
  }
}

// ---------- 4. per-dst softmax (no max; range-safe) + aggregation; fp8 k/v ----------
// 1 wave per node (grid-stride). lane = (g = edge slot 0-3, s = sublane 0-15);
// sublane s owns channels 8s..8s+7; head = s>>2; 4 edges per iteration.
__global__ __launch_bounds__(256) void attn_kernel(
    const unsigned short* __restrict__ q, const unsigned char* __restrict__ k8,
    const unsigned char* __restrict__ v8, const unsigned short* __restrict__ skp,
    const int* __restrict__ rowptr, const int* __restrict__ sorted_src,
    unsigned short* __restrict__ conv, int N, int nw) {
  int lane = threadIdx.x & 63;
  int g = lane >> 4;
  int s = lane & 15;
  int w0 = blockIdx.x * (blockDim.x >> 6) + (threadIdx.x >> 6);
  const float ASC = 0.17677669529663687f;  // 1/sqrt(32)
  for (int n = w0; n < N; n += nw) {
    int beg = rowptr[n], end = rowptr[n + 1];
    size_t rowb = (size_t)n * CH + s * 8;
    uint4 qr = *reinterpret_cast<const uint4*>(q + rowb);
    float qf[8];
    {
      f16x2 t0 = __builtin_bit_cast(f16x2, qr.x);
      f16x2 t1 = __builtin_bit_cast(f16x2, qr.y);
      f16x2 t2 = __builtin_bit_cast(f16x2, qr.z);
      f16x2 t3 = __builtin_bit_cast(f16x2, qr.w);
      qf[0] = (float)t0[0] * ASC; qf[1] = (float)t0[1] * ASC;
      qf[2] = (float)t1[0] * ASC; qf[3] = (float)t1[1] * ASC;
      qf[4] = (float)t2[0] * ASC; qf[5] = (float)t2[1] * ASC;
      qf[6] = (float)t3[0] * ASC; qf[7] = (float)t3[1] * ASC;
    }
    float ssum = 0.f;
    float va[8] = {0.f, 0.f, 0.f, 0.f, 0.f, 0.f, 0.f, 0.f};
    int nit = (end - beg + 3) >> 2;
    for (int it = 0; it < nit; ++it) {
      int e = beg + it * 4 + g;
      bool valid = e < end;
      int src = sorted_src[valid ? e : beg];
      size_t sb = (size_t)src * CH + s * 8;
      uint2 kr = *reinterpret_cast<const uint2*>(k8 + sb);
      uint2 vr = *reinterpret_cast<const uint2*>(v8 + sb);
      f32x2 ka = upkfp8<false>(kr.x), kb_ = upkfp8<true>(kr.x);
      f32x2 kc = upkfp8<false>(kr.y), kd = upkfp8<true>(kr.y);
      float p = ka[0] * qf[0];
      p = fmaf(ka[1], qf[1], p);
      p = fmaf(kb_[0], qf[2], p);
      p = fmaf(kb_[1], qf[3], p);
      p = fmaf(kc[0], qf[4], p);
      p = fmaf(kc[1], qf[5], p);
      p = fmaf(kd[0], qf[6], p);
      p = fmaf(kd[1], qf[7], p);
      p += __shfl_xor(p, 1);
      p += __shfl_xor(p, 2);  // full 32-ch head dot
      float ex = valid ? __expf(p) : 0.f;
      ssum += ex;
      f32x2 va0 = upkfp8<false>(vr.x), va1 = upkfp8<true>(vr.x);
      f32x2 va2 = upkfp8<false>(vr.y), va3 = upkfp8<true>(vr.y);
      va[0] = fmaf(ex, va0[0], va[0]);
      va[1] = fmaf(ex, va0[1], va[1]);
      va[2] = fmaf(ex, va1[0], va[2]);
      va[3] = fmaf(ex, va1[1], va[3]);
      va[4] = fmaf(ex, va2[0], va[4]);
      va[5] = fmaf(ex, va2[1], va[5]);
      va[6] = fmaf(ex, va3[0], va[6]);
      va[7] = fmaf(ex, va3[1], va[7]);
    }
#pragma unroll
    for (int msk = 16; msk <= 32; msk <<= 1) {
      ssum += __shfl_xor(ssum, msk);
#pragma unroll
      for (int i = 0; i < 8; ++i) va[i] += __shfl_xor(va[i], msk);
    }
    float inv = (end > beg) ? 1.0f / ssum : 0.f;
    if (g == 0) {
      uint4 sr = *reinterpret_cast<const uint4*>(skp + rowb);
      f16x2 s0 = __builtin_bit_cast(f16x2, sr.x);
      f16x2 s1 = __builtin_bit_cast(f16x2, sr.y);
      f16x2 s2 = __builtin_bit_cast(f16x2, sr.z);
      f16x2 s3 = __builtin_bit_cast(f16x2, sr.w);
      int4 pk;
      pk.x = (int)f2bf(va[0] * inv + (float)s0[0]) | ((int)f2bf(va[1] * inv + (float)s0[1]) << 16);
      pk.y = (int)f2bf(va[2] * inv + (float)s1[0]) | ((int)f2bf(va[3] * inv + (float)s1[1]) << 16);
      pk.z = (int)f2bf(va[4] * inv + (float)s2[0]) | ((int)f2bf(va[5] * inv + (float)s2[1]) << 16);
      pk.w = (int)f2bf(va[6] * inv + (float)s3[0]) | ((int)f2bf(va[7] * inv + (float)s3[1]) << 16);
      *reinterpret_cast<int4*>(conv + rowb) = pk;
    }
  }
}

// ---------- 5. out = conv @ Wfc + bfc + x via MFMA (swapped; float4 epilogue) ----------
__global__ __launch_bounds__(256) void final_mfma_kernel(
    const unsigned short* __restrict__ conv, const unsigned short* __restrict__ Wt,
    const float* __restrict__ bfc, const float* __restrict__ x,
    float* __restrict__ outp, int N) {
  __shared__ __align__(16) unsigned short As[64 * 128];
  int t = threadIdx.x;
  int lane = t & 63;
  int wid = t >> 6;
  size_t row0 = (size_t)blockIdx.x * 64;

  for (int i = 0; i < 4; ++i) {
    int c = i * 256 + t;
    int r = c >> 4;
    int kc = (c & 15) * 8;
    int4 pk = make_int4(0, 0, 0, 0);
    if (row0 + r < (size_t)N)
      pk = *reinterpret_cast<const int4*>(conv + (row0 + r) * CH + kc);
    int byte = (r * 256 + kc * 2) ^ ((r & 7) << 4);
    *reinterpret_cast<int4*>((char*)As + byte) = pk;
  }
  __syncthreads();

  const unsigned short* wt = Wt + ((size_t)4 << 14);
  int lr = lane & 15;
  int lg = lane >> 4;

  f32x4 acc[4][2];
#pragma unroll
  for (int mt = 0; mt < 4; ++mt)
#pragma unroll
    for (int i = 0; i < 2; ++i) acc[mt][i] = (f32x4){0.f, 0.f, 0.f, 0.f};

  for (int ks = 0; ks < 4; ++ks) {
    bf16x8 a[4], b[2];
#pragma unroll
    for (int mt = 0; mt < 4; ++mt) {
      int r = mt * 16 + lr;
      int byte = (r * 256 + (ks * 32 + lg * 8) * 2) ^ ((r & 7) << 4);
      a[mt] = *reinterpret_cast<const bf16x8*>((const char*)As + byte);
    }
#pragma unroll
    for (int i = 0; i < 2; ++i) {
      int n = (wid * 2 + i) * 16 + lr;
      b[i] = *reinterpret_cast<const bf16x8*>(wt + n * 128 + ks * 32 + lg * 8);
    }
#pragma unroll
    for (int mt = 0; mt < 4; ++mt)
#pragma unroll
      for (int i = 0; i < 2; ++i)
        acc[mt][i] = __builtin_amdgcn_mfma_f32_16x16x32_bf16(b[i], a[mt], acc[mt][i], 0, 0, 0);
  }

#pragma unroll
  for (int mt = 0; mt < 4; ++mt) {
    size_t row = row0 + mt * 16 + lr;
    if (row < (size_t)N) {
#pragma unroll
      for (int i = 0; i < 2; ++i) {
        int cb = (wid * 2 + i) * 16 + lg * 4;
        float4 bb = *reinterpret_cast<const float4*>(bfc + cb);
        float4 rx = *reinterpret_cast<const float4*>(x + row * CH + cb);
        float4 o;
        o.x = acc[mt][i][0] + bb.x + rx.x;
        o.y = acc[mt][i][1] + bb.y + rx.y;
        o.z = acc[mt][i][2] + bb.z + rx.z;
        o.w = acc[mt][i][3] + bb.w + rx.w;
        *reinterpret_cast<float4*>(outp + row * CH + cb) = o;
      }
    }
  }
}

// ---------------------------------------------------------------
extern "C" void kernel_launch(void* const* d_in, const int* in_sizes, int n_in,
                              void* d_out, int out_size, void* d_ws, size_t ws_size,
                              hipStream_t stream) {
  const float* x = (const float*)d_in[0];
  const int* ei = (const int*)d_in[1];
  const float* gamma = (const float*)d_in[2];
  const float* beta = (const float*)d_in[3];
  const float* Wq = (const float*)d_in[4];
  const float* bq = (const float*)d_in[5];
  const float* Wk = (const float*)d_in[6];
  const float* bk = (const float*)d_in[7];
  const float* Wv = (const float*)d_in[8];
  const float* bv = (const float*)d_in[9];
  const float* Ws = (const float*)d_in[10];
  const float* bs = (const float*)d_in[11];
  const float* Wfc = (const float*)d_in[12];
  const float* bfc = (const float*)d_in[13];

  const int N = in_sizes[0] / CH;
  const int E = in_sizes[1] / 2;
  const int* srcp = ei;
  const int* dstp = ei + E;
  float* outp = (float*)d_out;

  char* wsb = (char*)d_ws;
  size_t off = 0;
  auto take = [&](size_t bytes) -> void* {
    void* p = wsb + off;
    off = (off + bytes + 255) & ~(size_t)255;
    return p;
  };
  float* stats = (float*)take(256 * 4);
  float* scsh = (float*)take(256 * 4);
  unsigned short* Wt = (unsigned short*)take((size_t)5 * 16384 * 2);
  unsigned short* qb = (unsigned short*)take((size_t)N * CH * 2);
  unsigned char* kb8 = (unsigned char*)take((size_t)N * CH);
  unsigned char* vb8 = (unsigned char*)take((size_t)N * CH);
  unsigned short* sb = (unsigned short*)take((size_t)N * CH * 2);
  unsigned short* convb = (unsigned short*)take((size_t)N * CH * 2);
  int* deg = (int*)take((size_t)N * 4);
  int* fill = (int*)take((size_t)N * 4);
  int* rowptr = (int*)take((size_t)(N + 1) * 4);
  int nchunks = (N + 2047) / 2048;
  int* chunksums = (int*)take((size_t)nchunks * 4);
  int* chunkoffs = (int*)take((size_t)nchunks * 4);
  int* sorted_src = (int*)take((size_t)E * 4);

  hipMemsetAsync(stats, 0, 256 * 4, stream);
  hipMemsetAsync(deg, 0, (size_t)N * 4, stream);
  hipMemsetAsync(fill, 0, (size_t)N * 4, stream);

  bn_stats_kernel<<<512, 256, 0, stream>>>(x, stats, N);
  bn_finalize_kernel<<<1, 128, 0, stream>>>(stats, gamma, beta, scsh, N);
  pack_w_kernel<<<320, 256, 0, stream>>>(Wq, Wk, Wv, Ws, Wfc, Wt);

  int nblk = (N + 63) / 64;
  proj_mfma_kernel<<<nblk, 256, 0, stream>>>(x, scsh, Wt, bq, bk, bv, bs, qb, kb8, vb8, sb, N);

  deg_count_kernel<<<2048, 256, 0, stream>>>(dstp, deg, E);
  sum_chunks_kernel<<<nchunks, 256, 0, stream>>>(deg, chunksums, N);
  scan_sums_kernel<<<1, 64, 0, stream>>>(chunksums, chunkoffs, nchunks, rowptr, N);
  scan_chunks_kernel<<<nchunks, 256, 0, stream>>>(deg, chunkoffs, rowptr, N);
  scatter_kernel<<<2048, 256, 0, stream>>>(srcp, dstp, rowptr, fill, sorted_src, E);

  int ablocks = 4096;
  attn_kernel<<<ablocks, 256, 0, stream>>>(qb, kb8, vb8, sb, rowptr, sorted_src, convb, N,
                                           ablocks * 4);
  final_mfma_kernel<<<nblk, 256, 0, stream>>>(convb, Wt, bfc, x, outp, N);
}

// Round 8
// 346.029 us; speedup vs baseline: 2.0943x; 1.1936x over previous
//
#include <hip/hip_runtime.h>

#define CH 128  // channels = H*D = 4*32

typedef short bf16x8 __attribute__((ext_vector_type(8)));
typedef float f32x4 __attribute__((ext_vector_type(4)));
typedef float f32x2 __attribute__((ext_vector_type(2)));
typedef _Float16 f16x2 __attribute__((ext_vector_type(2)));

// ---------- helpers ----------
static __device__ __forceinline__ float bf2f(unsigned short u) {
  union { unsigned int i; float f; } c;
  c.i = ((unsigned int)u) << 16;
  return c.f;
}
static __device__ __forceinline__ unsigned short f2bf(float f) {
  union { float f; unsigned int i; } c;
  c.f = f;
  unsigned int r = c.i + 0x7fffu + ((c.i >> 16) & 1u);  // RNE
  return (unsigned short)(r >> 16);
}

// fp8 e4m3 fallbacks (used only if builtins are missing)
static __device__ float fp82f_sw(unsigned int b) {
  int sgn = (b >> 7) & 1;
  int e = (b >> 3) & 15;
  int m = b & 7;
  float v = e ? ldexpf(1.f + m * 0.125f, e - 7) : ldexpf((float)m, -9);
  return sgn ? -v : v;
}
static __device__ unsigned char f2fp8_sw(float f) {
  unsigned char s = (f < 0.f) ? 0x80 : 0;
  float af = fabsf(f);
  if (!(af < 448.f)) return s | 0x7e;
  int ex;
  frexpf(af, &ex);
  int e = ex - 1;
  if (e < -6) e = -6;
  float step = ldexpf(1.f, e - 3);
  float qq = rintf(af / step);
  if (qq >= 16.f) { qq = 8.f; e += 1; }
  if (e > 8) return s | 0x7e;
  unsigned char bits = (qq < 8.f) ? (unsigned char)qq
                                  : (unsigned char)(((e + 7) << 3) | ((int)qq - 8));
  return s | bits;
}
template <bool HI>
static __device__ __forceinline__ unsigned int pkfp8(float a, float b, unsigned int old) {
#if __has_builtin(__builtin_amdgcn_cvt_pk_fp8_f32)
  return (unsigned int)__builtin_amdgcn_cvt_pk_fp8_f32(a, b, (int)old, HI);
#else
  unsigned int w = ((unsigned)f2fp8_sw(a)) | (((unsigned)f2fp8_sw(b)) << 8);
  return HI ? ((old & 0x0000ffffu) | (w << 16)) : ((old & 0xffff0000u) | w);
#endif
}
template <bool HI>
static __device__ __forceinline__ f32x2 upkfp8(unsigned int src) {
#if __has_builtin(__builtin_amdgcn_cvt_pk_f32_fp8)
  return __builtin_amdgcn_cvt_pk_f32_fp8((int)src, HI);
#else
  unsigned int h = HI ? (src >> 16) : (src & 0xffffu);
  f32x2 r;
  r[0] = fp82f_sw(h & 0xff);
  r[1] = fp82f_sw((h >> 8) & 0xff);
  return r;
#endif
}

// ---------- 1. BatchNorm statistics ----------
__global__ void bn_stats_kernel(const float* __restrict__ x, float* __restrict__ stats, int N) {
  int t = threadIdx.x;
  int ch = t & (CH - 1);
  int r0 = t >> 7;
  float s = 0.f, ss = 0.f;
  for (int row = blockIdx.x * 2 + r0; row < N; row += gridDim.x * 2) {
    float v = x[(size_t)row * CH + ch];
    s += v;
    ss += v * v;
  }
  atomicAdd(&stats[ch], s);
  atomicAdd(&stats[CH + ch], ss);
}

__global__ void bn_finalize_kernel(const float* __restrict__ stats,
                                   const float* __restrict__ gamma,
                                   const float* __restrict__ beta,
                                   float* __restrict__ scsh, int N) {
  int c = threadIdx.x;
  if (c < CH) {
    float inv_n = 1.0f / (float)N;
    float mu = stats[c] * inv_n;
    float var = stats[CH + c] * inv_n - mu * mu;
    float sc = gamma[c] * rsqrtf(var + 1e-5f);
    scsh[c] = sc;
    scsh[CH + c] = beta[c] - mu * sc;
  }
}

// ---------- 1b. pack weights: Wt[mat][n][k] bf16, mats = q,k,v,skip,fc ----------
__global__ void pack_w_kernel(const float* __restrict__ Wq, const float* __restrict__ Wk,
                              const float* __restrict__ Wv, const float* __restrict__ Ws,
                              const float* __restrict__ Wfc, unsigned short* __restrict__ Wt) {
  int el = blockIdx.x * 256 + threadIdx.x;  // 5*16384 elements
  int mat = el >> 14;
  int rem = el & 16383;
  int kk = rem >> 7;
  int n = rem & 127;
  const float* W = mat == 0 ? Wq : mat == 1 ? Wk : mat == 2 ? Wv : mat == 3 ? Ws : Wfc;
  Wt[((size_t)mat << 14) + n * 128 + kk] = f2bf(W[kk * 128 + n]);
}

// ---------- 2. fused BN+ReLU + 4 projections via MFMA ----------
// Swapped-operand MFMA: lane holds 4 consecutive output channels of one node row.
// wave 0 -> q (f16), wave 1 -> k (fp8), wave 2 -> v (fp8), wave 3 -> skip (f16)
__global__ __launch_bounds__(256, 2) void proj_mfma_kernel(
    const float* __restrict__ x, const float* __restrict__ scsh,
    const unsigned short* __restrict__ Wt,
    const float* __restrict__ bq_, const float* __restrict__ bk_,
    const float* __restrict__ bv_, const float* __restrict__ bs_,
    unsigned short* __restrict__ q, unsigned char* __restrict__ k8,
    unsigned char* __restrict__ v8, unsigned short* __restrict__ s_, int N) {
  __shared__ __align__(16) unsigned short As[64 * 128];  // 16KB, XOR-swizzled
  int t = threadIdx.x;
  int lane = t & 63;
  int wid = t >> 6;
  size_t row0 = (size_t)blockIdx.x * 64;

  for (int i = 0; i < 4; ++i) {
    int c = i * 256 + t;
    int r = c >> 4;
    int kc = (c & 15) * 8;
    float4 v0 = make_float4(0.f, 0.f, 0.f, 0.f), v1 = v0;
    if (row0 + r < (size_t)N) {
      const float* g = x + (row0 + r) * CH + kc;
      v0 = *reinterpret_cast<const float4*>(g);
      v1 = *reinterpret_cast<const float4*>(g + 4);
    }
    float4 sca = *reinterpret_cast<const float4*>(scsh + kc);
    float4 scb = *reinterpret_cast<const float4*>(scsh + kc + 4);
    float4 sha = *reinterpret_cast<const float4*>(scsh + CH + kc);
    float4 shb = *reinterpret_cast<const float4*>(scsh + CH + kc + 4);
    unsigned short h[8];
    h[0] = f2bf(fmaxf(fmaf(v0.x, sca.x, sha.x), 0.f));
    h[1] = f2bf(fmaxf(fmaf(v0.y, sca.y, sha.y), 0.f));
    h[2] = f2bf(fmaxf(fmaf(v0.z, sca.z, sha.z), 0.f));
    h[3] = f2bf(fmaxf(fmaf(v0.w, sca.w, sha.w), 0.f));
    h[4] = f2bf(fmaxf(fmaf(v1.x, scb.x, shb.x), 0.f));
    h[5] = f2bf(fmaxf(fmaf(v1.y, scb.y, shb.y), 0.f));
    h[6] = f2bf(fmaxf(fmaf(v1.z, scb.z, shb.z), 0.f));
    h[7] = f2bf(fmaxf(fmaf(v1.w, scb.w, shb.w), 0.f));
    int4 pk;
    pk.x = (int)h[0] | ((int)h[1] << 16);
    pk.y = (int)h[2] | ((int)h[3] << 16);
    pk.z = (int)h[4] | ((int)h[5] << 16);
    pk.w = (int)h[6] | ((int)h[7] << 16);
    int byte = (r * 256 + kc * 2) ^ ((r & 7) << 4);
    *reinterpret_cast<int4*>((char*)As + byte) = pk;
  }
  __syncthreads();

  const unsigned short* wt = Wt + ((size_t)wid << 14);
  const float* bias = wid == 0 ? bq_ : wid == 1 ? bk_ : wid == 2 ? bv_ : bs_;
  int lr = lane & 15;
  int lg = lane >> 4;

  f32x4 acc[4][8];
#pragma unroll
  for (int mt = 0; mt < 4; ++mt)
#pragma unroll
    for (int nt = 0; nt < 8; ++nt) acc[mt][nt] = (f32x4){0.f, 0.f, 0.f, 0.f};

  for (int ks = 0; ks < 4; ++ks) {
    bf16x8 a[4], b[8];
#pragma unroll
    for (int mt = 0; mt < 4; ++mt) {
      int r = mt * 16 + lr;
      int byte = (r * 256 + (ks * 32 + lg * 8) * 2) ^ ((r & 7) << 4);
      a[mt] = *reinterpret_cast<const bf16x8*>((const char*)As + byte);
    }
#pragma unroll
    for (int nt = 0; nt < 8; ++nt)
      b[nt] = *reinterpret_cast<const bf16x8*>(wt + (nt * 16 + lr) * 128 + ks * 32 + lg * 8);
    // swapped operands: D[ch][node] -> lane holds node=lr, channels nt*16+lg*4+j
#pragma unroll
    for (int mt = 0; mt < 4; ++mt)
#pragma unroll
      for (int nt = 0; nt < 8; ++nt)
        acc[mt][nt] = __builtin_amdgcn_mfma_f32_16x16x32_bf16(b[nt], a[mt], acc[mt][nt], 0, 0, 0);
  }

  bool isfp8 = (wid == 1) || (wid == 2);
  unsigned short* o16 = (wid == 0) ? q : s_;
  unsigned char* o8 = (wid == 1) ? k8 : v8;
#pragma unroll
  for (int mt = 0; mt < 4; ++mt) {
    size_t row = row0 + mt * 16 + lr;
    if (row < (size_t)N) {
#pragma unroll
      for (int nt = 0; nt < 8; ++nt) {
        int cb = nt * 16 + lg * 4;
        float4 bb = *reinterpret_cast<const float4*>(bias + cb);
        float o0 = acc[mt][nt][0] + bb.x;
        float o1 = acc[mt][nt][1] + bb.y;
        float o2 = acc[mt][nt][2] + bb.z;
        float o3 = acc[mt][nt][3] + bb.w;
        if (isfp8) {
          unsigned int w = pkfp8<false>(o0, o1, 0u);
          w = pkfp8<true>(o2, o3, w);
          *reinterpret_cast<unsigned int*>(o8 + row * CH + cb) = w;
        } else {
          ushort4 u;
          u.x = __builtin_bit_cast(unsigned short, (_Float16)o0);
          u.y = __builtin_bit_cast(unsigned short, (_Float16)o1);
          u.z = __builtin_bit_cast(unsigned short, (_Float16)o2);
          u.w = __builtin_bit_cast(unsigned short, (_Float16)o3);
          *reinterpret_cast<ushort4*>(o16 + row * CH + cb) = u;
        }
      }
    }
  }
}

// ---------- 3. CSR build over dst (rank trick: deg_rank then atomic-free scatter) ----------
__global__ void deg_rank_kernel(const int* __restrict__ dst, int* __restrict__ deg,
                                int* __restrict__ rank, int E) {
  for (int e = blockIdx.x * blockDim.x + threadIdx.x; e < E; e += gridDim.x * blockDim.x) {
    rank[e] = atomicAdd(&deg[dst[e]], 1);
  }
}

__global__ void sum_chunks_kernel(const int* __restrict__ deg, int* __restrict__ chunksums, int N) {
  __shared__ int sd[256];
  int t = threadIdx.x;
  int base = blockIdx.x * 2048;
  int s = 0;
  for (int i = 0; i < 8; ++i) {
    int idx = base + t * 8 + i;
    if (idx < N) s += deg[idx];
  }
  sd[t] = s;
  __syncthreads();
  for (int o = 128; o > 0; o >>= 1) {
    if (t < o) sd[t] += sd[t + o];
    __syncthreads();
  }
  if (t == 0) chunksums[blockIdx.x] = sd[0];
}

__global__ void scan_sums_kernel(const int* __restrict__ chunksums, int* __restrict__ chunkoffs,
                                 int nchunks, int* __restrict__ rowptr, int N) {
  if (threadIdx.x == 0) {
    int acc = 0;
    for (int i = 0; i < nchunks; ++i) {
      chunkoffs[i] = acc;
      acc += chunksums[i];
    }
    rowptr[N] = acc;
  }
}

__global__ void scan_chunks_kernel(const int* __restrict__ deg, const int* __restrict__ chunkoffs,
                                   int* __restrict__ rowptr, int N) {
  __shared__ int sd[256];
  int t = threadIdx.x;
  int base = blockIdx.x * 2048;
  int vals[8];
  int s = 0;
  for (int i = 0; i < 8; ++i) {
    int idx = base + t * 8 + i;
    int d = (idx < N) ? deg[idx] : 0;
    vals[i] = s;
    s += d;
  }
  sd[t] = s;
  __syncthreads();
  int mytot = s;
  for (int o = 1; o < 256; o <<= 1) {
    int vprev = (t >= o) ? sd[t - o] : 0;
    __syncthreads();
    sd[t] += vprev;
    __syncthreads();
  }
  int texcl = sd[t] - mytot;
  int cb = chunkoffs[blockIdx.x];
  for (int i = 0; i < 8; ++i) {
    int idx = base + t * 8 + i;
    if (idx < N) rowptr[idx] = cb + texcl + vals[i];
  }
}

__global__ void scatter_kernel(const int* __restrict__ src, const int* __restrict__ dst,
                               const int* __restrict__ rowptr, const int* __restrict__ rank,
                               int* __restrict__ sorted_src, int E) {
  for (int e = blockIdx.x * blockDim.x + threadIdx.x; e < E; e += gridDim.x * blockDim.x) {
    int d = dst[e];
    int pos = rowptr[d] + rank[e];
    sorted_src[pos] = src[e];
  }
}

// ---------- 4. per-dst softmax (no max; range-safe) + aggregation; fp8 k/v ----------
// 1 wave per node (grid-stride). lane = (g = edge slot 0-3, s = sublane 0-15);
// sublane s owns channels 8s..8s+7; head = s>>2; 4 edges per iteration.
__global__ __launch_bounds__(256) void attn_kernel(
    const unsigned short* __restrict__ q, const unsigned char* __restrict__ k8,
    const unsigned char* __restrict__ v8, const unsigned short* __restrict__ skp,
    const int* __restrict__ rowptr, const int* __restrict__ sorted_src,
    unsigned short* __restrict__ conv, int N, int nw) {
  int lane = threadIdx.x & 63;
  int g = lane >> 4;
  int s = lane & 15;
  int w0 = blockIdx.x * (blockDim.x >> 6) + (threadIdx.x >> 6);
  const float ASC = 0.17677669529663687f;  // 1/sqrt(32)
  for (int n = w0; n < N; n += nw) {
    int beg = rowptr[n], end = rowptr[n + 1];
    size_t rowb = (size_t)n * CH + s * 8;
    uint4 qr = *reinterpret_cast<const uint4*>(q + rowb);
    float qf[8];
    {
      f16x2 t0 = __builtin_bit_cast(f16x2, qr.x);
      f16x2 t1 = __builtin_bit_cast(f16x2, qr.y);
      f16x2 t2 = __builtin_bit_cast(f16x2, qr.z);
      f16x2 t3 = __builtin_bit_cast(f16x2, qr.w);
      qf[0] = (float)t0[0] * ASC; qf[1] = (float)t0[1] * ASC;
      qf[2] = (float)t1[0] * ASC; qf[3] = (float)t1[1] * ASC;
      qf[4] = (float)t2[0] * ASC; qf[5] = (float)t2[1] * ASC;
      qf[6] = (float)t3[0] * ASC; qf[7] = (float)t3[1] * ASC;
    }
    float ssum = 0.f;
    float va[8] = {0.f, 0.f, 0.f, 0.f, 0.f, 0.f, 0.f, 0.f};
    int nit = (end - beg + 3) >> 2;
    for (int it = 0; it < nit; ++it) {
      int e = beg + it * 4 + g;
      bool valid = e < end;
      int src = sorted_src[valid ? e : beg];
      size_t sb = (size_t)src * CH + s * 8;
      uint2 kr = *reinterpret_cast<const uint2*>(k8 + sb);
      uint2 vr = *reinterpret_cast<const uint2*>(v8 + sb);
      f32x2 ka = upkfp8<false>(kr.x), kb_ = upkfp8<true>(kr.x);
      f32x2 kc = upkfp8<false>(kr.y), kd = upkfp8<true>(kr.y);
      float p = ka[0] * qf[0];
      p = fmaf(ka[1], qf[1], p);
      p = fmaf(kb_[0], qf[2], p);
      p = fmaf(kb_[1], qf[3], p);
      p = fmaf(kc[0], qf[4], p);
      p = fmaf(kc[1], qf[5], p);
      p = fmaf(kd[0], qf[6], p);
      p = fmaf(kd[1], qf[7], p);
      p += __shfl_xor(p, 1);
      p += __shfl_xor(p, 2);  // full 32-ch head dot
      float ex = valid ? __expf(p) : 0.f;
      ssum += ex;
      f32x2 va0 = upkfp8<false>(vr.x), va1 = upkfp8<true>(vr.x);
      f32x2 va2 = upkfp8<false>(vr.y), va3 = upkfp8<true>(vr.y);
      va[0] = fmaf(ex, va0[0], va[0]);
      va[1] = fmaf(ex, va0[1], va[1]);
      va[2] = fmaf(ex, va1[0], va[2]);
      va[3] = fmaf(ex, va1[1], va[3]);
      va[4] = fmaf(ex, va2[0], va[4]);
      va[5] = fmaf(ex, va2[1], va[5]);
      va[6] = fmaf(ex, va3[0], va[6]);
      va[7] = fmaf(ex, va3[1], va[7]);
    }
#pragma unroll
    for (int msk = 16; msk <= 32; msk <<= 1) {
      ssum += __shfl_xor(ssum, msk);
#pragma unroll
      for (int i = 0; i < 8; ++i) va[i] += __shfl_xor(va[i], msk);
    }
    float inv = (end > beg) ? 1.0f / ssum : 0.f;
    if (g == 0) {
      uint4 sr = *reinterpret_cast<const uint4*>(skp + rowb);
      f16x2 s0 = __builtin_bit_cast(f16x2, sr.x);
      f16x2 s1 = __builtin_bit_cast(f16x2, sr.y);
      f16x2 s2 = __builtin_bit_cast(f16x2, sr.z);
      f16x2 s3 = __builtin_bit_cast(f16x2, sr.w);
      int4 pk;
      pk.x = (int)f2bf(va[0] * inv + (float)s0[0]) | ((int)f2bf(va[1] * inv + (float)s0[1]) << 16);
      pk.y = (int)f2bf(va[2] * inv + (float)s1[0]) | ((int)f2bf(va[3] * inv + (float)s1[1]) << 16);
      pk.z = (int)f2bf(va[4] * inv + (float)s2[0]) | ((int)f2bf(va[5] * inv + (float)s2[1]) << 16);
      pk.w = (int)f2bf(va[6] * inv + (float)s3[0]) | ((int)f2bf(va[7] * inv + (float)s3[1]) << 16);
      *reinterpret_cast<int4*>(conv + rowb) = pk;
    }
  }
}

// ---------- 5. out = conv @ Wfc + bfc + x via MFMA (swapped; float4 epilogue) ----------
__global__ __launch_bounds__(256) void final_mfma_kernel(
    const unsigned short* __restrict__ conv, const unsigned short* __restrict__ Wt,
    const float* __restrict__ bfc, const float* __restrict__ x,
    float* __restrict__ outp, int N) {
  __shared__ __align__(16) unsigned short As[64 * 128];
  int t = threadIdx.x;
  int lane = t & 63;
  int wid = t >> 6;
  size_t row0 = (size_t)blockIdx.x * 64;

  for (int i = 0; i < 4; ++i) {
    int c = i * 256 + t;
    int r = c >> 4;
    int kc = (c & 15) * 8;
    int4 pk = make_int4(0, 0, 0, 0);
    if (row0 + r < (size_t)N)
      pk = *reinterpret_cast<const int4*>(conv + (row0 + r) * CH + kc);
    int byte = (r * 256 + kc * 2) ^ ((r & 7) << 4);
    *reinterpret_cast<int4*>((char*)As + byte) = pk;
  }
  __syncthreads();

  const unsigned short* wt = Wt + ((size_t)4 << 14);
  int lr = lane & 15;
  int lg = lane >> 4;

  f32x4 acc[4][2];
#pragma unroll
  for (int mt = 0; mt < 4; ++mt)
#pragma unroll
    for (int i = 0; i < 2; ++i) acc[mt][i] = (f32x4){0.f, 0.f, 0.f, 0.f};

  for (int ks = 0; ks < 4; ++ks) {
    bf16x8 a[4], b[2];
#pragma unroll
    for (int mt = 0; mt < 4; ++mt) {
      int r = mt * 16 + lr;
      int byte = (r * 256 + (ks * 32 + lg * 8) * 2) ^ ((r & 7) << 4);
      a[mt] = *reinterpret_cast<const bf16x8*>((const char*)As + byte);
    }
#pragma unroll
    for (int i = 0; i < 2; ++i) {
      int n = (wid * 2 + i) * 16 + lr;
      b[i] = *reinterpret_cast<const bf16x8*>(wt + n * 128 + ks * 32 + lg * 8);
    }
#pragma unroll
    for (int mt = 0; mt < 4; ++mt)
#pragma unroll
      for (int i = 0; i < 2; ++i)
        acc[mt][i] = __builtin_amdgcn_mfma_f32_16x16x32_bf16(b[i], a[mt], acc[mt][i], 0, 0, 0);
  }

#pragma unroll
  for (int mt = 0; mt < 4; ++mt) {
    size_t row = row0 + mt * 16 + lr;
    if (row < (size_t)N) {
#pragma unroll
      for (int i = 0; i < 2; ++i) {
        int cb = (wid * 2 + i) * 16 + lg * 4;
        float4 bb = *reinterpret_cast<const float4*>(bfc + cb);
        float4 rx = *reinterpret_cast<const float4*>(x + row * CH + cb);
        float4 o;
        o.x = acc[mt][i][0] + bb.x + rx.x;
        o.y = acc[mt][i][1] + bb.y + rx.y;
        o.z = acc[mt][i][2] + bb.z + rx.z;
        o.w = acc[mt][i][3] + bb.w + rx.w;
        *reinterpret_cast<float4*>(outp + row * CH + cb) = o;
      }
    }
  }
}

// ---------------------------------------------------------------
extern "C" void kernel_launch(void* const* d_in, const int* in_sizes, int n_in,
                              void* d_out, int out_size, void* d_ws, size_t ws_size,
                              hipStream_t stream) {
  const float* x = (const float*)d_in[0];
  const int* ei = (const int*)d_in[1];
  const float* gamma = (const float*)d_in[2];
  const float* beta = (const float*)d_in[3];
  const float* Wq = (const float*)d_in[4];
  const float* bq = (const float*)d_in[5];
  const float* Wk = (const float*)d_in[6];
  const float* bk = (const float*)d_in[7];
  const float* Wv = (const float*)d_in[8];
  const float* bv = (const float*)d_in[9];
  const float* Ws = (const float*)d_in[10];
  const float* bs = (const float*)d_in[11];
  const float* Wfc = (const float*)d_in[12];
  const float* bfc = (const float*)d_in[13];

  const int N = in_sizes[0] / CH;
  const int E = in_sizes[1] / 2;
  const int* srcp = ei;
  const int* dstp = ei + E;
  float* outp = (float*)d_out;

  char* wsb = (char*)d_ws;
  size_t off = 0;
  auto take = [&](size_t bytes) -> void* {
    void* p = wsb + off;
    off = (off + bytes + 255) & ~(size_t)255;
    return p;
  };
  float* stats = (float*)take(256 * 4);
  float* scsh = (float*)take(256 * 4);
  unsigned short* Wt = (unsigned short*)take((size_t)5 * 16384 * 2);
  unsigned short* qb = (unsigned short*)take((size_t)N * CH * 2);
  unsigned char* kb8 = (unsigned char*)take((size_t)N * CH);
  unsigned char* vb8 = (unsigned char*)take((size_t)N * CH);
  unsigned short* sb = (unsigned short*)take((size_t)N * CH * 2);
  unsigned short* convb = (unsigned short*)take((size_t)N * CH * 2);
  int* deg = (int*)take((size_t)N * 4);
  int* rank = (int*)take((size_t)E * 4);
  int* rowptr = (int*)take((size_t)(N + 1) * 4);
  int nchunks = (N + 2047) / 2048;
  int* chunksums = (int*)take((size_t)nchunks * 4);
  int* chunkoffs = (int*)take((size_t)nchunks * 4);
  int* sorted_src = (int*)take((size_t)E * 4);

  (void)hipMemsetAsync(stats, 0, 256 * 4, stream);
  (void)hipMemsetAsync(deg, 0, (size_t)N * 4, stream);

  bn_stats_kernel<<<512, 256, 0, stream>>>(x, stats, N);
  bn_finalize_kernel<<<1, 128, 0, stream>>>(stats, gamma, beta, scsh, N);
  pack_w_kernel<<<320, 256, 0, stream>>>(Wq, Wk, Wv, Ws, Wfc, Wt);

  int nblk = (N + 63) / 64;
  proj_mfma_kernel<<<nblk, 256, 0, stream>>>(x, scsh, Wt, bq, bk, bv, bs, qb, kb8, vb8, sb, N);

  deg_rank_kernel<<<2048, 256, 0, stream>>>(dstp, deg, rank, E);
  sum_chunks_kernel<<<nchunks, 256, 0, stream>>>(deg, chunksums, N);
  scan_sums_kernel<<<1, 64, 0, stream>>>(chunksums, chunkoffs, nchunks, rowptr, N);
  scan_chunks_kernel<<<nchunks, 256, 0, stream>>>(deg, chunkoffs, rowptr, N);
  scatter_kernel<<<2048, 256, 0, stream>>>(srcp, dstp, rowptr, rank, sorted_src, E);

  int ablocks = 4096;
  attn_kernel<<<ablocks, 256, 0, stream>>>(qb, kb8, vb8, sb, rowptr, sorted_src, convb, N,
                                           ablocks * 4);
  final_mfma_kernel<<<nblk, 256, 0, stream>>>(convb, Wt, bfc, x, outp, N);
}

// Round 9
// 342.588 us; speedup vs baseline: 2.1153x; 1.0100x over previous
//
#include <hip/hip_runtime.h>

#define CH 128  // channels = H*D = 4*32

typedef short bf16x8 __attribute__((ext_vector_type(8)));
typedef float f32x4 __attribute__((ext_vector_type(4)));
typedef float f32x2 __attribute__((ext_vector_type(2)));
typedef _Float16 f16x2 __attribute__((ext_vector_type(2)));

// ---------- helpers ----------
static __device__ __forceinline__ unsigned short f2bf(float f) {
  union { float f; unsigned int i; } c;
  c.f = f;
  unsigned int r = c.i + 0x7fffu + ((c.i >> 16) & 1u);  // RNE
  return (unsigned short)(r >> 16);
}

// fp8 e4m3 fallbacks (used only if builtins are missing)
static __device__ float fp82f_sw(unsigned int b) {
  int sgn = (b >> 7) & 1;
  int e = (b >> 3) & 15;
  int m = b & 7;
  float v = e ? ldexpf(1.f + m * 0.125f, e - 7) : ldexpf((float)m, -9);
  return sgn ? -v : v;
}
static __device__ unsigned char f2fp8_sw(float f) {
  unsigned char s = (f < 0.f) ? 0x80 : 0;
  float af = fabsf(f);
  if (!(af < 448.f)) return s | 0x7e;
  int ex;
  frexpf(af, &ex);
  int e = ex - 1;
  if (e < -6) e = -6;
  float step = ldexpf(1.f, e - 3);
  float qq = rintf(af / step);
  if (qq >= 16.f) { qq = 8.f; e += 1; }
  if (e > 8) return s | 0x7e;
  unsigned char bits = (qq < 8.f) ? (unsigned char)qq
                                  : (unsigned char)(((e + 7) << 3) | ((int)qq - 8));
  return s | bits;
}
template <bool HI>
static __device__ __forceinline__ unsigned int pkfp8(float a, float b, unsigned int old) {
#if __has_builtin(__builtin_amdgcn_cvt_pk_fp8_f32)
  return (unsigned int)__builtin_amdgcn_cvt_pk_fp8_f32(a, b, (int)old, HI);
#else
  unsigned int w = ((unsigned)f2fp8_sw(a)) | (((unsigned)f2fp8_sw(b)) << 8);
  return HI ? ((old & 0x0000ffffu) | (w << 16)) : ((old & 0xffff0000u) | w);
#endif
}
template <bool HI>
static __device__ __forceinline__ f32x2 upkfp8(unsigned int src) {
#if __has_builtin(__builtin_amdgcn_cvt_pk_f32_fp8)
  return __builtin_amdgcn_cvt_pk_f32_fp8((int)src, HI);
#else
  unsigned int h = HI ? (src >> 16) : (src & 0xffffu);
  f32x2 r;
  r[0] = fp82f_sw(h & 0xff);
  r[1] = fp82f_sw((h >> 8) & 0xff);
  return r;
#endif
}

// ---------- 1. BatchNorm statistics ----------
__global__ void bn_stats_kernel(const float* __restrict__ x, float* __restrict__ stats, int N) {
  int t = threadIdx.x;
  int ch = t & (CH - 1);
  int r0 = t >> 7;
  float s = 0.f, ss = 0.f;
  for (int row = blockIdx.x * 2 + r0; row < N; row += gridDim.x * 2) {
    float v = x[(size_t)row * CH + ch];
    s += v;
    ss += v * v;
  }
  atomicAdd(&stats[ch], s);
  atomicAdd(&stats[CH + ch], ss);
}

__global__ void bn_finalize_kernel(const float* __restrict__ stats,
                                   const float* __restrict__ gamma,
                                   const float* __restrict__ beta,
                                   float* __restrict__ scsh, int N) {
  int c = threadIdx.x;
  if (c < CH) {
    float inv_n = 1.0f / (float)N;
    float mu = stats[c] * inv_n;
    float var = stats[CH + c] * inv_n - mu * mu;
    float sc = gamma[c] * rsqrtf(var + 1e-5f);
    scsh[c] = sc;
    scsh[CH + c] = beta[c] - mu * sc;
  }
}

// ---------- 1b. pack weights: Wt[mat][n][k] bf16, mats = q,k,v,skip,fc ----------
__global__ void pack_w_kernel(const float* __restrict__ Wq, const float* __restrict__ Wk,
                              const float* __restrict__ Wv, const float* __restrict__ Ws,
                              const float* __restrict__ Wfc, unsigned short* __restrict__ Wt) {
  int el = blockIdx.x * 256 + threadIdx.x;  // 5*16384 elements
  int mat = el >> 14;
  int rem = el & 16383;
  int kk = rem >> 7;
  int n = rem & 127;
  const float* W = mat == 0 ? Wq : mat == 1 ? Wk : mat == 2 ? Wv : mat == 3 ? Ws : Wfc;
  Wt[((size_t)mat << 14) + n * 128 + kk] = f2bf(W[kk * 128 + n]);
}

// ---------- 2. fused BN+ReLU + 4 projections via MFMA ----------
// Swapped-operand MFMA: lane holds 4 consecutive output channels of one node row.
// wave 0 -> q (f16), wave 1 -> k (fp8), wave 2 -> v (fp8), wave 3 -> skip (f16)
__global__ __launch_bounds__(256, 2) void proj_mfma_kernel(
    const float* __restrict__ x, const float* __restrict__ scsh,
    const unsigned short* __restrict__ Wt,
    const float* __restrict__ bq_, const float* __restrict__ bk_,
    const float* __restrict__ bv_, const float* __restrict__ bs_,
    unsigned short* __restrict__ q, unsigned char* __restrict__ k8,
    unsigned char* __restrict__ v8, unsigned short* __restrict__ s_, int N) {
  __shared__ __align__(16) unsigned short As[64 * 128];  // 16KB, XOR-swizzled
  int t = threadIdx.x;
  int lane = t & 63;
  int wid = t >> 6;
  size_t row0 = (size_t)blockIdx.x * 64;

  for (int i = 0; i < 4; ++i) {
    int c = i * 256 + t;
    int r = c >> 4;
    int kc = (c & 15) * 8;
    float4 v0 = make_float4(0.f, 0.f, 0.f, 0.f), v1 = v0;
    if (row0 + r < (size_t)N) {
      const float* g = x + (row0 + r) * CH + kc;
      v0 = *reinterpret_cast<const float4*>(g);
      v1 = *reinterpret_cast<const float4*>(g + 4);
    }
    float4 sca = *reinterpret_cast<const float4*>(scsh + kc);
    float4 scb = *reinterpret_cast<const float4*>(scsh + kc + 4);
    float4 sha = *reinterpret_cast<const float4*>(scsh + CH + kc);
    float4 shb = *reinterpret_cast<const float4*>(scsh + CH + kc + 4);
    unsigned short h[8];
    h[0] = f2bf(fmaxf(fmaf(v0.x, sca.x, sha.x), 0.f));
    h[1] = f2bf(fmaxf(fmaf(v0.y, sca.y, sha.y), 0.f));
    h[2] = f2bf(fmaxf(fmaf(v0.z, sca.z, sha.z), 0.f));
    h[3] = f2bf(fmaxf(fmaf(v0.w, sca.w, sha.w), 0.f));
    h[4] = f2bf(fmaxf(fmaf(v1.x, scb.x, shb.x), 0.f));
    h[5] = f2bf(fmaxf(fmaf(v1.y, scb.y, shb.y), 0.f));
    h[6] = f2bf(fmaxf(fmaf(v1.z, scb.z, shb.z), 0.f));
    h[7] = f2bf(fmaxf(fmaf(v1.w, scb.w, shb.w), 0.f));
    int4 pk;
    pk.x = (int)h[0] | ((int)h[1] << 16);
    pk.y = (int)h[2] | ((int)h[3] << 16);
    pk.z = (int)h[4] | ((int)h[5] << 16);
    pk.w = (int)h[6] | ((int)h[7] << 16);
    int byte = (r * 256 + kc * 2) ^ ((r & 7) << 4);
    *reinterpret_cast<int4*>((char*)As + byte) = pk;
  }
  __syncthreads();

  const unsigned short* wt = Wt + ((size_t)wid << 14);
  const float* bias = wid == 0 ? bq_ : wid == 1 ? bk_ : wid == 2 ? bv_ : bs_;
  int lr = lane & 15;
  int lg = lane >> 4;

  f32x4 acc[4][8];
#pragma unroll
  for (int mt = 0; mt < 4; ++mt)
#pragma unroll
    for (int nt = 0; nt < 8; ++nt) acc[mt][nt] = (f32x4){0.f, 0.f, 0.f, 0.f};

  for (int ks = 0; ks < 4; ++ks) {
    bf16x8 a[4], b[8];
#pragma unroll
    for (int mt = 0; mt < 4; ++mt) {
      int r = mt * 16 + lr;
      int byte = (r * 256 + (ks * 32 + lg * 8) * 2) ^ ((r & 7) << 4);
      a[mt] = *reinterpret_cast<const bf16x8*>((const char*)As + byte);
    }
#pragma unroll
    for (int nt = 0; nt < 8; ++nt)
      b[nt] = *reinterpret_cast<const bf16x8*>(wt + (nt * 16 + lr) * 128 + ks * 32 + lg * 8);
    // swapped operands: D[ch][node] -> lane holds node=lr, channels nt*16+lg*4+j
#pragma unroll
    for (int mt = 0; mt < 4; ++mt)
#pragma unroll
      for (int nt = 0; nt < 8; ++nt)
        acc[mt][nt] = __builtin_amdgcn_mfma_f32_16x16x32_bf16(b[nt], a[mt], acc[mt][nt], 0, 0, 0);
  }

  bool isfp8 = (wid == 1) || (wid == 2);
  unsigned short* o16 = (wid == 0) ? q : s_;
  unsigned char* o8 = (wid == 1) ? k8 : v8;
#pragma unroll
  for (int mt = 0; mt < 4; ++mt) {
    size_t row = row0 + mt * 16 + lr;
    if (row < (size_t)N) {
#pragma unroll
      for (int nt = 0; nt < 8; ++nt) {
        int cb = nt * 16 + lg * 4;
        float4 bb = *reinterpret_cast<const float4*>(bias + cb);
        float o0 = acc[mt][nt][0] + bb.x;
        float o1 = acc[mt][nt][1] + bb.y;
        float o2 = acc[mt][nt][2] + bb.z;
        float o3 = acc[mt][nt][3] + bb.w;
        if (isfp8) {
          unsigned int w = pkfp8<false>(o0, o1, 0u);
          w = pkfp8<true>(o2, o3, w);
          *reinterpret_cast<unsigned int*>(o8 + row * CH + cb) = w;
        } else {
          ushort4 u;
          u.x = __builtin_bit_cast(unsigned short, (_Float16)o0);
          u.y = __builtin_bit_cast(unsigned short, (_Float16)o1);
          u.z = __builtin_bit_cast(unsigned short, (_Float16)o2);
          u.w = __builtin_bit_cast(unsigned short, (_Float16)o3);
          *reinterpret_cast<ushort4*>(o16 + row * CH + cb) = u;
        }
      }
    }
  }
}

// ---------- 3. CSR build over dst (rank trick: deg_rank then atomic-free scatter) ----------
__global__ void deg_rank_kernel(const int* __restrict__ dst, int* __restrict__ deg,
                                int* __restrict__ rank, int E) {
  for (int e = blockIdx.x * blockDim.x + threadIdx.x; e < E; e += gridDim.x * blockDim.x) {
    rank[e] = atomicAdd(&deg[dst[e]], 1);
  }
}

__global__ void sum_chunks_kernel(const int* __restrict__ deg, int* __restrict__ chunksums, int N) {
  __shared__ int sd[256];
  int t = threadIdx.x;
  int base = blockIdx.x * 2048;
  int s = 0;
  for (int i = 0; i < 8; ++i) {
    int idx = base + t * 8 + i;
    if (idx < N) s += deg[idx];
  }
  sd[t] = s;
  __syncthreads();
  for (int o = 128; o > 0; o >>= 1) {
    if (t < o) sd[t] += sd[t + o];
    __syncthreads();
  }
  if (t == 0) chunksums[blockIdx.x] = sd[0];
}

__global__ void scan_sums_kernel(const int* __restrict__ chunksums, int* __restrict__ chunkoffs,
                                 int nchunks, int* __restrict__ rowptr, int N) {
  if (threadIdx.x == 0) {
    int acc = 0;
    for (int i = 0; i < nchunks; ++i) {
      chunkoffs[i] = acc;
      acc += chunksums[i];
    }
    rowptr[N] = acc;
  }
}

__global__ void scan_chunks_kernel(const int* __restrict__ deg, const int* __restrict__ chunkoffs,
                                   int* __restrict__ rowptr, int N) {
  __shared__ int sd[256];
  int t = threadIdx.x;
  int base = blockIdx.x * 2048;
  int vals[8];
  int s = 0;
  for (int i = 0; i < 8; ++i) {
    int idx = base + t * 8 + i;
    int d = (idx < N) ? deg[idx] : 0;
    vals[i] = s;
    s += d;
  }
  sd[t] = s;
  __syncthreads();
  int mytot = s;
  for (int o = 1; o < 256; o <<= 1) {
    int vprev = (t >= o) ? sd[t - o] : 0;
    __syncthreads();
    sd[t] += vprev;
    __syncthreads();
  }
  int texcl = sd[t] - mytot;
  int cb = chunkoffs[blockIdx.x];
  for (int i = 0; i < 8; ++i) {
    int idx = base + t * 8 + i;
    if (idx < N) rowptr[idx] = cb + texcl + vals[i];
  }
}

__global__ void scatter_kernel(const int* __restrict__ src, const int* __restrict__ dst,
                               const int* __restrict__ rowptr, const int* __restrict__ rank,
                               int* __restrict__ sorted_src, int E) {
  for (int e = blockIdx.x * blockDim.x + threadIdx.x; e < E; e += gridDim.x * blockDim.x) {
    int d = dst[e];
    int pos = rowptr[d] + rank[e];
    sorted_src[pos] = src[e];
  }
}

// ---------- 4. per-dst softmax (no max; range-safe) + aggregation; fp8 k/v ----------
// 1 wave per node (grid-stride). lane = (g = edge slot 0-3, s = sublane 0-15);
// sublane s owns channels 8s..8s+7; head = s>>2; 4 edges per iteration.
// Inner loop in packed f32x2 arithmetic (v_pk_fma_f32 / v_pk_mul_f32).
__global__ __launch_bounds__(256) void attn_kernel(
    const unsigned short* __restrict__ q, const unsigned char* __restrict__ k8,
    const unsigned char* __restrict__ v8, const unsigned short* __restrict__ skp,
    const int* __restrict__ rowptr, const int* __restrict__ sorted_src,
    unsigned short* __restrict__ conv, int N, int nw) {
  int lane = threadIdx.x & 63;
  int g = lane >> 4;
  int s = lane & 15;
  int w0 = blockIdx.x * (blockDim.x >> 6) + (threadIdx.x >> 6);
  const float ASC = 0.17677669529663687f;  // 1/sqrt(32)
  for (int n = w0; n < N; n += nw) {
    int beg = rowptr[n], end = rowptr[n + 1];
    size_t rowb = (size_t)n * CH + s * 8;
    uint4 qr = *reinterpret_cast<const uint4*>(q + rowb);
    f32x2 qv[4];
    {
      f16x2 t0 = __builtin_bit_cast(f16x2, qr.x);
      f16x2 t1 = __builtin_bit_cast(f16x2, qr.y);
      f16x2 t2 = __builtin_bit_cast(f16x2, qr.z);
      f16x2 t3 = __builtin_bit_cast(f16x2, qr.w);
      qv[0] = (f32x2){(float)t0[0] * ASC, (float)t0[1] * ASC};
      qv[1] = (f32x2){(float)t1[0] * ASC, (float)t1[1] * ASC};
      qv[2] = (f32x2){(float)t2[0] * ASC, (float)t2[1] * ASC};
      qv[3] = (f32x2){(float)t3[0] * ASC, (float)t3[1] * ASC};
    }
    float ssum = 0.f;
    f32x2 vA = (f32x2){0.f, 0.f}, vB = vA, vC = vA, vD = vA;
    int nit = (end - beg + 3) >> 2;
    for (int it = 0; it < nit; ++it) {
      int e = beg + it * 4 + g;
      bool valid = e < end;
      int src = sorted_src[valid ? e : beg];
      size_t sb = (size_t)src * CH + s * 8;
      uint2 kr = *reinterpret_cast<const uint2*>(k8 + sb);
      uint2 vr = *reinterpret_cast<const uint2*>(v8 + sb);
      f32x2 pacc = upkfp8<false>(kr.x) * qv[0];
      pacc += upkfp8<true>(kr.x) * qv[1];
      pacc += upkfp8<false>(kr.y) * qv[2];
      pacc += upkfp8<true>(kr.y) * qv[3];
      float p = pacc[0] + pacc[1];
      p += __shfl_xor(p, 1);
      p += __shfl_xor(p, 2);  // full 32-ch head dot
      float ex = valid ? __expf(p) : 0.f;
      ssum += ex;
      f32x2 e2 = (f32x2){ex, ex};
      vA += e2 * upkfp8<false>(vr.x);
      vB += e2 * upkfp8<true>(vr.x);
      vC += e2 * upkfp8<false>(vr.y);
      vD += e2 * upkfp8<true>(vr.y);
    }
    float va[8] = {vA[0], vA[1], vB[0], vB[1], vC[0], vC[1], vD[0], vD[1]};
#pragma unroll
    for (int msk = 16; msk <= 32; msk <<= 1) {
      ssum += __shfl_xor(ssum, msk);
#pragma unroll
      for (int i = 0; i < 8; ++i) va[i] += __shfl_xor(va[i], msk);
    }
    float inv = (end > beg) ? 1.0f / ssum : 0.f;
    if (g == 0) {
      uint4 sr = *reinterpret_cast<const uint4*>(skp + rowb);
      f16x2 s0 = __builtin_bit_cast(f16x2, sr.x);
      f16x2 s1 = __builtin_bit_cast(f16x2, sr.y);
      f16x2 s2 = __builtin_bit_cast(f16x2, sr.z);
      f16x2 s3 = __builtin_bit_cast(f16x2, sr.w);
      int4 pk;
      pk.x = (int)f2bf(va[0] * inv + (float)s0[0]) | ((int)f2bf(va[1] * inv + (float)s0[1]) << 16);
      pk.y = (int)f2bf(va[2] * inv + (float)s1[0]) | ((int)f2bf(va[3] * inv + (float)s1[1]) << 16);
      pk.z = (int)f2bf(va[4] * inv + (float)s2[0]) | ((int)f2bf(va[5] * inv + (float)s2[1]) << 16);
      pk.w = (int)f2bf(va[6] * inv + (float)s3[0]) | ((int)f2bf(va[7] * inv + (float)s3[1]) << 16);
      *reinterpret_cast<int4*>(conv + rowb) = pk;
    }
  }
}

// ---------- 5. out = conv @ Wfc + bfc + x via MFMA (swapped; float4 epilogue) ----------
__global__ __launch_bounds__(256) void final_mfma_kernel(
    const unsigned short* __restrict__ conv, const unsigned short* __restrict__ Wt,
    const float* __restrict__ bfc, const float* __restrict__ x,
    float* __restrict__ outp, int N) {
  __shared__ __align__(16) unsigned short As[64 * 128];
  int t = threadIdx.x;
  int lane = t & 63;
  int wid = t >> 6;
  size_t row0 = (size_t)blockIdx.x * 64;

  for (int i = 0; i < 4; ++i) {
    int c = i * 256 + t;
    int r = c >> 4;
    int kc = (c & 15) * 8;
    int4 pk = make_int4(0, 0, 0, 0);
    if (row0 + r < (size_t)N)
      pk = *reinterpret_cast<const int4*>(conv + (row0 + r) * CH + kc);
    int byte = (r * 256 + kc * 2) ^ ((r & 7) << 4);
    *reinterpret_cast<int4*>((char*)As + byte) = pk;
  }
  __syncthreads();

  const unsigned short* wt = Wt + ((size_t)4 << 14);
  int lr = lane & 15;
  int lg = lane >> 4;

  f32x4 acc[4][2];
#pragma unroll
  for (int mt = 0; mt < 4; ++mt)
#pragma unroll
    for (int i = 0; i < 2; ++i) acc[mt][i] = (f32x4){0.f, 0.f, 0.f, 0.f};

  for (int ks = 0; ks < 4; ++ks) {
    bf16x8 a[4], b[2];
#pragma unroll
    for (int mt = 0; mt < 4; ++mt) {
      int r = mt * 16 + lr;
      int byte = (r * 256 + (ks * 32 + lg * 8) * 2) ^ ((r & 7) << 4);
      a[mt] = *reinterpret_cast<const bf16x8*>((const char*)As + byte);
    }
#pragma unroll
    for (int i = 0; i < 2; ++i) {
      int n = (wid * 2 + i) * 16 + lr;
      b[i] = *reinterpret_cast<const bf16x8*>(wt + n * 128 + ks * 32 + lg * 8);
    }
#pragma unroll
    for (int mt = 0; mt < 4; ++mt)
#pragma unroll
      for (int i = 0; i < 2; ++i)
        acc[mt][i] = __builtin_amdgcn_mfma_f32_16x16x32_bf16(b[i], a[mt], acc[mt][i], 0, 0, 0);
  }

#pragma unroll
  for (int mt = 0; mt < 4; ++mt) {
    size_t row = row0 + mt * 16 + lr;
    if (row < (size_t)N) {
#pragma unroll
      for (int i = 0; i < 2; ++i) {
        int cb = (wid * 2 + i) * 16 + lg * 4;
        float4 bb = *reinterpret_cast<const float4*>(bfc + cb);
        float4 rx = *reinterpret_cast<const float4*>(x + row * CH + cb);
        float4 o;
        o.x = acc[mt][i][0] + bb.x + rx.x;
        o.y = acc[mt][i][1] + bb.y + rx.y;
        o.z = acc[mt][i][2] + bb.z + rx.z;
        o.w = acc[mt][i][3] + bb.w + rx.w;
        *reinterpret_cast<float4*>(outp + row * CH + cb) = o;
      }
    }
  }
}

// ---------------------------------------------------------------
extern "C" void kernel_launch(void* const* d_in, const int* in_sizes, int n_in,
                              void* d_out, int out_size, void* d_ws, size_t ws_size,
                              hipStream_t stream) {
  const float* x = (const float*)d_in[0];
  const int* ei = (const int*)d_in[1];
  const float* gamma = (const float*)d_in[2];
  const float* beta = (const float*)d_in[3];
  const float* Wq = (const float*)d_in[4];
  const float* bq = (const float*)d_in[5];
  const float* Wk = (const float*)d_in[6];
  const float* bk = (const float*)d_in[7];
  const float* Wv = (const float*)d_in[8];
  const float* bv = (const float*)d_in[9];
  const float* Ws = (const float*)d_in[10];
  const float* bs = (const float*)d_in[11];
  const float* Wfc = (const float*)d_in[12];
  const float* bfc = (const float*)d_in[13];

  const int N = in_sizes[0] / CH;
  const int E = in_sizes[1] / 2;
  const int* srcp = ei;
  const int* dstp = ei + E;
  float* outp = (float*)d_out;

  char* wsb = (char*)d_ws;
  size_t off = 0;
  auto take = [&](size_t bytes) -> void* {
    void* p = wsb + off;
    off = (off + bytes + 255) & ~(size_t)255;
    return p;
  };
  float* stats = (float*)take(256 * 4);
  float* scsh = (float*)take(256 * 4);
  unsigned short* Wt = (unsigned short*)take((size_t)5 * 16384 * 2);
  unsigned short* qb = (unsigned short*)take((size_t)N * CH * 2);
  unsigned char* kb8 = (unsigned char*)take((size_t)N * CH);
  unsigned char* vb8 = (unsigned char*)take((size_t)N * CH);
  unsigned short* sb = (unsigned short*)take((size_t)N * CH * 2);
  unsigned short* convb = (unsigned short*)take((size_t)N * CH * 2);
  int* deg = (int*)take((size_t)N * 4);
  int* rank = (int*)take((size_t)E * 4);
  int* rowptr = (int*)take((size_t)(N + 1) * 4);
  int nchunks = (N + 2047) / 2048;
  int* chunksums = (int*)take((size_t)nchunks * 4);
  int* chunkoffs = (int*)take((size_t)nchunks * 4);
  int* sorted_src = (int*)take((size_t)E * 4);

  (void)hipMemsetAsync(stats, 0, 256 * 4, stream);
  (void)hipMemsetAsync(deg, 0, (size_t)N * 4, stream);

  bn_stats_kernel<<<512, 256, 0, stream>>>(x, stats, N);
  bn_finalize_kernel<<<1, 128, 0, stream>>>(stats, gamma, beta, scsh, N);
  pack_w_kernel<<<320, 256, 0, stream>>>(Wq, Wk, Wv, Ws, Wfc, Wt);

  int nblk = (N + 63) / 64;
  proj_mfma_kernel<<<nblk, 256, 0, stream>>>(x, scsh, Wt, bq, bk, bv, bs, qb, kb8, vb8, sb, N);

  deg_rank_kernel<<<2048, 256, 0, stream>>>(dstp, deg, rank, E);
  sum_chunks_kernel<<<nchunks, 256, 0, stream>>>(deg, chunksums, N);
  scan_sums_kernel<<<1, 64, 0, stream>>>(chunksums, chunkoffs, nchunks, rowptr, N);
  scan_chunks_kernel<<<nchunks, 256, 0, stream>>>(deg, chunkoffs, rowptr, N);
  scatter_kernel<<<2048, 256, 0, stream>>>(srcp, dstp, rowptr, rank, sorted_src, E);

  int ablocks = 4096;
  attn_kernel<<<ablocks, 256, 0, stream>>>(qb, kb8, vb8, sb, rowptr, sorted_src, convb, N,
                                           ablocks * 4);
  final_mfma_kernel<<<nblk, 256, 0, stream>>>(convb, Wt, bfc, x, outp, N);
}

// Round 10
// 342.201 us; speedup vs baseline: 2.1177x; 1.0011x over previous
//
#include <hip/hip_runtime.h>

#define CH 128  // channels = H*D = 4*32

typedef short bf16x8 __attribute__((ext_vector_type(8)));
typedef float f32x4 __attribute__((ext_vector_type(4)));
typedef float f32x2 __attribute__((ext_vector_type(2)));
typedef _Float16 f16x2 __attribute__((ext_vector_type(2)));

// ---------- helpers ----------
static __device__ __forceinline__ unsigned short f2bf(float f) {
  union { float f; unsigned int i; } c;
  c.f = f;
  unsigned int r = c.i + 0x7fffu + ((c.i >> 16) & 1u);  // RNE
  return (unsigned short)(r >> 16);
}

// fp8 e4m3 fallbacks (used only if builtins are missing)
static __device__ float fp82f_sw(unsigned int b) {
  int sgn = (b >> 7) & 1;
  int e = (b >> 3) & 15;
  int m = b & 7;
  float v = e ? ldexpf(1.f + m * 0.125f, e - 7) : ldexpf((float)m, -9);
  return sgn ? -v : v;
}
static __device__ unsigned char f2fp8_sw(float f) {
  unsigned char s = (f < 0.f) ? 0x80 : 0;
  float af = fabsf(f);
  if (!(af < 448.f)) return s | 0x7e;
  int ex;
  frexpf(af, &ex);
  int e = ex - 1;
  if (e < -6) e = -6;
  float step = ldexpf(1.f, e - 3);
  float qq = rintf(af / step);
  if (qq >= 16.f) { qq = 8.f; e += 1; }
  if (e > 8) return s | 0x7e;
  unsigned char bits = (qq < 8.f) ? (unsigned char)qq
                                  : (unsigned char)(((e + 7) << 3) | ((int)qq - 8));
  return s | bits;
}
template <bool HI>
static __device__ __forceinline__ unsigned int pkfp8(float a, float b, unsigned int old) {
#if __has_builtin(__builtin_amdgcn_cvt_pk_fp8_f32)
  return (unsigned int)__builtin_amdgcn_cvt_pk_fp8_f32(a, b, (int)old, HI);
#else
  unsigned int w = ((unsigned)f2fp8_sw(a)) | (((unsigned)f2fp8_sw(b)) << 8);
  return HI ? ((old & 0x0000ffffu) | (w << 16)) : ((old & 0xffff0000u) | w);
#endif
}
template <bool HI>
static __device__ __forceinline__ f32x2 upkfp8(unsigned int src) {
#if __has_builtin(__builtin_amdgcn_cvt_pk_f32_fp8)
  return __builtin_amdgcn_cvt_pk_f32_fp8((int)src, HI);
#else
  unsigned int h = HI ? (src >> 16) : (src & 0xffffu);
  f32x2 r;
  r[0] = fp82f_sw(h & 0xff);
  r[1] = fp82f_sw((h >> 8) & 0xff);
  return r;
#endif
}

// ---------- 1. BatchNorm statistics ----------
__global__ void bn_stats_kernel(const float* __restrict__ x, float* __restrict__ stats, int N) {
  int t = threadIdx.x;
  int ch = t & (CH - 1);
  int r0 = t >> 7;
  float s = 0.f, ss = 0.f;
  for (int row = blockIdx.x * 2 + r0; row < N; row += gridDim.x * 2) {
    float v = x[(size_t)row * CH + ch];
    s += v;
    ss += v * v;
  }
  atomicAdd(&stats[ch], s);
  atomicAdd(&stats[CH + ch], ss);
}

__global__ void bn_finalize_kernel(const float* __restrict__ stats,
                                   const float* __restrict__ gamma,
                                   const float* __restrict__ beta,
                                   float* __restrict__ scsh, int N) {
  int c = threadIdx.x;
  if (c < CH) {
    float inv_n = 1.0f / (float)N;
    float mu = stats[c] * inv_n;
    float var = stats[CH + c] * inv_n - mu * mu;
    float sc = gamma[c] * rsqrtf(var + 1e-5f);
    scsh[c] = sc;
    scsh[CH + c] = beta[c] - mu * sc;
  }
}

// ---------- 1b. pack weights: Wt[mat][n][k] bf16, mats = q,k,v,skip,fc ----------
__global__ void pack_w_kernel(const float* __restrict__ Wq, const float* __restrict__ Wk,
                              const float* __restrict__ Wv, const float* __restrict__ Ws,
                              const float* __restrict__ Wfc, unsigned short* __restrict__ Wt) {
  int el = blockIdx.x * 256 + threadIdx.x;  // 5*16384 elements
  int mat = el >> 14;
  int rem = el & 16383;
  int kk = rem >> 7;
  int n = rem & 127;
  const float* W = mat == 0 ? Wq : mat == 1 ? Wk : mat == 2 ? Wv : mat == 3 ? Ws : Wfc;
  Wt[((size_t)mat << 14) + n * 128 + kk] = f2bf(W[kk * 128 + n]);
}

// ---------- 2. fused BN+ReLU + 4 projections via MFMA ----------
// Swapped-operand MFMA: lane holds 4 consecutive output channels of one node row.
// wave 0 -> q (f16), wave 1 -> k (fp8), wave 2 -> v (fp8), wave 3 -> skip (f16)
__global__ __launch_bounds__(256, 2) void proj_mfma_kernel(
    const float* __restrict__ x, const float* __restrict__ scsh,
    const unsigned short* __restrict__ Wt,
    const float* __restrict__ bq_, const float* __restrict__ bk_,
    const float* __restrict__ bv_, const float* __restrict__ bs_,
    unsigned short* __restrict__ q, unsigned char* __restrict__ k8,
    unsigned char* __restrict__ v8, unsigned short* __restrict__ s_, int N) {
  __shared__ __align__(16) unsigned short As[64 * 128];  // 16KB, XOR-swizzled
  int t = threadIdx.x;
  int lane = t & 63;
  int wid = t >> 6;
  size_t row0 = (size_t)blockIdx.x * 64;

  for (int i = 0; i < 4; ++i) {
    int c = i * 256 + t;
    int r = c >> 4;
    int kc = (c & 15) * 8;
    float4 v0 = make_float4(0.f, 0.f, 0.f, 0.f), v1 = v0;
    if (row0 + r < (size_t)N) {
      const float* g = x + (row0 + r) * CH + kc;
      v0 = *reinterpret_cast<const float4*>(g);
      v1 = *reinterpret_cast<const float4*>(g + 4);
    }
    float4 sca = *reinterpret_cast<const float4*>(scsh + kc);
    float4 scb = *reinterpret_cast<const float4*>(scsh + kc + 4);
    float4 sha = *reinterpret_cast<const float4*>(scsh + CH + kc);
    float4 shb = *reinterpret_cast<const float4*>(scsh + CH + kc + 4);
    unsigned short h[8];
    h[0] = f2bf(fmaxf(fmaf(v0.x, sca.x, sha.x), 0.f));
    h[1] = f2bf(fmaxf(fmaf(v0.y, sca.y, sha.y), 0.f));
    h[2] = f2bf(fmaxf(fmaf(v0.z, sca.z, sha.z), 0.f));
    h[3] = f2bf(fmaxf(fmaf(v0.w, sca.w, sha.w), 0.f));
    h[4] = f2bf(fmaxf(fmaf(v1.x, scb.x, shb.x), 0.f));
    h[5] = f2bf(fmaxf(fmaf(v1.y, scb.y, shb.y), 0.f));
    h[6] = f2bf(fmaxf(fmaf(v1.z, scb.z, shb.z), 0.f));
    h[7] = f2bf(fmaxf(fmaf(v1.w, scb.w, shb.w), 0.f));
    int4 pk;
    pk.x = (int)h[0] | ((int)h[1] << 16);
    pk.y = (int)h[2] | ((int)h[3] << 16);
    pk.z = (int)h[4] | ((int)h[5] << 16);
    pk.w = (int)h[6] | ((int)h[7] << 16);
    int byte = (r * 256 + kc * 2) ^ ((r & 7) << 4);
    *reinterpret_cast<int4*>((char*)As + byte) = pk;
  }
  __syncthreads();

  const unsigned short* wt = Wt + ((size_t)wid << 14);
  const float* bias = wid == 0 ? bq_ : wid == 1 ? bk_ : wid == 2 ? bv_ : bs_;
  int lr = lane & 15;
  int lg = lane >> 4;

  f32x4 acc[4][8];
#pragma unroll
  for (int mt = 0; mt < 4; ++mt)
#pragma unroll
    for (int nt = 0; nt < 8; ++nt) acc[mt][nt] = (f32x4){0.f, 0.f, 0.f, 0.f};

  for (int ks = 0; ks < 4; ++ks) {
    bf16x8 a[4], b[8];
#pragma unroll
    for (int mt = 0; mt < 4; ++mt) {
      int r = mt * 16 + lr;
      int byte = (r * 256 + (ks * 32 + lg * 8) * 2) ^ ((r & 7) << 4);
      a[mt] = *reinterpret_cast<const bf16x8*>((const char*)As + byte);
    }
#pragma unroll
    for (int nt = 0; nt < 8; ++nt)
      b[nt] = *reinterpret_cast<const bf16x8*>(wt + (nt * 16 + lr) * 128 + ks * 32 + lg * 8);
    // swapped operands: D[ch][node] -> lane holds node=lr, channels nt*16+lg*4+j
#pragma unroll
    for (int mt = 0; mt < 4; ++mt)
#pragma unroll
      for (int nt = 0; nt < 8; ++nt)
        acc[mt][nt] = __builtin_amdgcn_mfma_f32_16x16x32_bf16(b[nt], a[mt], acc[mt][nt], 0, 0, 0);
  }

  bool isfp8 = (wid == 1) || (wid == 2);
  unsigned short* o16 = (wid == 0) ? q : s_;
  unsigned char* o8 = (wid == 1) ? k8 : v8;
#pragma unroll
  for (int mt = 0; mt < 4; ++mt) {
    size_t row = row0 + mt * 16 + lr;
    if (row < (size_t)N) {
#pragma unroll
      for (int nt = 0; nt < 8; ++nt) {
        int cb = nt * 16 + lg * 4;
        float4 bb = *reinterpret_cast<const float4*>(bias + cb);
        float o0 = acc[mt][nt][0] + bb.x;
        float o1 = acc[mt][nt][1] + bb.y;
        float o2 = acc[mt][nt][2] + bb.z;
        float o3 = acc[mt][nt][3] + bb.w;
        if (isfp8) {
          unsigned int w = pkfp8<false>(o0, o1, 0u);
          w = pkfp8<true>(o2, o3, w);
          *reinterpret_cast<unsigned int*>(o8 + row * CH + cb) = w;
        } else {
          ushort4 u;
          u.x = __builtin_bit_cast(unsigned short, (_Float16)o0);
          u.y = __builtin_bit_cast(unsigned short, (_Float16)o1);
          u.z = __builtin_bit_cast(unsigned short, (_Float16)o2);
          u.w = __builtin_bit_cast(unsigned short, (_Float16)o3);
          *reinterpret_cast<ushort4*>(o16 + row * CH + cb) = u;
        }
      }
    }
  }
}

// ---------- 3. CSR build over dst (rank trick: deg_rank then atomic-free scatter) ----------
__global__ void deg_rank_kernel(const int* __restrict__ dst, int* __restrict__ deg,
                                int* __restrict__ rank, int E) {
  for (int e = blockIdx.x * blockDim.x + threadIdx.x; e < E; e += gridDim.x * blockDim.x) {
    rank[e] = atomicAdd(&deg[dst[e]], 1);
  }
}

__global__ void sum_chunks_kernel(const int* __restrict__ deg, int* __restrict__ chunksums, int N) {
  __shared__ int sd[256];
  int t = threadIdx.x;
  int base = blockIdx.x * 2048;
  int s = 0;
  for (int i = 0; i < 8; ++i) {
    int idx = base + t * 8 + i;
    if (idx < N) s += deg[idx];
  }
  sd[t] = s;
  __syncthreads();
  for (int o = 128; o > 0; o >>= 1) {
    if (t < o) sd[t] += sd[t + o];
    __syncthreads();
  }
  if (t == 0) chunksums[blockIdx.x] = sd[0];
}

__global__ void scan_sums_kernel(const int* __restrict__ chunksums, int* __restrict__ chunkoffs,
                                 int nchunks, int* __restrict__ rowptr, int N) {
  if (threadIdx.x == 0) {
    int acc = 0;
    for (int i = 0; i < nchunks; ++i) {
      chunkoffs[i] = acc;
      acc += chunksums[i];
    }
    rowptr[N] = acc;
  }
}

__global__ void scan_chunks_kernel(const int* __restrict__ deg, const int* __restrict__ chunkoffs,
                                   int* __restrict__ rowptr, int N) {
  __shared__ int sd[256];
  int t = threadIdx.x;
  int base = blockIdx.x * 2048;
  int vals[8];
  int s = 0;
  for (int i = 0; i < 8; ++i) {
    int idx = base + t * 8 + i;
    int d = (idx < N) ? deg[idx] : 0;
    vals[i] = s;
    s += d;
  }
  sd[t] = s;
  __syncthreads();
  int mytot = s;
  for (int o = 1; o < 256; o <<= 1) {
    int vprev = (t >= o) ? sd[t - o] : 0;
    __syncthreads();
    sd[t] += vprev;
    __syncthreads();
  }
  int texcl = sd[t] - mytot;
  int cb = chunkoffs[blockIdx.x];
  for (int i = 0; i < 8; ++i) {
    int idx = base + t * 8 + i;
    if (idx < N) rowptr[idx] = cb + texcl + vals[i];
  }
}

__global__ void scatter_kernel(const int* __restrict__ src, const int* __restrict__ dst,
                               const int* __restrict__ rowptr, const int* __restrict__ rank,
                               int* __restrict__ sorted_src, int E) {
  for (int e = blockIdx.x * blockDim.x + threadIdx.x; e < E; e += gridDim.x * blockDim.x) {
    int d = dst[e];
    int pos = rowptr[d] + rank[e];
    sorted_src[pos] = src[e];
  }
}

// ---------- 4. per-dst softmax (no max; range-safe) + aggregation; fp8 k/v ----------
// 1 wave per node (grid-stride). lane = (g = edge slot 0-3, s = sublane 0-15);
// sublane s owns channels 8s..8s+7; head = s>>2; 4 edges per iteration.
// Inner loop in packed f32x2 arithmetic (v_pk_fma_f32 / v_pk_mul_f32).
__global__ __launch_bounds__(256) void attn_kernel(
    const unsigned short* __restrict__ q, const unsigned char* __restrict__ k8,
    const unsigned char* __restrict__ v8, const unsigned short* __restrict__ skp,
    const int* __restrict__ rowptr, const int* __restrict__ sorted_src,
    unsigned short* __restrict__ conv, int N, int nw) {
  int lane = threadIdx.x & 63;
  int g = lane >> 4;
  int s = lane & 15;
  int w0 = blockIdx.x * (blockDim.x >> 6) + (threadIdx.x >> 6);
  const float ASC = 0.17677669529663687f;  // 1/sqrt(32)
  for (int n = w0; n < N; n += nw) {
    int beg = rowptr[n], end = rowptr[n + 1];
    size_t rowb = (size_t)n * CH + s * 8;
    uint4 qr = *reinterpret_cast<const uint4*>(q + rowb);
    f32x2 qv[4];
    {
      f16x2 t0 = __builtin_bit_cast(f16x2, qr.x);
      f16x2 t1 = __builtin_bit_cast(f16x2, qr.y);
      f16x2 t2 = __builtin_bit_cast(f16x2, qr.z);
      f16x2 t3 = __builtin_bit_cast(f16x2, qr.w);
      qv[0] = (f32x2){(float)t0[0] * ASC, (float)t0[1] * ASC};
      qv[1] = (f32x2){(float)t1[0] * ASC, (float)t1[1] * ASC};
      qv[2] = (f32x2){(float)t2[0] * ASC, (float)t2[1] * ASC};
      qv[3] = (f32x2){(float)t3[0] * ASC, (float)t3[1] * ASC};
    }
    float ssum = 0.f;
    f32x2 vA = (f32x2){0.f, 0.f}, vB = vA, vC = vA, vD = vA;
    int nit = (end - beg + 3) >> 2;
    for (int it = 0; it < nit; ++it) {
      int e = beg + it * 4 + g;
      bool valid = e < end;
      int src = sorted_src[valid ? e : beg];
      size_t sb = (size_t)src * CH + s * 8;
      uint2 kr = *reinterpret_cast<const uint2*>(k8 + sb);
      uint2 vr = *reinterpret_cast<const uint2*>(v8 + sb);
      f32x2 pacc = upkfp8<false>(kr.x) * qv[0];
      pacc += upkfp8<true>(kr.x) * qv[1];
      pacc += upkfp8<false>(kr.y) * qv[2];
      pacc += upkfp8<true>(kr.y) * qv[3];
      float p = pacc[0] + pacc[1];
      p += __shfl_xor(p, 1);
      p += __shfl_xor(p, 2);  // full 32-ch head dot
      float ex = valid ? __expf(p) : 0.f;
      ssum += ex;
      f32x2 e2 = (f32x2){ex, ex};
      vA += e2 * upkfp8<false>(vr.x);
      vB += e2 * upkfp8<true>(vr.x);
      vC += e2 * upkfp8<false>(vr.y);
      vD += e2 * upkfp8<true>(vr.y);
    }
    float va[8] = {vA[0], vA[1], vB[0], vB[1], vC[0], vC[1], vD[0], vD[1]};
#pragma unroll
    for (int msk = 16; msk <= 32; msk <<= 1) {
      ssum += __shfl_xor(ssum, msk);
#pragma unroll
      for (int i = 0; i < 8; ++i) va[i] += __shfl_xor(va[i], msk);
    }
    float inv = (end > beg) ? 1.0f / ssum : 0.f;
    if (g == 0) {
      uint4 sr = *reinterpret_cast<const uint4*>(skp + rowb);
      f16x2 s0 = __builtin_bit_cast(f16x2, sr.x);
      f16x2 s1 = __builtin_bit_cast(f16x2, sr.y);
      f16x2 s2 = __builtin_bit_cast(f16x2, sr.z);
      f16x2 s3 = __builtin_bit_cast(f16x2, sr.w);
      int4 pk;
      pk.x = (int)f2bf(va[0] * inv + (float)s0[0]) | ((int)f2bf(va[1] * inv + (float)s0[1]) << 16);
      pk.y = (int)f2bf(va[2] * inv + (float)s1[0]) | ((int)f2bf(va[3] * inv + (float)s1[1]) << 16);
      pk.z = (int)f2bf(va[4] * inv + (float)s2[0]) | ((int)f2bf(va[5] * inv + (float)s2[1]) << 16);
      pk.w = (int)f2bf(va[6] * inv + (float)s3[0]) | ((int)f2bf(va[7] * inv + (float)s3[1]) << 16);
      *reinterpret_cast<int4*>(conv + rowb) = pk;
    }
  }
}

// ---------- 5. out = conv @ Wfc + bfc + x via MFMA (swapped; float4 epilogue) ----------
__global__ __launch_bounds__(256) void final_mfma_kernel(
    const unsigned short* __restrict__ conv, const unsigned short* __restrict__ Wt,
    const float* __restrict__ bfc, const float* __restrict__ x,
    float* __restrict__ outp, int N) {
  __shared__ __align__(16) unsigned short As[64 * 128];
  int t = threadIdx.x;
  int lane = t & 63;
  int wid = t >> 6;
  size_t row0 = (size_t)blockIdx.x * 64;

  for (int i = 0; i < 4; ++i) {
    int c = i * 256 + t;
    int r = c >> 4;
    int kc = (c & 15) * 8;
    int4 pk = make_int4(0, 0, 0, 0);
    if (row0 + r < (size_t)N)
      pk = *reinterpret_cast<const int4*>(conv + (row0 + r) * CH + kc);
    int byte = (r * 256 + kc * 2) ^ ((r & 7) << 4);
    *reinterpret_cast<int4*>((char*)As + byte) = pk;
  }
  __syncthreads();

  const unsigned short* wt = Wt + ((size_t)4 << 14);
  int lr = lane & 15;
  int lg = lane >> 4;

  f32x4 acc[4][2];
#pragma unroll
  for (int mt = 0; mt < 4; ++mt)
#pragma unroll
    for (int i = 0; i < 2; ++i) acc[mt][i] = (f32x4){0.f, 0.f, 0.f, 0.f};

  for (int ks = 0; ks < 4; ++ks) {
    bf16x8 a[4], b[2];
#pragma unroll
    for (int mt = 0; mt < 4; ++mt) {
      int r = mt * 16 + lr;
      int byte = (r * 256 + (ks * 32 + lg * 8) * 2) ^ ((r & 7) << 4);
      a[mt] = *reinterpret_cast<const bf16x8*>((const char*)As + byte);
    }
#pragma unroll
    for (int i = 0; i < 2; ++i) {
      int n = (wid * 2 + i) * 16 + lr;
      b[i] = *reinterpret_cast<const bf16x8*>(wt + n * 128 + ks * 32 + lg * 8);
    }
#pragma unroll
    for (int mt = 0; mt < 4; ++mt)
#pragma unroll
      for (int i = 0; i < 2; ++i)
        acc[mt][i] = __builtin_amdgcn_mfma_f32_16x16x32_bf16(b[i], a[mt], acc[mt][i], 0, 0, 0);
  }

#pragma unroll
  for (int mt = 0; mt < 4; ++mt) {
    size_t row = row0 + mt * 16 + lr;
    if (row < (size_t)N) {
#pragma unroll
      for (int i = 0; i < 2; ++i) {
        int cb = (wid * 2 + i) * 16 + lg * 4;
        float4 bb = *reinterpret_cast<const float4*>(bfc + cb);
        float4 rx = *reinterpret_cast<const float4*>(x + row * CH + cb);
        float4 o;
        o.x = acc[mt][i][0] + bb.x + rx.x;
        o.y = acc[mt][i][1] + bb.y + rx.y;
        o.z = acc[mt][i][2] + bb.z + rx.z;
        o.w = acc[mt][i][3] + bb.w + rx.w;
        *reinterpret_cast<float4*>(outp + row * CH + cb) = o;
      }
    }
  }
}

// ---------------------------------------------------------------
extern "C" void kernel_launch(void* const* d_in, const int* in_sizes, int n_in,
                              void* d_out, int out_size, void* d_ws, size_t ws_size,
                              hipStream_t stream) {
  const float* x = (const float*)d_in[0];
  const int* ei = (const int*)d_in[1];
  const float* gamma = (const float*)d_in[2];
  const float* beta = (const float*)d_in[3];
  const float* Wq = (const float*)d_in[4];
  const float* bq = (const float*)d_in[5];
  const float* Wk = (const float*)d_in[6];
  const float* bk = (const float*)d_in[7];
  const float* Wv = (const float*)d_in[8];
  const float* bv = (const float*)d_in[9];
  const float* Ws = (const float*)d_in[10];
  const float* bs = (const float*)d_in[11];
  const float* Wfc = (const float*)d_in[12];
  const float* bfc = (const float*)d_in[13];

  const int N = in_sizes[0] / CH;
  const int E = in_sizes[1] / 2;
  const int* srcp = ei;
  const int* dstp = ei + E;
  float* outp = (float*)d_out;

  char* wsb = (char*)d_ws;
  size_t off = 0;
  auto take = [&](size_t bytes) -> void* {
    void* p = wsb + off;
    off = (off + bytes + 255) & ~(size_t)255;
    return p;
  };
  float* stats = (float*)take(256 * 4);
  float* scsh = (float*)take(256 * 4);
  unsigned short* Wt = (unsigned short*)take((size_t)5 * 16384 * 2);
  unsigned short* qb = (unsigned short*)take((size_t)N * CH * 2);
  unsigned char* kb8 = (unsigned char*)take((size_t)N * CH);
  unsigned char* vb8 = (unsigned char*)take((size_t)N * CH);
  unsigned short* sb = (unsigned short*)take((size_t)N * CH * 2);
  unsigned short* convb = (unsigned short*)take((size_t)N * CH * 2);
  int* deg = (int*)take((size_t)N * 4);
  int* rank = (int*)take((size_t)E * 4);
  int* rowptr = (int*)take((size_t)(N + 1) * 4);
  int nchunks = (N + 2047) / 2048;
  int* chunksums = (int*)take((size_t)nchunks * 4);
  int* chunkoffs = (int*)take((size_t)nchunks * 4);
  int* sorted_src = (int*)take((size_t)E * 4);

  (void)hipMemsetAsync(stats, 0, 256 * 4, stream);
  (void)hipMemsetAsync(deg, 0, (size_t)N * 4, stream);

  bn_stats_kernel<<<512, 256, 0, stream>>>(x, stats, N);
  bn_finalize_kernel<<<1, 128, 0, stream>>>(stats, gamma, beta, scsh, N);
  pack_w_kernel<<<320, 256, 0, stream>>>(Wq, Wk, Wv, Ws, Wfc, Wt);

  int nblk = (N + 63) / 64;
  proj_mfma_kernel<<<nblk, 256, 0, stream>>>(x, scsh, Wt, bq, bk, bv, bs, qb, kb8, vb8, sb, N);

  deg_rank_kernel<<<2048, 256, 0, stream>>>(dstp, deg, rank, E);
  sum_chunks_kernel<<<nchunks, 256, 0, stream>>>(deg, chunksums, N);
  scan_sums_kernel<<<1, 64, 0, stream>>>(chunksums, chunkoffs, nchunks, rowptr, N);
  scan_chunks_kernel<<<nchunks, 256, 0, stream>>>(deg, chunkoffs, rowptr, N);
  scatter_kernel<<<2048, 256, 0, stream>>>(srcp, dstp, rowptr, rank, sorted_src, E);

  int ablocks = 4096;
  attn_kernel<<<ablocks, 256, 0, stream>>>(qb, kb8, vb8, sb, rowptr, sorted_src, convb, N,
                                           ablocks * 4);
  final_mfma_kernel<<<nblk, 256, 0, stream>>>(convb, Wt, bfc, x, outp, N);
}

// Round 11
// 326.264 us; speedup vs baseline: 2.2211x; 1.0488x over previous
//
#include <hip/hip_runtime.h>

#define CH 128  // channels = H*D = 4*32

typedef short bf16x8 __attribute__((ext_vector_type(8)));
typedef float f32x4 __attribute__((ext_vector_type(4)));
typedef float f32x2 __attribute__((ext_vector_type(2)));
typedef _Float16 f16x2 __attribute__((ext_vector_type(2)));

// ---------- helpers ----------
static __device__ __forceinline__ unsigned short f2bf(float f) {
  union { float f; unsigned int i; } c;
  c.f = f;
  unsigned int r = c.i + 0x7fffu + ((c.i >> 16) & 1u);  // RNE
  return (unsigned short)(r >> 16);
}

// fp8 e4m3 fallbacks (used only if builtins are missing)
static __device__ float fp82f_sw(unsigned int b) {
  int sgn = (b >> 7) & 1;
  int e = (b >> 3) & 15;
  int m = b & 7;
  float v = e ? ldexpf(1.f + m * 0.125f, e - 7) : ldexpf((float)m, -9);
  return sgn ? -v : v;
}
static __device__ unsigned char f2fp8_sw(float f) {
  unsigned char s = (f < 0.f) ? 0x80 : 0;
  float af = fabsf(f);
  if (!(af < 448.f)) return s | 0x7e;
  int ex;
  frexpf(af, &ex);
  int e = ex - 1;
  if (e < -6) e = -6;
  float step = ldexpf(1.f, e - 3);
  float qq = rintf(af / step);
  if (qq >= 16.f) { qq = 8.f; e += 1; }
  if (e > 8) return s | 0x7e;
  unsigned char bits = (qq < 8.f) ? (unsigned char)qq
                                  : (unsigned char)(((e + 7) << 3) | ((int)qq - 8));
  return s | bits;
}
template <bool HI>
static __device__ __forceinline__ unsigned int pkfp8(float a, float b, unsigned int old) {
#if __has_builtin(__builtin_amdgcn_cvt_pk_fp8_f32)
  return (unsigned int)__builtin_amdgcn_cvt_pk_fp8_f32(a, b, (int)old, HI);
#else
  unsigned int w = ((unsigned)f2fp8_sw(a)) | (((unsigned)f2fp8_sw(b)) << 8);
  return HI ? ((old & 0x0000ffffu) | (w << 16)) : ((old & 0xffff0000u) | w);
#endif
}
template <bool HI>
static __device__ __forceinline__ f32x2 upkfp8(unsigned int src) {
#if __has_builtin(__builtin_amdgcn_cvt_pk_f32_fp8)
  return __builtin_amdgcn_cvt_pk_f32_fp8((int)src, HI);
#else
  unsigned int h = HI ? (src >> 16) : (src & 0xffffu);
  f32x2 r;
  r[0] = fp82f_sw(h & 0xff);
  r[1] = fp82f_sw((h >> 8) & 0xff);
  return r;
#endif
}

// ---------- 1. BatchNorm statistics ----------
__global__ void bn_stats_kernel(const float* __restrict__ x, float* __restrict__ stats, int N) {
  int t = threadIdx.x;
  int ch = t & (CH - 1);
  int r0 = t >> 7;
  float s = 0.f, ss = 0.f;
  for (int row = blockIdx.x * 2 + r0; row < N; row += gridDim.x * 2) {
    float v = x[(size_t)row * CH + ch];
    s += v;
    ss += v * v;
  }
  atomicAdd(&stats[ch], s);
  atomicAdd(&stats[CH + ch], ss);
}

// ---------- 1b. pack weights: Wt[mat][n][k] bf16, mats = q,k,v,skip,fc ----------
__global__ void pack_w_kernel(const float* __restrict__ Wq, const float* __restrict__ Wk,
                              const float* __restrict__ Wv, const float* __restrict__ Ws,
                              const float* __restrict__ Wfc, unsigned short* __restrict__ Wt) {
  int el = blockIdx.x * 256 + threadIdx.x;  // 5*16384 elements
  int mat = el >> 14;
  int rem = el & 16383;
  int kk = rem >> 7;
  int n = rem & 127;
  const float* W = mat == 0 ? Wq : mat == 1 ? Wk : mat == 2 ? Wv : mat == 3 ? Ws : Wfc;
  Wt[((size_t)mat << 14) + n * 128 + kk] = f2bf(W[kk * 128 + n]);
}

// ---------- 2. fused BN+ReLU + 4 projections via MFMA ----------
// BN scale/shift derived per-block from stats (bn_finalize folded in).
// Swapped-operand MFMA: lane holds 4 consecutive output channels of one node row.
// wave 0 -> q (f16), wave 1 -> k (fp8), wave 2 -> v (fp8), wave 3 -> skip (f16)
__global__ __launch_bounds__(256, 2) void proj_mfma_kernel(
    const float* __restrict__ x, const float* __restrict__ stats,
    const float* __restrict__ gamma, const float* __restrict__ beta,
    const unsigned short* __restrict__ Wt,
    const float* __restrict__ bq_, const float* __restrict__ bk_,
    const float* __restrict__ bv_, const float* __restrict__ bs_,
    unsigned short* __restrict__ q, unsigned char* __restrict__ k8,
    unsigned char* __restrict__ v8, unsigned short* __restrict__ s_, int N) {
  __shared__ __align__(16) unsigned short As[64 * 128];  // 16KB, XOR-swizzled
  __shared__ __align__(16) float scsh[256];
  int t = threadIdx.x;
  int lane = t & 63;
  int wid = t >> 6;
  size_t row0 = (size_t)blockIdx.x * 64;

  if (t < CH) {
    float inv_n = 1.0f / (float)N;
    float mu = stats[t] * inv_n;
    float var = stats[CH + t] * inv_n - mu * mu;
    float sc = gamma[t] * rsqrtf(var + 1e-5f);
    scsh[t] = sc;
    scsh[CH + t] = beta[t] - mu * sc;
  }
  __syncthreads();

  for (int i = 0; i < 4; ++i) {
    int c = i * 256 + t;
    int r = c >> 4;
    int kc = (c & 15) * 8;
    float4 v0 = make_float4(0.f, 0.f, 0.f, 0.f), v1 = v0;
    if (row0 + r < (size_t)N) {
      const float* g = x + (row0 + r) * CH + kc;
      v0 = *reinterpret_cast<const float4*>(g);
      v1 = *reinterpret_cast<const float4*>(g + 4);
    }
    float4 sca = *reinterpret_cast<const float4*>(scsh + kc);
    float4 scb = *reinterpret_cast<const float4*>(scsh + kc + 4);
    float4 sha = *reinterpret_cast<const float4*>(scsh + CH + kc);
    float4 shb = *reinterpret_cast<const float4*>(scsh + CH + kc + 4);
    unsigned short h[8];
    h[0] = f2bf(fmaxf(fmaf(v0.x, sca.x, sha.x), 0.f));
    h[1] = f2bf(fmaxf(fmaf(v0.y, sca.y, sha.y), 0.f));
    h[2] = f2bf(fmaxf(fmaf(v0.z, sca.z, sha.z), 0.f));
    h[3] = f2bf(fmaxf(fmaf(v0.w, sca.w, sha.w), 0.f));
    h[4] = f2bf(fmaxf(fmaf(v1.x, scb.x, shb.x), 0.f));
    h[5] = f2bf(fmaxf(fmaf(v1.y, scb.y, shb.y), 0.f));
    h[6] = f2bf(fmaxf(fmaf(v1.z, scb.z, shb.z), 0.f));
    h[7] = f2bf(fmaxf(fmaf(v1.w, scb.w, shb.w), 0.f));
    int4 pk;
    pk.x = (int)h[0] | ((int)h[1] << 16);
    pk.y = (int)h[2] | ((int)h[3] << 16);
    pk.z = (int)h[4] | ((int)h[5] << 16);
    pk.w = (int)h[6] | ((int)h[7] << 16);
    int byte = (r * 256 + kc * 2) ^ ((r & 7) << 4);
    *reinterpret_cast<int4*>((char*)As + byte) = pk;
  }
  __syncthreads();

  const unsigned short* wt = Wt + ((size_t)wid << 14);
  const float* bias = wid == 0 ? bq_ : wid == 1 ? bk_ : wid == 2 ? bv_ : bs_;
  int lr = lane & 15;
  int lg = lane >> 4;

  f32x4 acc[4][8];
#pragma unroll
  for (int mt = 0; mt < 4; ++mt)
#pragma unroll
    for (int nt = 0; nt < 8; ++nt) acc[mt][nt] = (f32x4){0.f, 0.f, 0.f, 0.f};

  for (int ks = 0; ks < 4; ++ks) {
    bf16x8 a[4], b[8];
#pragma unroll
    for (int mt = 0; mt < 4; ++mt) {
      int r = mt * 16 + lr;
      int byte = (r * 256 + (ks * 32 + lg * 8) * 2) ^ ((r & 7) << 4);
      a[mt] = *reinterpret_cast<const bf16x8*>((const char*)As + byte);
    }
#pragma unroll
    for (int nt = 0; nt < 8; ++nt)
      b[nt] = *reinterpret_cast<const bf16x8*>(wt + (nt * 16 + lr) * 128 + ks * 32 + lg * 8);
    // swapped operands: D[ch][node] -> lane holds node=lr, channels nt*16+lg*4+j
#pragma unroll
    for (int mt = 0; mt < 4; ++mt)
#pragma unroll
      for (int nt = 0; nt < 8; ++nt)
        acc[mt][nt] = __builtin_amdgcn_mfma_f32_16x16x32_bf16(b[nt], a[mt], acc[mt][nt], 0, 0, 0);
  }

  bool isfp8 = (wid == 1) || (wid == 2);
  unsigned short* o16 = (wid == 0) ? q : s_;
  unsigned char* o8 = (wid == 1) ? k8 : v8;
#pragma unroll
  for (int mt = 0; mt < 4; ++mt) {
    size_t row = row0 + mt * 16 + lr;
    if (row < (size_t)N) {
#pragma unroll
      for (int nt = 0; nt < 8; ++nt) {
        int cb = nt * 16 + lg * 4;
        float4 bb = *reinterpret_cast<const float4*>(bias + cb);
        float o0 = acc[mt][nt][0] + bb.x;
        float o1 = acc[mt][nt][1] + bb.y;
        float o2 = acc[mt][nt][2] + bb.z;
        float o3 = acc[mt][nt][3] + bb.w;
        if (isfp8) {
          unsigned int w = pkfp8<false>(o0, o1, 0u);
          w = pkfp8<true>(o2, o3, w);
          *reinterpret_cast<unsigned int*>(o8 + row * CH + cb) = w;
        } else {
          ushort4 u;
          u.x = __builtin_bit_cast(unsigned short, (_Float16)o0);
          u.y = __builtin_bit_cast(unsigned short, (_Float16)o1);
          u.z = __builtin_bit_cast(unsigned short, (_Float16)o2);
          u.w = __builtin_bit_cast(unsigned short, (_Float16)o3);
          *reinterpret_cast<ushort4*>(o16 + row * CH + cb) = u;
        }
      }
    }
  }
}

// ---------- 3. CSR build over dst (rank trick: deg_rank then atomic-free scatter) ----------
__global__ void deg_rank_kernel(const int* __restrict__ dst, int* __restrict__ deg,
                                int* __restrict__ rank, int E) {
  for (int e = blockIdx.x * blockDim.x + threadIdx.x; e < E; e += gridDim.x * blockDim.x) {
    rank[e] = atomicAdd(&deg[dst[e]], 1);
  }
}

__global__ void sum_chunks_kernel(const int* __restrict__ deg, int* __restrict__ chunksums, int N) {
  __shared__ int sd[256];
  int t = threadIdx.x;
  int base = blockIdx.x * 2048;
  int s = 0;
  for (int i = 0; i < 8; ++i) {
    int idx = base + t * 8 + i;
    if (idx < N) s += deg[idx];
  }
  sd[t] = s;
  __syncthreads();
  for (int o = 128; o > 0; o >>= 1) {
    if (t < o) sd[t] += sd[t + o];
    __syncthreads();
  }
  if (t == 0) chunksums[blockIdx.x] = sd[0];
}

// scan_chunks with inlined scan_sums: each block derives its base from chunksums.
__global__ void scan_chunks_kernel(const int* __restrict__ deg, const int* __restrict__ chunksums,
                                   int* __restrict__ rowptr, int N, int nchunks) {
  __shared__ int sd[256];
  __shared__ int base_off;
  int t = threadIdx.x;
  int cb = blockIdx.x;
  // base = sum of chunksums[0..cb)
  int pre = 0;
  for (int i = t; i < cb; i += 256) pre += chunksums[i];
  sd[t] = pre;
  __syncthreads();
  for (int o = 128; o > 0; o >>= 1) {
    if (t < o) sd[t] += sd[t + o];
    __syncthreads();
  }
  if (t == 0) base_off = sd[0];
  __syncthreads();
  int cbase = base_off;
  __syncthreads();  // sd reused below

  int base = cb * 2048;
  int vals[8];
  int s = 0;
  for (int i = 0; i < 8; ++i) {
    int idx = base + t * 8 + i;
    int d = (idx < N) ? deg[idx] : 0;
    vals[i] = s;
    s += d;
  }
  sd[t] = s;
  __syncthreads();
  int mytot = s;
  for (int o = 1; o < 256; o <<= 1) {
    int vprev = (t >= o) ? sd[t - o] : 0;
    __syncthreads();
    sd[t] += vprev;
    __syncthreads();
  }
  int texcl = sd[t] - mytot;
  for (int i = 0; i < 8; ++i) {
    int idx = base + t * 8 + i;
    if (idx < N) rowptr[idx] = cbase + texcl + vals[i];
  }
  if (cb == nchunks - 1 && t == 255) rowptr[N] = cbase + sd[255];
}

__global__ void scatter_kernel(const int* __restrict__ src, const int* __restrict__ dst,
                               const int* __restrict__ rowptr, const int* __restrict__ rank,
                               int* __restrict__ sorted_src, int E) {
  for (int e = blockIdx.x * blockDim.x + threadIdx.x; e < E; e += gridDim.x * blockDim.x) {
    int d = dst[e];
    int pos = rowptr[d] + rank[e];
    sorted_src[pos] = src[e];
  }
}

// ---------- 4. per-dst softmax (no max; range-safe) + aggregation; fp8 k/v ----------
// 1 wave per node (grid-stride). lane = (g = edge slot 0-3, s = sublane 0-15);
// sublane s owns channels 8s..8s+7; head = s>>2; 8 edges per iteration (2 slots,
// all loads issued up front for memory-level parallelism).
__global__ __launch_bounds__(256) void attn_kernel(
    const unsigned short* __restrict__ q, const unsigned char* __restrict__ k8,
    const unsigned char* __restrict__ v8, const unsigned short* __restrict__ skp,
    const int* __restrict__ rowptr, const int* __restrict__ sorted_src,
    unsigned short* __restrict__ conv, int N, int nw) {
  int lane = threadIdx.x & 63;
  int g = lane >> 4;
  int s = lane & 15;
  int w0 = blockIdx.x * (blockDim.x >> 6) + (threadIdx.x >> 6);
  const float ASC = 0.17677669529663687f;  // 1/sqrt(32)
  for (int n = w0; n < N; n += nw) {
    int beg = rowptr[n], end = rowptr[n + 1];
    size_t rowb = (size_t)n * CH + s * 8;
    uint4 qr = *reinterpret_cast<const uint4*>(q + rowb);
    f32x2 qv[4];
    {
      f16x2 t0 = __builtin_bit_cast(f16x2, qr.x);
      f16x2 t1 = __builtin_bit_cast(f16x2, qr.y);
      f16x2 t2 = __builtin_bit_cast(f16x2, qr.z);
      f16x2 t3 = __builtin_bit_cast(f16x2, qr.w);
      qv[0] = (f32x2){(float)t0[0] * ASC, (float)t0[1] * ASC};
      qv[1] = (f32x2){(float)t1[0] * ASC, (float)t1[1] * ASC};
      qv[2] = (f32x2){(float)t2[0] * ASC, (float)t2[1] * ASC};
      qv[3] = (f32x2){(float)t3[0] * ASC, (float)t3[1] * ASC};
    }
    float ssum = 0.f;
    f32x2 vA = (f32x2){0.f, 0.f}, vB = vA, vC = vA, vD = vA;
    int nit2 = (end - beg + 7) >> 3;
    for (int it = 0; it < nit2; ++it) {
      int e0 = beg + it * 8 + g;
      int e1 = e0 + 4;
      bool v0 = e0 < end;
      bool v1 = e1 < end;
      // issue all independent loads up front (MLP)
      int src0 = sorted_src[v0 ? e0 : beg];
      int src1 = sorted_src[v1 ? e1 : beg];
      size_t sb0 = (size_t)src0 * CH + s * 8;
      size_t sb1 = (size_t)src1 * CH + s * 8;
      uint2 kr0 = *reinterpret_cast<const uint2*>(k8 + sb0);
      uint2 vr0 = *reinterpret_cast<const uint2*>(v8 + sb0);
      uint2 kr1 = *reinterpret_cast<const uint2*>(k8 + sb1);
      uint2 vr1 = *reinterpret_cast<const uint2*>(v8 + sb1);
      // slot 0
      f32x2 p0 = upkfp8<false>(kr0.x) * qv[0];
      p0 += upkfp8<true>(kr0.x) * qv[1];
      p0 += upkfp8<false>(kr0.y) * qv[2];
      p0 += upkfp8<true>(kr0.y) * qv[3];
      float pa = p0[0] + p0[1];
      // slot 1
      f32x2 p1 = upkfp8<false>(kr1.x) * qv[0];
      p1 += upkfp8<true>(kr1.x) * qv[1];
      p1 += upkfp8<false>(kr1.y) * qv[2];
      p1 += upkfp8<true>(kr1.y) * qv[3];
      float pb = p1[0] + p1[1];
      pa += __shfl_xor(pa, 1);
      pb += __shfl_xor(pb, 1);
      pa += __shfl_xor(pa, 2);
      pb += __shfl_xor(pb, 2);
      float ex0 = v0 ? __expf(pa) : 0.f;
      float ex1 = v1 ? __expf(pb) : 0.f;
      ssum += ex0 + ex1;
      f32x2 e20 = (f32x2){ex0, ex0};
      f32x2 e21 = (f32x2){ex1, ex1};
      vA += e20 * upkfp8<false>(vr0.x);
      vB += e20 * upkfp8<true>(vr0.x);
      vC += e20 * upkfp8<false>(vr0.y);
      vD += e20 * upkfp8<true>(vr0.y);
      vA += e21 * upkfp8<false>(vr1.x);
      vB += e21 * upkfp8<true>(vr1.x);
      vC += e21 * upkfp8<false>(vr1.y);
      vD += e21 * upkfp8<true>(vr1.y);
    }
    float va[8] = {vA[0], vA[1], vB[0], vB[1], vC[0], vC[1], vD[0], vD[1]};
#pragma unroll
    for (int msk = 16; msk <= 32; msk <<= 1) {
      ssum += __shfl_xor(ssum, msk);
#pragma unroll
      for (int i = 0; i < 8; ++i) va[i] += __shfl_xor(va[i], msk);
    }
    float inv = (end > beg) ? 1.0f / ssum : 0.f;
    if (g == 0) {
      uint4 sr = *reinterpret_cast<const uint4*>(skp + rowb);
      f16x2 s0 = __builtin_bit_cast(f16x2, sr.x);
      f16x2 s1 = __builtin_bit_cast(f16x2, sr.y);
      f16x2 s2 = __builtin_bit_cast(f16x2, sr.z);
      f16x2 s3 = __builtin_bit_cast(f16x2, sr.w);
      int4 pk;
      pk.x = (int)f2bf(va[0] * inv + (float)s0[0]) | ((int)f2bf(va[1] * inv + (float)s0[1]) << 16);
      pk.y = (int)f2bf(va[2] * inv + (float)s1[0]) | ((int)f2bf(va[3] * inv + (float)s1[1]) << 16);
      pk.z = (int)f2bf(va[4] * inv + (float)s2[0]) | ((int)f2bf(va[5] * inv + (float)s2[1]) << 16);
      pk.w = (int)f2bf(va[6] * inv + (float)s3[0]) | ((int)f2bf(va[7] * inv + (float)s3[1]) << 16);
      *reinterpret_cast<int4*>(conv + rowb) = pk;
    }
  }
}

// ---------- 5. out = conv @ Wfc + bfc + x via MFMA (swapped; float4 epilogue) ----------
__global__ __launch_bounds__(256) void final_mfma_kernel(
    const unsigned short* __restrict__ conv, const unsigned short* __restrict__ Wt,
    const float* __restrict__ bfc, const float* __restrict__ x,
    float* __restrict__ outp, int N) {
  __shared__ __align__(16) unsigned short As[64 * 128];
  int t = threadIdx.x;
  int lane = t & 63;
  int wid = t >> 6;
  size_t row0 = (size_t)blockIdx.x * 64;

  for (int i = 0; i < 4; ++i) {
    int c = i * 256 + t;
    int r = c >> 4;
    int kc = (c & 15) * 8;
    int4 pk = make_int4(0, 0, 0, 0);
    if (row0 + r < (size_t)N)
      pk = *reinterpret_cast<const int4*>(conv + (row0 + r) * CH + kc);
    int byte = (r * 256 + kc * 2) ^ ((r & 7) << 4);
    *reinterpret_cast<int4*>((char*)As + byte) = pk;
  }
  __syncthreads();

  const unsigned short* wt = Wt + ((size_t)4 << 14);
  int lr = lane & 15;
  int lg = lane >> 4;

  f32x4 acc[4][2];
#pragma unroll
  for (int mt = 0; mt < 4; ++mt)
#pragma unroll
    for (int i = 0; i < 2; ++i) acc[mt][i] = (f32x4){0.f, 0.f, 0.f, 0.f};

  for (int ks = 0; ks < 4; ++ks) {
    bf16x8 a[4], b[2];
#pragma unroll
    for (int mt = 0; mt < 4; ++mt) {
      int r = mt * 16 + lr;
      int byte = (r * 256 + (ks * 32 + lg * 8) * 2) ^ ((r & 7) << 4);
      a[mt] = *reinterpret_cast<const bf16x8*>((const char*)As + byte);
    }
#pragma unroll
    for (int i = 0; i < 2; ++i) {
      int n = (wid * 2 + i) * 16 + lr;
      b[i] = *reinterpret_cast<const bf16x8*>(wt + n * 128 + ks * 32 + lg * 8);
    }
#pragma unroll
    for (int mt = 0; mt < 4; ++mt)
#pragma unroll
      for (int i = 0; i < 2; ++i)
        acc[mt][i] = __builtin_amdgcn_mfma_f32_16x16x32_bf16(b[i], a[mt], acc[mt][i], 0, 0, 0);
  }

#pragma unroll
  for (int mt = 0; mt < 4; ++mt) {
    size_t row = row0 + mt * 16 + lr;
    if (row < (size_t)N) {
#pragma unroll
      for (int i = 0; i < 2; ++i) {
        int cb = (wid * 2 + i) * 16 + lg * 4;
        float4 bb = *reinterpret_cast<const float4*>(bfc + cb);
        float4 rx = *reinterpret_cast<const float4*>(x + row * CH + cb);
        float4 o;
        o.x = acc[mt][i][0] + bb.x + rx.x;
        o.y = acc[mt][i][1] + bb.y + rx.y;
        o.z = acc[mt][i][2] + bb.z + rx.z;
        o.w = acc[mt][i][3] + bb.w + rx.w;
        *reinterpret_cast<float4*>(outp + row * CH + cb) = o;
      }
    }
  }
}

// ---------------------------------------------------------------
extern "C" void kernel_launch(void* const* d_in, const int* in_sizes, int n_in,
                              void* d_out, int out_size, void* d_ws, size_t ws_size,
                              hipStream_t stream) {
  const float* x = (const float*)d_in[0];
  const int* ei = (const int*)d_in[1];
  const float* gamma = (const float*)d_in[2];
  const float* beta = (const float*)d_in[3];
  const float* Wq = (const float*)d_in[4];
  const float* bq = (const float*)d_in[5];
  const float* Wk = (const float*)d_in[6];
  const float* bk = (const float*)d_in[7];
  const float* Wv = (const float*)d_in[8];
  const float* bv = (const float*)d_in[9];
  const float* Ws = (const float*)d_in[10];
  const float* bs = (const float*)d_in[11];
  const float* Wfc = (const float*)d_in[12];
  const float* bfc = (const float*)d_in[13];

  const int N = in_sizes[0] / CH;
  const int E = in_sizes[1] / 2;
  const int* srcp = ei;
  const int* dstp = ei + E;
  float* outp = (float*)d_out;

  char* wsb = (char*)d_ws;
  size_t off = 0;
  auto take = [&](size_t bytes) -> void* {
    void* p = wsb + off;
    off = (off + bytes + 255) & ~(size_t)255;
    return p;
  };
  float* stats = (float*)take(256 * 4);
  unsigned short* Wt = (unsigned short*)take((size_t)5 * 16384 * 2);
  unsigned short* qb = (unsigned short*)take((size_t)N * CH * 2);
  unsigned char* kb8 = (unsigned char*)take((size_t)N * CH);
  unsigned char* vb8 = (unsigned char*)take((size_t)N * CH);
  unsigned short* sb = (unsigned short*)take((size_t)N * CH * 2);
  unsigned short* convb = (unsigned short*)take((size_t)N * CH * 2);
  int* deg = (int*)take((size_t)N * 4);
  int* rank = (int*)take((size_t)E * 4);
  int* rowptr = (int*)take((size_t)(N + 1) * 4);
  int nchunks = (N + 2047) / 2048;
  int* chunksums = (int*)take((size_t)nchunks * 4);
  int* sorted_src = (int*)take((size_t)E * 4);

  (void)hipMemsetAsync(stats, 0, 256 * 4, stream);
  (void)hipMemsetAsync(deg, 0, (size_t)N * 4, stream);

  bn_stats_kernel<<<512, 256, 0, stream>>>(x, stats, N);
  pack_w_kernel<<<320, 256, 0, stream>>>(Wq, Wk, Wv, Ws, Wfc, Wt);

  int nblk = (N + 63) / 64;
  proj_mfma_kernel<<<nblk, 256, 0, stream>>>(x, stats, gamma, beta, Wt, bq, bk, bv, bs, qb, kb8,
                                             vb8, sb, N);

  deg_rank_kernel<<<2048, 256, 0, stream>>>(dstp, deg, rank, E);
  sum_chunks_kernel<<<nchunks, 256, 0, stream>>>(deg, chunksums, N);
  scan_chunks_kernel<<<nchunks, 256, 0, stream>>>(deg, chunksums, rowptr, N, nchunks);
  scatter_kernel<<<2048, 256, 0, stream>>>(srcp, dstp, rowptr, rank, sorted_src, E);

  int ablocks = 4096;
  attn_kernel<<<ablocks, 256, 0, stream>>>(qb, kb8, vb8, sb, rowptr, sorted_src, convb, N,
                                           ablocks * 4);
  final_mfma_kernel<<<nblk, 256, 0, stream>>>(convb, Wt, bfc, x, outp, N);
}

// Round 12
// 306.987 us; speedup vs baseline: 2.3606x; 1.0628x over previous
//
#include <hip/hip_runtime.h>

#define CH 128  // channels = H*D = 4*32

typedef short bf16x8 __attribute__((ext_vector_type(8)));
typedef float f32x4 __attribute__((ext_vector_type(4)));
typedef float f32x2 __attribute__((ext_vector_type(2)));
typedef _Float16 f16x2 __attribute__((ext_vector_type(2)));

// ---------- helpers ----------
static __device__ __forceinline__ unsigned short f2bf(float f) {
  union { float f; unsigned int i; } c;
  c.f = f;
  unsigned int r = c.i + 0x7fffu + ((c.i >> 16) & 1u);  // RNE
  return (unsigned short)(r >> 16);
}

// fp8 e4m3 fallbacks (used only if builtins are missing)
static __device__ float fp82f_sw(unsigned int b) {
  int sgn = (b >> 7) & 1;
  int e = (b >> 3) & 15;
  int m = b & 7;
  float v = e ? ldexpf(1.f + m * 0.125f, e - 7) : ldexpf((float)m, -9);
  return sgn ? -v : v;
}
static __device__ unsigned char f2fp8_sw(float f) {
  unsigned char s = (f < 0.f) ? 0x80 : 0;
  float af = fabsf(f);
  if (!(af < 448.f)) return s | 0x7e;
  int ex;
  frexpf(af, &ex);
  int e = ex - 1;
  if (e < -6) e = -6;
  float step = ldexpf(1.f, e - 3);
  float qq = rintf(af / step);
  if (qq >= 16.f) { qq = 8.f; e += 1; }
  if (e > 8) return s | 0x7e;
  unsigned char bits = (qq < 8.f) ? (unsigned char)qq
                                  : (unsigned char)(((e + 7) << 3) | ((int)qq - 8));
  return s | bits;
}
template <bool HI>
static __device__ __forceinline__ unsigned int pkfp8(float a, float b, unsigned int old) {
#if __has_builtin(__builtin_amdgcn_cvt_pk_fp8_f32)
  return (unsigned int)__builtin_amdgcn_cvt_pk_fp8_f32(a, b, (int)old, HI);
#else
  unsigned int w = ((unsigned)f2fp8_sw(a)) | (((unsigned)f2fp8_sw(b)) << 8);
  return HI ? ((old & 0x0000ffffu) | (w << 16)) : ((old & 0xffff0000u) | w);
#endif
}
template <bool HI>
static __device__ __forceinline__ f32x2 upkfp8(unsigned int src) {
#if __has_builtin(__builtin_amdgcn_cvt_pk_f32_fp8)
  return __builtin_amdgcn_cvt_pk_f32_fp8((int)src, HI);
#else
  unsigned int h = HI ? (src >> 16) : (src & 0xffffu);
  f32x2 r;
  r[0] = fp82f_sw(h & 0xff);
  r[1] = fp82f_sw((h >> 8) & 0xff);
  return r;
#endif
}

// ---------- 1. BatchNorm statistics ----------
__global__ void bn_stats_kernel(const float* __restrict__ x, float* __restrict__ stats, int N) {
  int t = threadIdx.x;
  int ch = t & (CH - 1);
  int r0 = t >> 7;
  float s = 0.f, ss = 0.f;
  for (int row = blockIdx.x * 2 + r0; row < N; row += gridDim.x * 2) {
    float v = x[(size_t)row * CH + ch];
    s += v;
    ss += v * v;
  }
  atomicAdd(&stats[ch], s);
  atomicAdd(&stats[CH + ch], ss);
}

// ---------- 1b. pack weights: Wt[mat][n][k] bf16, mats = q,k,v,skip,fc ----------
__global__ void pack_w_kernel(const float* __restrict__ Wq, const float* __restrict__ Wk,
                              const float* __restrict__ Wv, const float* __restrict__ Ws,
                              const float* __restrict__ Wfc, unsigned short* __restrict__ Wt) {
  int el = blockIdx.x * 256 + threadIdx.x;  // 5*16384 elements
  int mat = el >> 14;
  int rem = el & 16383;
  int kk = rem >> 7;
  int n = rem & 127;
  const float* W = mat == 0 ? Wq : mat == 1 ? Wk : mat == 2 ? Wv : mat == 3 ? Ws : Wfc;
  Wt[((size_t)mat << 14) + n * 128 + kk] = f2bf(W[kk * 128 + n]);
}

// ---------- 2. fused BN+ReLU + 4 projections via MFMA ----------
// BN scale/shift derived per-block from stats. Swapped-operand MFMA; epilogue
// staged through per-wave 4KB LDS region -> full-cache-line coalesced stores.
// wave 0 -> q (f16), wave 1 -> k (fp8), wave 2 -> v (fp8), wave 3 -> skip (f16)
__global__ __launch_bounds__(256, 2) void proj_mfma_kernel(
    const float* __restrict__ x, const float* __restrict__ stats,
    const float* __restrict__ gamma, const float* __restrict__ beta,
    const unsigned short* __restrict__ Wt,
    const float* __restrict__ bq_, const float* __restrict__ bk_,
    const float* __restrict__ bv_, const float* __restrict__ bs_,
    unsigned short* __restrict__ q, unsigned char* __restrict__ k8,
    unsigned char* __restrict__ v8, unsigned short* __restrict__ s_, int N) {
  __shared__ __align__(16) unsigned short As[64 * 128];  // 16KB, XOR-swizzled
  __shared__ __align__(16) float scsh[256];
  int t = threadIdx.x;
  int lane = t & 63;
  int wid = t >> 6;
  size_t row0 = (size_t)blockIdx.x * 64;

  if (t < CH) {
    float inv_n = 1.0f / (float)N;
    float mu = stats[t] * inv_n;
    float var = stats[CH + t] * inv_n - mu * mu;
    float sc = gamma[t] * rsqrtf(var + 1e-5f);
    scsh[t] = sc;
    scsh[CH + t] = beta[t] - mu * sc;
  }
  __syncthreads();

  for (int i = 0; i < 4; ++i) {
    int c = i * 256 + t;
    int r = c >> 4;
    int kc = (c & 15) * 8;
    float4 v0 = make_float4(0.f, 0.f, 0.f, 0.f), v1 = v0;
    if (row0 + r < (size_t)N) {
      const float* g = x + (row0 + r) * CH + kc;
      v0 = *reinterpret_cast<const float4*>(g);
      v1 = *reinterpret_cast<const float4*>(g + 4);
    }
    float4 sca = *reinterpret_cast<const float4*>(scsh + kc);
    float4 scb = *reinterpret_cast<const float4*>(scsh + kc + 4);
    float4 sha = *reinterpret_cast<const float4*>(scsh + CH + kc);
    float4 shb = *reinterpret_cast<const float4*>(scsh + CH + kc + 4);
    unsigned short h[8];
    h[0] = f2bf(fmaxf(fmaf(v0.x, sca.x, sha.x), 0.f));
    h[1] = f2bf(fmaxf(fmaf(v0.y, sca.y, sha.y), 0.f));
    h[2] = f2bf(fmaxf(fmaf(v0.z, sca.z, sha.z), 0.f));
    h[3] = f2bf(fmaxf(fmaf(v0.w, sca.w, sha.w), 0.f));
    h[4] = f2bf(fmaxf(fmaf(v1.x, scb.x, shb.x), 0.f));
    h[5] = f2bf(fmaxf(fmaf(v1.y, scb.y, shb.y), 0.f));
    h[6] = f2bf(fmaxf(fmaf(v1.z, scb.z, shb.z), 0.f));
    h[7] = f2bf(fmaxf(fmaf(v1.w, scb.w, shb.w), 0.f));
    int4 pk;
    pk.x = (int)h[0] | ((int)h[1] << 16);
    pk.y = (int)h[2] | ((int)h[3] << 16);
    pk.z = (int)h[4] | ((int)h[5] << 16);
    pk.w = (int)h[6] | ((int)h[7] << 16);
    int byte = (r * 256 + kc * 2) ^ ((r & 7) << 4);
    *reinterpret_cast<int4*>((char*)As + byte) = pk;
  }
  __syncthreads();

  const unsigned short* wt = Wt + ((size_t)wid << 14);
  const float* bias = wid == 0 ? bq_ : wid == 1 ? bk_ : wid == 2 ? bv_ : bs_;
  int lr = lane & 15;
  int lg = lane >> 4;

  f32x4 acc[4][8];
#pragma unroll
  for (int mt = 0; mt < 4; ++mt)
#pragma unroll
    for (int nt = 0; nt < 8; ++nt) acc[mt][nt] = (f32x4){0.f, 0.f, 0.f, 0.f};

  for (int ks = 0; ks < 4; ++ks) {
    bf16x8 a[4], b[8];
#pragma unroll
    for (int mt = 0; mt < 4; ++mt) {
      int r = mt * 16 + lr;
      int byte = (r * 256 + (ks * 32 + lg * 8) * 2) ^ ((r & 7) << 4);
      a[mt] = *reinterpret_cast<const bf16x8*>((const char*)As + byte);
    }
#pragma unroll
    for (int nt = 0; nt < 8; ++nt)
      b[nt] = *reinterpret_cast<const bf16x8*>(wt + (nt * 16 + lr) * 128 + ks * 32 + lg * 8);
    // swapped operands: D[ch][node] -> lane holds node=mt*16+lr, channels nt*16+lg*4+j
#pragma unroll
    for (int mt = 0; mt < 4; ++mt)
#pragma unroll
      for (int nt = 0; nt < 8; ++nt)
        acc[mt][nt] = __builtin_amdgcn_mfma_f32_16x16x32_bf16(b[nt], a[mt], acc[mt][nt], 0, 0, 0);
  }

  // all waves done reading As -> safe to reuse as per-wave staging (4KB each)
  __syncthreads();
  char* reg = (char*)As + wid * 4096;
  bool isfp8 = (wid == 1) || (wid == 2);
  unsigned short* o16 = (wid == 0) ? q : s_;
  unsigned char* o8 = (wid == 1) ? k8 : v8;

  if (!isfp8) {
    // f16: per mt, stage 16 rows x 256B, then 4 coalesced int4 insts (4 full lines/row)
#pragma unroll
    for (int mt = 0; mt < 4; ++mt) {
#pragma unroll
      for (int nt = 0; nt < 8; ++nt) {
        int cb = nt * 16 + lg * 4;
        float4 bb = *reinterpret_cast<const float4*>(bias + cb);
        ushort4 u;
        u.x = __builtin_bit_cast(unsigned short, (_Float16)(acc[mt][nt][0] + bb.x));
        u.y = __builtin_bit_cast(unsigned short, (_Float16)(acc[mt][nt][1] + bb.y));
        u.z = __builtin_bit_cast(unsigned short, (_Float16)(acc[mt][nt][2] + bb.z));
        u.w = __builtin_bit_cast(unsigned short, (_Float16)(acc[mt][nt][3] + bb.w));
        int byte = (lr * 256 + cb * 2) ^ ((lr & 7) << 4);
        *reinterpret_cast<ushort4*>(reg + byte) = u;
      }
#pragma unroll
      for (int i = 0; i < 4; ++i) {
        int r = i * 4 + (lane >> 4);
        int byte = (r * 256 + (lane & 15) * 16) ^ ((r & 7) << 4);
        int4 val = *reinterpret_cast<const int4*>(reg + byte);
        size_t row = row0 + mt * 16 + r;
        if (row < (size_t)N)
          *reinterpret_cast<int4*>(o16 + row * CH + (lane & 15) * 8) = val;
      }
    }
  } else {
    // fp8: per mt, stage 16 rows x 128B, then 2 coalesced int4 insts (2 full lines/row)
#pragma unroll
    for (int mt = 0; mt < 4; ++mt) {
#pragma unroll
      for (int nt = 0; nt < 8; ++nt) {
        int cb = nt * 16 + lg * 4;
        float4 bb = *reinterpret_cast<const float4*>(bias + cb);
        unsigned int w = pkfp8<false>(acc[mt][nt][0] + bb.x, acc[mt][nt][1] + bb.y, 0u);
        w = pkfp8<true>(acc[mt][nt][2] + bb.z, acc[mt][nt][3] + bb.w, w);
        int byte = (lr * 128 + cb) ^ ((lr & 7) << 4);
        *reinterpret_cast<unsigned int*>(reg + byte) = w;
      }
#pragma unroll
      for (int i = 0; i < 2; ++i) {
        int r = i * 8 + (lane >> 3);
        int byte = (r * 128 + (lane & 7) * 16) ^ ((r & 7) << 4);
        int4 val = *reinterpret_cast<const int4*>(reg + byte);
        size_t row = row0 + mt * 16 + r;
        if (row < (size_t)N)
          *reinterpret_cast<int4*>(o8 + row * CH + (lane & 7) * 16) = val;
      }
    }
  }
}

// ---------- 3. CSR build over dst (rank trick: deg_rank then atomic-free scatter) ----------
__global__ void deg_rank_kernel(const int* __restrict__ dst, int* __restrict__ deg,
                                int* __restrict__ rank, int E) {
  for (int e = blockIdx.x * blockDim.x + threadIdx.x; e < E; e += gridDim.x * blockDim.x) {
    rank[e] = atomicAdd(&deg[dst[e]], 1);
  }
}

__global__ void sum_chunks_kernel(const int* __restrict__ deg, int* __restrict__ chunksums, int N) {
  __shared__ int sd[256];
  int t = threadIdx.x;
  int base = blockIdx.x * 2048;
  int s = 0;
  for (int i = 0; i < 8; ++i) {
    int idx = base + t * 8 + i;
    if (idx < N) s += deg[idx];
  }
  sd[t] = s;
  __syncthreads();
  for (int o = 128; o > 0; o >>= 1) {
    if (t < o) sd[t] += sd[t + o];
    __syncthreads();
  }
  if (t == 0) chunksums[blockIdx.x] = sd[0];
}

// scan_chunks with inlined scan_sums: each block derives its base from chunksums.
__global__ void scan_chunks_kernel(const int* __restrict__ deg, const int* __restrict__ chunksums,
                                   int* __restrict__ rowptr, int N, int nchunks) {
  __shared__ int sd[256];
  __shared__ int base_off;
  int t = threadIdx.x;
  int cb = blockIdx.x;
  int pre = 0;
  for (int i = t; i < cb; i += 256) pre += chunksums[i];
  sd[t] = pre;
  __syncthreads();
  for (int o = 128; o > 0; o >>= 1) {
    if (t < o) sd[t] += sd[t + o];
    __syncthreads();
  }
  if (t == 0) base_off = sd[0];
  __syncthreads();
  int cbase = base_off;
  __syncthreads();  // sd reused below

  int base = cb * 2048;
  int vals[8];
  int s = 0;
  for (int i = 0; i < 8; ++i) {
    int idx = base + t * 8 + i;
    int d = (idx < N) ? deg[idx] : 0;
    vals[i] = s;
    s += d;
  }
  sd[t] = s;
  __syncthreads();
  int mytot = s;
  for (int o = 1; o < 256; o <<= 1) {
    int vprev = (t >= o) ? sd[t - o] : 0;
    __syncthreads();
    sd[t] += vprev;
    __syncthreads();
  }
  int texcl = sd[t] - mytot;
  for (int i = 0; i < 8; ++i) {
    int idx = base + t * 8 + i;
    if (idx < N) rowptr[idx] = cbase + texcl + vals[i];
  }
  if (cb == nchunks - 1 && t == 255) rowptr[N] = cbase + sd[255];
}

__global__ void scatter_kernel(const int* __restrict__ src, const int* __restrict__ dst,
                               const int* __restrict__ rowptr, const int* __restrict__ rank,
                               int* __restrict__ sorted_src, int E) {
  for (int e = blockIdx.x * blockDim.x + threadIdx.x; e < E; e += gridDim.x * blockDim.x) {
    int d = dst[e];
    int pos = rowptr[d] + rank[e];
    sorted_src[pos] = src[e];
  }
}

// ---------- 4. per-dst softmax (no max; range-safe) + aggregation; fp8 k/v ----------
// 1 wave per node (grid-stride). 8 edges per iteration (2 slots, loads up front).
__global__ __launch_bounds__(256) void attn_kernel(
    const unsigned short* __restrict__ q, const unsigned char* __restrict__ k8,
    const unsigned char* __restrict__ v8, const unsigned short* __restrict__ skp,
    const int* __restrict__ rowptr, const int* __restrict__ sorted_src,
    unsigned short* __restrict__ conv, int N, int nw) {
  int lane = threadIdx.x & 63;
  int g = lane >> 4;
  int s = lane & 15;
  int w0 = blockIdx.x * (blockDim.x >> 6) + (threadIdx.x >> 6);
  const float ASC = 0.17677669529663687f;  // 1/sqrt(32)
  for (int n = w0; n < N; n += nw) {
    int beg = rowptr[n], end = rowptr[n + 1];
    size_t rowb = (size_t)n * CH + s * 8;
    uint4 qr = *reinterpret_cast<const uint4*>(q + rowb);
    f32x2 qv[4];
    {
      f16x2 t0 = __builtin_bit_cast(f16x2, qr.x);
      f16x2 t1 = __builtin_bit_cast(f16x2, qr.y);
      f16x2 t2 = __builtin_bit_cast(f16x2, qr.z);
      f16x2 t3 = __builtin_bit_cast(f16x2, qr.w);
      qv[0] = (f32x2){(float)t0[0] * ASC, (float)t0[1] * ASC};
      qv[1] = (f32x2){(float)t1[0] * ASC, (float)t1[1] * ASC};
      qv[2] = (f32x2){(float)t2[0] * ASC, (float)t2[1] * ASC};
      qv[3] = (f32x2){(float)t3[0] * ASC, (float)t3[1] * ASC};
    }
    float ssum = 0.f;
    f32x2 vA = (f32x2){0.f, 0.f}, vB = vA, vC = vA, vD = vA;
    int nit2 = (end - beg + 7) >> 3;
    for (int it = 0; it < nit2; ++it) {
      int e0 = beg + it * 8 + g;
      int e1 = e0 + 4;
      bool v0 = e0 < end;
      bool v1 = e1 < end;
      int src0 = sorted_src[v0 ? e0 : beg];
      int src1 = sorted_src[v1 ? e1 : beg];
      size_t sb0 = (size_t)src0 * CH + s * 8;
      size_t sb1 = (size_t)src1 * CH + s * 8;
      uint2 kr0 = *reinterpret_cast<const uint2*>(k8 + sb0);
      uint2 vr0 = *reinterpret_cast<const uint2*>(v8 + sb0);
      uint2 kr1 = *reinterpret_cast<const uint2*>(k8 + sb1);
      uint2 vr1 = *reinterpret_cast<const uint2*>(v8 + sb1);
      f32x2 p0 = upkfp8<false>(kr0.x) * qv[0];
      p0 += upkfp8<true>(kr0.x) * qv[1];
      p0 += upkfp8<false>(kr0.y) * qv[2];
      p0 += upkfp8<true>(kr0.y) * qv[3];
      float pa = p0[0] + p0[1];
      f32x2 p1 = upkfp8<false>(kr1.x) * qv[0];
      p1 += upkfp8<true>(kr1.x) * qv[1];
      p1 += upkfp8<false>(kr1.y) * qv[2];
      p1 += upkfp8<true>(kr1.y) * qv[3];
      float pb = p1[0] + p1[1];
      pa += __shfl_xor(pa, 1);
      pb += __shfl_xor(pb, 1);
      pa += __shfl_xor(pa, 2);
      pb += __shfl_xor(pb, 2);
      float ex0 = v0 ? __expf(pa) : 0.f;
      float ex1 = v1 ? __expf(pb) : 0.f;
      ssum += ex0 + ex1;
      f32x2 e20 = (f32x2){ex0, ex0};
      f32x2 e21 = (f32x2){ex1, ex1};
      vA += e20 * upkfp8<false>(vr0.x);
      vB += e20 * upkfp8<true>(vr0.x);
      vC += e20 * upkfp8<false>(vr0.y);
      vD += e20 * upkfp8<true>(vr0.y);
      vA += e21 * upkfp8<false>(vr1.x);
      vB += e21 * upkfp8<true>(vr1.x);
      vC += e21 * upkfp8<false>(vr1.y);
      vD += e21 * upkfp8<true>(vr1.y);
    }
    float va[8] = {vA[0], vA[1], vB[0], vB[1], vC[0], vC[1], vD[0], vD[1]};
#pragma unroll
    for (int msk = 16; msk <= 32; msk <<= 1) {
      ssum += __shfl_xor(ssum, msk);
#pragma unroll
      for (int i = 0; i < 8; ++i) va[i] += __shfl_xor(va[i], msk);
    }
    float inv = (end > beg) ? 1.0f / ssum : 0.f;
    if (g == 0) {
      uint4 sr = *reinterpret_cast<const uint4*>(skp + rowb);
      f16x2 s0 = __builtin_bit_cast(f16x2, sr.x);
      f16x2 s1 = __builtin_bit_cast(f16x2, sr.y);
      f16x2 s2 = __builtin_bit_cast(f16x2, sr.z);
      f16x2 s3 = __builtin_bit_cast(f16x2, sr.w);
      int4 pk;
      pk.x = (int)f2bf(va[0] * inv + (float)s0[0]) | ((int)f2bf(va[1] * inv + (float)s0[1]) << 16);
      pk.y = (int)f2bf(va[2] * inv + (float)s1[0]) | ((int)f2bf(va[3] * inv + (float)s1[1]) << 16);
      pk.z = (int)f2bf(va[4] * inv + (float)s2[0]) | ((int)f2bf(va[5] * inv + (float)s2[1]) << 16);
      pk.w = (int)f2bf(va[6] * inv + (float)s3[0]) | ((int)f2bf(va[7] * inv + (float)s3[1]) << 16);
      *reinterpret_cast<int4*>(conv + rowb) = pk;
    }
  }
}

// ---------- 5. out = conv @ Wfc + bfc + x via MFMA; LDS-staged coalesced epilogue ----------
__global__ __launch_bounds__(256) void final_mfma_kernel(
    const unsigned short* __restrict__ conv, const unsigned short* __restrict__ Wt,
    const float* __restrict__ bfc, const float* __restrict__ x,
    float* __restrict__ outp, int N) {
  __shared__ __align__(16) unsigned short As[64 * 128];
  int t = threadIdx.x;
  int lane = t & 63;
  int wid = t >> 6;
  size_t row0 = (size_t)blockIdx.x * 64;

  for (int i = 0; i < 4; ++i) {
    int c = i * 256 + t;
    int r = c >> 4;
    int kc = (c & 15) * 8;
    int4 pk = make_int4(0, 0, 0, 0);
    if (row0 + r < (size_t)N)
      pk = *reinterpret_cast<const int4*>(conv + (row0 + r) * CH + kc);
    int byte = (r * 256 + kc * 2) ^ ((r & 7) << 4);
    *reinterpret_cast<int4*>((char*)As + byte) = pk;
  }
  __syncthreads();

  const unsigned short* wt = Wt + ((size_t)4 << 14);
  int lr = lane & 15;
  int lg = lane >> 4;

  f32x4 acc[4][2];
#pragma unroll
  for (int mt = 0; mt < 4; ++mt)
#pragma unroll
    for (int i = 0; i < 2; ++i) acc[mt][i] = (f32x4){0.f, 0.f, 0.f, 0.f};

  for (int ks = 0; ks < 4; ++ks) {
    bf16x8 a[4], b[2];
#pragma unroll
    for (int mt = 0; mt < 4; ++mt) {
      int r = mt * 16 + lr;
      int byte = (r * 256 + (ks * 32 + lg * 8) * 2) ^ ((r & 7) << 4);
      a[mt] = *reinterpret_cast<const bf16x8*>((const char*)As + byte);
    }
#pragma unroll
    for (int i = 0; i < 2; ++i) {
      int n = (wid * 2 + i) * 16 + lr;
      b[i] = *reinterpret_cast<const bf16x8*>(wt + n * 128 + ks * 32 + lg * 8);
    }
#pragma unroll
    for (int mt = 0; mt < 4; ++mt)
#pragma unroll
      for (int i = 0; i < 2; ++i)
        acc[mt][i] = __builtin_amdgcn_mfma_f32_16x16x32_bf16(b[i], a[mt], acc[mt][i], 0, 0, 0);
  }

  // stage f32 outputs through per-wave 4KB LDS -> full-line coalesced stores
  __syncthreads();
  char* reg = (char*)As + wid * 4096;
#pragma unroll
  for (int mt = 0; mt < 4; ++mt) {
#pragma unroll
    for (int i = 0; i < 2; ++i) {
      int byte = (lr * 128 + i * 64 + lg * 16) ^ ((lr & 7) << 4);
      *reinterpret_cast<f32x4*>(reg + byte) = acc[mt][i];
    }
#pragma unroll
    for (int i2 = 0; i2 < 2; ++i2) {
      int r = i2 * 8 + (lane >> 3);
      int byte = (r * 128 + (lane & 7) * 16) ^ ((r & 7) << 4);
      f32x4 val = *reinterpret_cast<const f32x4*>(reg + byte);
      int ch = wid * 32 + (lane & 7) * 4;
      size_t row = row0 + mt * 16 + r;
      if (row < (size_t)N) {
        float4 bb = *reinterpret_cast<const float4*>(bfc + ch);
        float4 rx = *reinterpret_cast<const float4*>(x + row * CH + ch);
        float4 o;
        o.x = val[0] + bb.x + rx.x;
        o.y = val[1] + bb.y + rx.y;
        o.z = val[2] + bb.z + rx.z;
        o.w = val[3] + bb.w + rx.w;
        *reinterpret_cast<float4*>(outp + row * CH + ch) = o;
      }
    }
  }
}

// ---------------------------------------------------------------
extern "C" void kernel_launch(void* const* d_in, const int* in_sizes, int n_in,
                              void* d_out, int out_size, void* d_ws, size_t ws_size,
                              hipStream_t stream) {
  const float* x = (const float*)d_in[0];
  const int* ei = (const int*)d_in[1];
  const float* gamma = (const float*)d_in[2];
  const float* beta = (const float*)d_in[3];
  const float* Wq = (const float*)d_in[4];
  const float* bq = (const float*)d_in[5];
  const float* Wk = (const float*)d_in[6];
  const float* bk = (const float*)d_in[7];
  const float* Wv = (const float*)d_in[8];
  const float* bv = (const float*)d_in[9];
  const float* Ws = (const float*)d_in[10];
  const float* bs = (const float*)d_in[11];
  const float* Wfc = (const float*)d_in[12];
  const float* bfc = (const float*)d_in[13];

  const int N = in_sizes[0] / CH;
  const int E = in_sizes[1] / 2;
  const int* srcp = ei;
  const int* dstp = ei + E;
  float* outp = (float*)d_out;

  char* wsb = (char*)d_ws;
  size_t off = 0;
  auto take = [&](size_t bytes) -> void* {
    void* p = wsb + off;
    off = (off + bytes + 255) & ~(size_t)255;
    return p;
  };
  float* stats = (float*)take(256 * 4);
  unsigned short* Wt = (unsigned short*)take((size_t)5 * 16384 * 2);
  unsigned short* qb = (unsigned short*)take((size_t)N * CH * 2);
  unsigned char* kb8 = (unsigned char*)take((size_t)N * CH);
  unsigned char* vb8 = (unsigned char*)take((size_t)N * CH);
  unsigned short* sb = (unsigned short*)take((size_t)N * CH * 2);
  unsigned short* convb = (unsigned short*)take((size_t)N * CH * 2);
  int* deg = (int*)take((size_t)N * 4);
  int* rank = (int*)take((size_t)E * 4);
  int* rowptr = (int*)take((size_t)(N + 1) * 4);
  int nchunks = (N + 2047) / 2048;
  int* chunksums = (int*)take((size_t)nchunks * 4);
  int* sorted_src = (int*)take((size_t)E * 4);

  (void)hipMemsetAsync(stats, 0, 256 * 4, stream);
  (void)hipMemsetAsync(deg, 0, (size_t)N * 4, stream);

  bn_stats_kernel<<<512, 256, 0, stream>>>(x, stats, N);
  pack_w_kernel<<<320, 256, 0, stream>>>(Wq, Wk, Wv, Ws, Wfc, Wt);

  int nblk = (N + 63) / 64;
  proj_mfma_kernel<<<nblk, 256, 0, stream>>>(x, stats, gamma, beta, Wt, bq, bk, bv, bs, qb, kb8,
                                             vb8, sb, N);

  deg_rank_kernel<<<2048, 256, 0, stream>>>(dstp, deg, rank, E);
  sum_chunks_kernel<<<nchunks, 256, 0, stream>>>(deg, chunksums, N);
  scan_chunks_kernel<<<nchunks, 256, 0, stream>>>(deg, chunksums, rowptr, N, nchunks);
  scatter_kernel<<<2048, 256, 0, stream>>>(srcp, dstp, rowptr, rank, sorted_src, E);

  int ablocks = 4096;
  attn_kernel<<<ablocks, 256, 0, stream>>>(qb, kb8, vb8, sb, rowptr, sorted_src, convb, N,
                                           ablocks * 4);
  final_mfma_kernel<<<nblk, 256, 0, stream>>>(convb, Wt, bfc, x, outp, N);
}